// Round 5
// baseline (6646.942 us; speedup 1.0000x reference)
//
#include <hip/hip_runtime.h>
#include <hip/hip_bf16.h>
#include <math.h>

typedef unsigned short u16;
typedef unsigned int   u32;
typedef __attribute__((ext_vector_type(8))) short short8;   // 8 bf16 = 4 VGPRs
typedef __attribute__((ext_vector_type(4))) float f32x4;

// ---- model dims ----
#define BSZ   64
#define TT    96
#define CCH   16
#define INDIM 16
#define HD    256
#define NHEAD 8
#define DHEAD 32
#define NCLS  4
#define LSEQ  100      // TT + NCLS
#define NLAY  4
#define EPSV  1e-5f
#define BSEQ  (BSZ*CCH)        // 1024 sequences
#define MTOK  (BSEQ*LSEQ)      // 102400 tokens
#define NCH   8                // pipeline chunks
#define SCH   (BSEQ/NCH)       // 128 sequences per chunk
#define RCH   (MTOK/NCH)       // 12800 rows per chunk

__device__ __forceinline__ float bf2f(u16 x){ return __uint_as_float(((u32)x)<<16); }
__device__ __forceinline__ u16 f2bf(float f){
    u32 u = __float_as_uint(f);
    u32 r = (u + 0x7fffu + ((u>>16)&1u)) >> 16;
    return (u16)r;
}
__device__ __forceinline__ float lo16(u32 r){ return __uint_as_float(r<<16); }
__device__ __forceinline__ float hi16(u32 r){ return __uint_as_float(r&0xffff0000u); }

// ---------------- f32 -> bf16 bulk convert ----------------
__global__ __launch_bounds__(256)
void k_cvt(const float* __restrict__ src, u16* __restrict__ dst, int n)
{
    for (int i = blockIdx.x*256 + threadIdx.x; i < n; i += gridDim.x*256)
        dst[i] = f2bf(src[i]);
}

// ---------------- embed ----------------
__global__ __launch_bounds__(256)
void k_embed(const float* __restrict__ x, const float* __restrict__ Wfc,
             const float* __restrict__ bfc, const float* __restrict__ cls,
             const float* __restrict__ pos, u16* __restrict__ h)
{
    int bid = blockIdx.x;              // s*LSEQ + l
    int s = bid / LSEQ, l = bid - s*LSEQ;
    int n = s >> 4, c = s & 15;
    int hc = threadIdx.x;
    float v;
    if (l < TT) {
        const float* xr = x + (size_t)((n*TT + l)*CCH + c)*INDIM;
        const float* wr = Wfc + hc*INDIM;
        float acc = bfc[hc];
        #pragma unroll
        for (int i=0;i<INDIM;i++) acc += xr[i] * wr[i];
        v = acc;
    } else {
        v = cls[(size_t)((l-TT)*CCH + c)*HD + hc];
    }
    v += pos[(size_t)(l*CCH + c)*HD + hc];
    h[(size_t)bid*HD + hc] = f2bf(v);
}

// ---------------- graph constructor ----------------
__global__ __launch_bounds__(256)
void k_graph_m(const float* __restrict__ emb, const float* __restrict__ Wl,
               const float* __restrict__ bl, float* __restrict__ m)
{
    int r = blockIdx.x, o = threadIdx.x;
    __shared__ float e[HD];
    e[o] = emb[r*HD + o];
    __syncthreads();
    const float* w = Wl + (size_t)o*HD;
    float acc = bl[o];
    for (int k=0;k<HD;k++) acc += e[k]*w[k];
    m[r*HD + o] = tanhf(acc);
}

__global__ __launch_bounds__(256)
void k_graph_a(const float* __restrict__ m1, const float* __restrict__ m2,
               float* __restrict__ a)
{
    int t = threadIdx.x; int v = t >> 4, w = t & 15;
    __shared__ float adj[16][17];
    float s1=0.f, s2=0.f;
    for (int k=0;k<HD;k++){
        s1 += m1[v*HD+k]*m2[w*HD+k];
        s2 += m2[v*HD+k]*m1[w*HD+k];
    }
    float g = tanhf(s1 - s2); g = g > 0.f ? g : 0.f;
    adj[v][w] = g + (v==w ? 1.f : 0.f);
    __syncthreads();
    float rs = 0.f;
    #pragma unroll
    for (int j=0;j<16;j++) rs += adj[v][j];
    a[t] = adj[v][w] / rs;
}

// ---------------- MFMA GEMM: C[M,N](bf16) = A @ W^T + bias, opt ReLU ----------------
// BM=128, BN=128, BK=32; 256 threads = 4 waves, each 64x64 via 4x4 MFMA 16x16x32 tiles.
__global__ __launch_bounds__(256)
void k_gemmA(const u16* __restrict__ A, int lda,
             const u16* __restrict__ W, const float* __restrict__ bias,
             u16* __restrict__ C, int ldc, int K, int relu)
{
    __shared__ u16 As[128*40];
    __shared__ u16 Ws[128*40];
    int t = threadIdx.x;
    int lane = t & 63, w = t >> 6;
    int wm = (w & 1)*64, wn = (w >> 1)*64;
    int fr = lane & 15, quad = lane >> 4;
    size_t mb = (size_t)blockIdx.x * 128;
    int nb = blockIdx.y * 128;
    int lrow = t >> 2, lch = (t & 3) << 3;

    f32x4 acc[4][4] = {};
    for (int k0 = 0; k0 < K; k0 += 32){
        uint4 av0 = *(const uint4*)&A[(mb + lrow     )*(size_t)lda + k0 + lch];
        uint4 av1 = *(const uint4*)&A[(mb + lrow + 64)*(size_t)lda + k0 + lch];
        uint4 wv0 = *(const uint4*)&W[(size_t)(nb + lrow     )*K + k0 + lch];
        uint4 wv1 = *(const uint4*)&W[(size_t)(nb + lrow + 64)*K + k0 + lch];
        __syncthreads();
        *(uint4*)&As[ lrow      *40 + lch] = av0;
        *(uint4*)&As[(lrow + 64)*40 + lch] = av1;
        *(uint4*)&Ws[ lrow      *40 + lch] = wv0;
        *(uint4*)&Ws[(lrow + 64)*40 + lch] = wv1;
        __syncthreads();
        short8 af[4], bf[4];
        #pragma unroll
        for (int mt=0; mt<4; mt++)
            af[mt] = *(const short8*)&As[(wm + mt*16 + fr)*40 + quad*8];
        #pragma unroll
        for (int nt=0; nt<4; nt++)
            bf[nt] = *(const short8*)&Ws[(wn + nt*16 + fr)*40 + quad*8];
        #pragma unroll
        for (int mt=0; mt<4; mt++)
            #pragma unroll
            for (int nt=0; nt<4; nt++)
                acc[mt][nt] = __builtin_amdgcn_mfma_f32_16x16x32_bf16(
                    af[mt], bf[nt], acc[mt][nt], 0, 0, 0);
    }
    float bb[4];
    #pragma unroll
    for (int nt=0; nt<4; nt++) bb[nt] = bias[nb + wn + nt*16 + fr];
    #pragma unroll
    for (int mt=0; mt<4; mt++){
        #pragma unroll
        for (int nt=0; nt<4; nt++){
            #pragma unroll
            for (int r=0; r<4; r++){
                float v = acc[mt][nt][r] + bb[nt];
                if (relu) v = v > 0.f ? v : 0.f;
                size_t rg = mb + wm + mt*16 + quad*4 + r;
                C[rg*(size_t)ldc + nb + wn + nt*16 + fr] = f2bf(v);
            }
        }
    }
}

// ------- MFMA GEMM (N=256) + bias + residual + LayerNorm fused, in-place h -------
// BM=64, BN=256, BK=32; 256 threads = 4 waves; wave w owns rows w*16..w*16+15, all 256 cols.
__global__ __launch_bounds__(256)
void k_gemmB(const u16* __restrict__ A, int lda, int K,
             const u16* __restrict__ W, const float* __restrict__ bias,
             u16* __restrict__ h, const float* __restrict__ gam,
             const float* __restrict__ bet, size_t row0)
{
    __shared__ u16 smem[16640];          // As[64*40] + Ws[256*40] -> Cs[64*260]
    u16* As = smem;                      // 2560
    u16* Ws = smem + 2560;               // 10240
    u16* Cs = smem;                      // 16640 overlay (after K-loop)
    int t = threadIdx.x;
    int lane = t & 63, w = t >> 6;
    int fr = lane & 15, quad = lane >> 4;
    size_t mb = (size_t)blockIdx.x * 64;
    int arow = t >> 2, ach = (t & 3) << 3;
    f32x4 acc[16] = {};
    for (int k0 = 0; k0 < K; k0 += 32){
        uint4 av = *(const uint4*)&A[(mb + arow)*(size_t)lda + k0 + ach];
        uint4 wv[4];
        #pragma unroll
        for (int j=0;j<4;j++){
            int slot = t + j*256;
            int wrow = slot >> 2, wch = (slot & 3) << 3;
            wv[j] = *(const uint4*)&W[(size_t)wrow*K + k0 + wch];
        }
        __syncthreads();
        *(uint4*)&As[arow*40 + ach] = av;
        #pragma unroll
        for (int j=0;j<4;j++){
            int slot = t + j*256;
            int wrow = slot >> 2, wch = (slot & 3) << 3;
            *(uint4*)&Ws[wrow*40 + wch] = wv[j];
        }
        __syncthreads();
        short8 af = *(const short8*)&As[(w*16 + fr)*40 + quad*8];
        #pragma unroll
        for (int nt=0; nt<16; nt++){
            short8 bf = *(const short8*)&Ws[(nt*16 + fr)*40 + quad*8];
            acc[nt] = __builtin_amdgcn_mfma_f32_16x16x32_bf16(af, bf, acc[nt], 0,0,0);
        }
    }
    __syncthreads();   // all waves done reading As/Ws
    #pragma unroll
    for (int nt=0; nt<16; nt++){
        float bb = bias[nt*16 + fr];
        #pragma unroll
        for (int r=0;r<4;r++)
            Cs[(w*16 + quad*4 + r)*260 + nt*16 + fr] = f2bf(acc[nt][r] + bb);
    }
    __syncthreads();
    // LN: row = t>>2 (0..63), part = t&3 covers cols part*64..part*64+63
    int row = t >> 2, part = t & 3;
    size_t grow = row0 + mb + row;
    float v[64];
    #pragma unroll
    for (int c8=0;c8<8;c8++){
        uint4 cs4 = *(const uint4*)&Cs[row*260 + part*64 + c8*8];
        uint4 h4  = *(const uint4*)&h[grow*HD + part*64 + c8*8];
        u32 cr[4] = {cs4.x,cs4.y,cs4.z,cs4.w};
        u32 hr[4] = {h4.x,h4.y,h4.z,h4.w};
        #pragma unroll
        for (int j=0;j<4;j++){
            v[c8*8+2*j]   = lo16(cr[j]) + lo16(hr[j]);
            v[c8*8+2*j+1] = hi16(cr[j]) + hi16(hr[j]);
        }
    }
    float s = 0.f;
    #pragma unroll
    for (int k=0;k<64;k++) s += v[k];
    s += __shfl_xor(s, 1, 64);
    s += __shfl_xor(s, 2, 64);
    float mean = s * (1.f/256.f);
    float vv = 0.f;
    #pragma unroll
    for (int k=0;k<64;k++){ float d = v[k]-mean; vv += d*d; }
    vv += __shfl_xor(vv, 1, 64);
    vv += __shfl_xor(vv, 2, 64);
    float inv = rsqrtf(vv*(1.f/256.f) + EPSV);
    #pragma unroll
    for (int c8=0;c8<8;c8++){
        float4 g0 = *(const float4*)&gam[part*64 + c8*8];
        float4 g1 = *(const float4*)&gam[part*64 + c8*8 + 4];
        float4 b0 = *(const float4*)&bet[part*64 + c8*8];
        float4 b1 = *(const float4*)&bet[part*64 + c8*8 + 4];
        float gg[8] = {g0.x,g0.y,g0.z,g0.w,g1.x,g1.y,g1.z,g1.w};
        float bb[8] = {b0.x,b0.y,b0.z,b0.w,b1.x,b1.y,b1.z,b1.w};
        u32 out[4];
        #pragma unroll
        for (int j=0;j<4;j++){
            u16 a = f2bf((v[c8*8+2*j]-mean)*inv*gg[2*j] + bb[2*j]);
            u16 b = f2bf((v[c8*8+2*j+1]-mean)*inv*gg[2*j+1] + bb[2*j+1]);
            out[j] = (u32)a | ((u32)b<<16);
        }
        uint4 o4 = {out[0],out[1],out[2],out[3]};
        *(uint4*)&h[grow*HD + part*64 + c8*8] = o4;
    }
}

// ---------------- attention: thread-per-query-row, online softmax, o -> q slot ----------------
__global__ __launch_bounds__(256)
void k_attn(u16* __restrict__ qkv)
{
    __shared__ float kf[2][3200];
    __shared__ float vf[2][3200];
    int t = threadIdx.x;
    int p = t >> 7, t2 = t & 127;
    int gp = blockIdx.x*2 + p;
    int s = gp >> 3, hh = gp & 7;
    size_t base = (size_t)s*LSEQ*768 + hh*32;
    for (int idx=t2; idx<1600; idx+=128){
        int i = idx >> 4, d2 = (idx & 15) << 1;
        u32 kk = *(const u32*)&qkv[base + (size_t)i*768 + 256 + d2];
        u32 vv = *(const u32*)&qkv[base + (size_t)i*768 + 512 + d2];
        kf[p][i*32+d2]   = lo16(kk); kf[p][i*32+d2+1] = hi16(kk);
        vf[p][i*32+d2]   = lo16(vv); vf[p][i*32+d2+1] = hi16(vv);
    }
    const float scale = 0.17677669529663687f;  // 1/sqrt(32)
    float q[32];
    int i = t2;
    if (i < LSEQ){
        const u16* qp = &qkv[base + (size_t)i*768];
        #pragma unroll
        for (int c=0;c<4;c++){
            uint4 r4 = *(const uint4*)&qp[c*8];
            u32 rr[4] = {r4.x, r4.y, r4.z, r4.w};
            #pragma unroll
            for (int j=0;j<4;j++){
                q[c*8+2*j]   = lo16(rr[j])*scale;
                q[c*8+2*j+1] = hi16(rr[j])*scale;
            }
        }
    }
    __syncthreads();
    if (i < LSEQ){
        float m = -1e30f, l = 0.f, o[32];
        #pragma unroll
        for (int d=0;d<32;d++) o[d] = 0.f;
        int jmax = (i < TT) ? i : (LSEQ-1);
        for (int j=0; j<=jmax; j++){
            const float4* kr = (const float4*)&kf[p][j*32];
            float sc = 0.f;
            #pragma unroll
            for (int c=0;c<8;c++){
                float4 kk = kr[c];
                sc += q[4*c]*kk.x + q[4*c+1]*kk.y + q[4*c+2]*kk.z + q[4*c+3]*kk.w;
            }
            float mn = fmaxf(m, sc);
            float al = __expf(m - mn);
            float pj = __expf(sc - mn);
            l = l*al + pj;
            const float4* vr = (const float4*)&vf[p][j*32];
            #pragma unroll
            for (int c=0;c<8;c++){
                float4 vv = vr[c];
                o[4*c]   = o[4*c]*al   + pj*vv.x;
                o[4*c+1] = o[4*c+1]*al + pj*vv.y;
                o[4*c+2] = o[4*c+2]*al + pj*vv.z;
                o[4*c+3] = o[4*c+3]*al + pj*vv.w;
            }
            m = mn;
        }
        float inv = 1.f/l;
        #pragma unroll
        for (int d2=0; d2<32; d2+=2){
            u32 pk = (u32)f2bf(o[d2]*inv) | ((u32)f2bf(o[d2+1]*inv) << 16);
            *(u32*)&qkv[base + (size_t)i*768 + d2] = pk;
        }
    }
}

// ---------------- mixprop on cls tokens, in-place h (bf16) update ----------------
__global__ __launch_bounds__(256)
void k_mixprop(u16* __restrict__ h, const float* __restrict__ a,
               const float* __restrict__ Wm, const float* __restrict__ bm)
{
    int n = blockIdx.x >> 2, tt = blockIdx.x & 3;
    __shared__ float xs[256][17], h1s[256][17], h2s[256][17];
    __shared__ float as[16][17];
    int t = threadIdx.x;
    as[t>>4][t&15] = a[t];
    for (int idx=t; idx<4096; idx+=256){
        int w = idx >> 8, hc = idx & 255;
        xs[hc][w] = bf2f(h[((size_t)(n*16 + w)*LSEQ + TT + tt)*HD + hc]);
    }
    __syncthreads();
    for (int idx=t; idx<4096; idx+=256){
        int v = idx & 15, hc = idx >> 4;
        float acc = 0.f;
        #pragma unroll
        for (int w=0;w<16;w++) acc += as[v][w]*xs[hc][w];
        h1s[hc][v] = acc;
    }
    __syncthreads();
    for (int idx=t; idx<4096; idx+=256){
        int v = idx & 15, hc = idx >> 4;
        float acc = 0.f;
        #pragma unroll
        for (int w=0;w<16;w++) acc += as[v][w]*h1s[hc][w];
        h2s[hc][v] = acc;
    }
    __syncthreads();
    int o = t;
    const float* wr = Wm + (size_t)o*768;
    float acc[16];
    #pragma unroll
    for (int w=0;w<16;w++) acc[w] = 0.f;
    for (int hc=0; hc<256; hc++){
        float w0 = wr[hc];
        float w1 = wr[256+hc];
        float w2 = wr[512+hc];
        #pragma unroll
        for (int w=0;w<16;w++)
            acc[w] += xs[hc][w]*w0 + h1s[hc][w]*w1 + h2s[hc][w]*w2;
    }
    float bb = bm[o];
    #pragma unroll
    for (int w=0;w<16;w++)
        h[((size_t)(n*16 + w)*LSEQ + TT + tt)*HD + o] = f2bf(acc[w] + bb);
}

// ---------------- head ----------------
__global__ __launch_bounds__(256)
void k_z(const u16* __restrict__ h, u16* __restrict__ z)
{
    int bid = blockIdx.x, t = threadIdx.x;     // bid = n*16+c
    #pragma unroll
    for (int tc=0;tc<4;tc++)
        z[((size_t)bid*4 + tc)*HD + t] = f2bf(tanhf(bf2f(h[((size_t)bid*LSEQ + TT + tc)*HD + t])));
}

// head1 partial: grid (nb 0..15, kb 0..15); partial over K-chunk of 1024
__global__ __launch_bounds__(256)
void k_head1p(const u16* __restrict__ z, const u16* __restrict__ Wd1b,
              float* __restrict__ d1p)
{
    __shared__ float zch[64][137];
    __shared__ float wt[16][137];
    int t = threadIdx.x;
    int col = t & 15, rgrp = t >> 4;
    int ob = blockIdx.x * 16;
    int kb = blockIdx.y;
    float acc[4] = {0.f,0.f,0.f,0.f};
    for (int kc=0; kc<1024; kc+=128){
        int base_k = kb*1024 + kc;
        #pragma unroll
        for (int jj=0; jj<16; jj++){
            int idx = t + jj*256;
            int n = idx >> 6, k2 = (idx & 63) << 1;
            u32 r = *(const u32*)&z[(size_t)n*16384 + base_k + k2];
            zch[n][k2] = lo16(r); zch[n][k2+1] = hi16(r);
        }
        #pragma unroll
        for (int jj=0; jj<4; jj++){
            int idx = t + jj*256;
            int r = idx >> 6, k2 = (idx & 63) << 1;
            u32 w = *(const u32*)&Wd1b[(size_t)(ob + r)*16384 + base_k + k2];
            wt[r][k2] = lo16(w); wt[r][k2+1] = hi16(w);
        }
        __syncthreads();
        for (int k=0;k<128;k++){
            float wv = wt[col][k];
            #pragma unroll
            for (int u=0;u<4;u++) acc[u] += zch[rgrp + 16*u][k]*wv;
        }
        __syncthreads();
    }
    #pragma unroll
    for (int u=0;u<4;u++)
        d1p[(size_t)(kb*64 + rgrp + 16*u)*HD + ob + col] = acc[u];
}

__global__ __launch_bounds__(256)
void k_head1r(const float* __restrict__ d1p, const float* __restrict__ bd1,
              float* __restrict__ d1)
{
    int e = blockIdx.x*256 + threadIdx.x;      // 16384
    int r = e >> 8, c = e & 255;
    float s = 0.f;
    #pragma unroll
    for (int kb=0; kb<16; kb++) s += d1p[(size_t)(kb*64 + r)*HD + c];
    float xx = s + bd1[c];
    float ge = 0.5f*xx*(1.f + erff(xx*0.70710678118654752f));
    d1[(size_t)r*HD + c] = ge;
}

__global__ __launch_bounds__(64)
void k_head2(const float* __restrict__ d1, const float* __restrict__ Wd2,
             const float* __restrict__ bd2, float* __restrict__ out)
{
    int n = blockIdx.x, lane = threadIdx.x;
    float p = 0.f;
    #pragma unroll
    for (int j=0;j<4;j++){
        int k = lane*4 + j;
        p += d1[(size_t)n*HD + k]*Wd2[k];
    }
    #pragma unroll
    for (int m=1;m<64;m<<=1) p += __shfl_xor(p, m, 64);
    if (lane==0) out[n] = p + bd2[0];
}

// ---------------- launch ----------------
extern "C" void kernel_launch(void* const* d_in, const int* in_sizes, int n_in,
                              void* d_out, int out_size, void* d_ws, size_t ws_size,
                              hipStream_t stream)
{
    const float* x    = (const float*)d_in[0];
    const float* Wfc  = (const float*)d_in[3];
    const float* bfc  = (const float*)d_in[4];
    const float* cls  = (const float*)d_in[5];
    const float* pos  = (const float*)d_in[6];
    const float* emb1 = (const float*)d_in[7];
    const float* emb2 = (const float*)d_in[8];
    const float* Wl1  = (const float*)d_in[9];
    const float* bl1  = (const float*)d_in[10];
    const float* Wl2  = (const float*)d_in[11];
    const float* bl2  = (const float*)d_in[12];
    const float* Wqkv = (const float*)d_in[13];
    const float* bqkv = (const float*)d_in[14];
    const float* Wo   = (const float*)d_in[15];
    const float* bo   = (const float*)d_in[16];
    const float* W1   = (const float*)d_in[17];
    const float* b1   = (const float*)d_in[18];
    const float* W2   = (const float*)d_in[19];
    const float* b2   = (const float*)d_in[20];
    const float* ln1g = (const float*)d_in[21];
    const float* ln1b = (const float*)d_in[22];
    const float* ln2g = (const float*)d_in[23];
    const float* ln2b = (const float*)d_in[24];
    const float* Wmlp = (const float*)d_in[25];
    const float* bmlp = (const float*)d_in[26];
    const float* Wd1  = (const float*)d_in[27];
    const float* bd1  = (const float*)d_in[28];
    const float* Wd2  = (const float*)d_in[29];
    const float* bd2  = (const float*)d_in[30];

    // workspace layout (~96.6 MB)
    u16* h    = (u16*)d_ws;                    // 26,214,400
    u16* buf  = h    + (size_t)MTOK*HD;        // 13,107,200  (qkv 12800x768 / ff1 12800x1024)
    u16* wq   = buf  + (size_t)RCH*1024;       //    786,432  (all 4 layers)
    u16* wo   = wq   + (size_t)4*768*256;      //    262,144
    u16* w1   = wo   + (size_t)4*256*256;      //  1,048,576
    u16* w2   = w1   + (size_t)4*1024*256;     //  1,048,576
    u16* wd1b = w2   + (size_t)4*256*1024;     //  4,194,304
    u16* zb   = wd1b + (size_t)256*16384;      //  1,048,576
    float* fp = (float*)(zb + (size_t)BSZ*16384);
    float* m1  = fp;                           // 4096
    float* m2  = m1 + CCH*HD;                  // 4096
    float* an  = m2 + CCH*HD;                  // 256
    float* d1p = an + CCH*CCH;                 // 16*64*256 = 262144
    float* d1  = d1p + (size_t)16*64*HD;       // 16384

    // pre-convert all weights to bf16
    k_cvt<<<512, 256, 0, stream>>>(Wqkv, wq, 4*768*256);
    k_cvt<<<256, 256, 0, stream>>>(Wo,   wo, 4*256*256);
    k_cvt<<<512, 256, 0, stream>>>(W1,   w1, 4*1024*256);
    k_cvt<<<512, 256, 0, stream>>>(W2,   w2, 4*256*1024);
    k_cvt<<<1024,256, 0, stream>>>(Wd1, wd1b, 256*16384);

    k_embed<<<MTOK, 256, 0, stream>>>(x, Wfc, bfc, cls, pos, h);
    k_graph_m<<<16, 256, 0, stream>>>(emb1, Wl1, bl1, m1);
    k_graph_m<<<16, 256, 0, stream>>>(emb2, Wl2, bl2, m2);
    k_graph_a<<<1, 256, 0, stream>>>(m1, m2, an);

    for (int l=0; l<NLAY; l++){
        if (l > 0)
            k_mixprop<<<BSZ*NCLS, 256, 0, stream>>>(h, an,
                Wmlp + (size_t)(l-1)*HD*768, bmlp + (size_t)(l-1)*HD);

        for (int c=0; c<NCH; c++){
            size_t row0 = (size_t)c * RCH;
            // qkv projection: (12800x256) @ (768x256)^T -> buf
            k_gemmA<<<dim3(RCH/128, 768/128), 256, 0, stream>>>(
                h + row0*HD, HD, wq + (size_t)l*768*256, bqkv + (size_t)l*768,
                buf, 768, HD, 0);
            // attention (o -> q slot)
            k_attn<<<SCH*NHEAD/2, 256, 0, stream>>>(buf);
            // out-proj + residual + LN1 fused
            k_gemmB<<<RCH/64, 256, 0, stream>>>(
                buf, 768, HD, wo + (size_t)l*256*256, bo + (size_t)l*HD,
                h, ln1g + (size_t)l*HD, ln1b + (size_t)l*HD, row0);
            // FF1: (12800x256) @ (1024x256)^T -> buf, relu
            k_gemmA<<<dim3(RCH/128, 1024/128), 256, 0, stream>>>(
                h + row0*HD, HD, w1 + (size_t)l*1024*256, b1 + (size_t)l*1024,
                buf, 1024, HD, 1);
            // FF2 + residual + LN2 fused
            k_gemmB<<<RCH/64, 256, 0, stream>>>(
                buf, 1024, 1024, w2 + (size_t)l*256*1024, b2 + (size_t)l*HD,
                h, ln2g + (size_t)l*HD, ln2b + (size_t)l*HD, row0);
        }
    }

    k_z<<<BSZ*CCH, 256, 0, stream>>>(h, zb);
    k_head1p<<<dim3(16, 16), 256, 0, stream>>>(zb, wd1b, d1p);
    k_head1r<<<64, 256, 0, stream>>>(d1p, bd1, d1);
    k_head2<<<BSZ, 64, 0, stream>>>(d1, Wd2, bd2, (float*)d_out);
}

// Round 6
// 5098.099 us; speedup vs baseline: 1.3038x; 1.3038x over previous
//
#include <hip/hip_runtime.h>
#include <hip/hip_bf16.h>
#include <math.h>

typedef unsigned short u16;
typedef unsigned int   u32;
typedef __attribute__((ext_vector_type(8))) short short8;   // 8 bf16 = 4 VGPRs
typedef __attribute__((ext_vector_type(4))) float f32x4;

// ---- model dims ----
#define BSZ   64
#define TT    96
#define CCH   16
#define INDIM 16
#define HD    256
#define NHEAD 8
#define DHEAD 32
#define NCLS  4
#define LSEQ  100      // TT + NCLS
#define NLAY  4
#define EPSV  1e-5f
#define BSEQ  (BSZ*CCH)        // 1024 sequences
#define MTOK  (BSEQ*LSEQ)      // 102400 tokens
#define NCH   8                // pipeline chunks
#define SCH   (BSEQ/NCH)       // 128 sequences per chunk
#define RCH   (MTOK/NCH)       // 12800 rows per chunk

__device__ __forceinline__ float bf2f(u16 x){ return __uint_as_float(((u32)x)<<16); }
__device__ __forceinline__ u16 f2bf(float f){
    u32 u = __float_as_uint(f);
    u32 r = (u + 0x7fffu + ((u>>16)&1u)) >> 16;
    return (u16)r;
}
__device__ __forceinline__ float lo16(u32 r){ return __uint_as_float(r<<16); }
__device__ __forceinline__ float hi16(u32 r){ return __uint_as_float(r&0xffff0000u); }

// ---------------- f32 -> bf16 bulk convert ----------------
__global__ __launch_bounds__(256)
void k_cvt(const float* __restrict__ src, u16* __restrict__ dst, int n)
{
    for (int i = blockIdx.x*256 + threadIdx.x; i < n; i += gridDim.x*256)
        dst[i] = f2bf(src[i]);
}

// ---------------- Wmlp transpose: WmT[l][j][o] = bf16(Wmlp[l][o][j]) ----------------
__global__ __launch_bounds__(256)
void k_wmT(const float* __restrict__ Wm, u16* __restrict__ wmT)
{
    int b = blockIdx.x;           // l*768 + j
    int l = b / 768, j = b - l*768;
    int o = threadIdx.x;
    wmT[(size_t)b*256 + o] = f2bf(Wm[(size_t)(l*256 + o)*768 + j]);
}

// ---------------- embed ----------------
__global__ __launch_bounds__(256)
void k_embed(const float* __restrict__ x, const float* __restrict__ Wfc,
             const float* __restrict__ bfc, const float* __restrict__ cls,
             const float* __restrict__ pos, u16* __restrict__ h)
{
    int bid = blockIdx.x;              // s*LSEQ + l
    int s = bid / LSEQ, l = bid - s*LSEQ;
    int n = s >> 4, c = s & 15;
    int hc = threadIdx.x;
    float v;
    if (l < TT) {
        const float* xr = x + (size_t)((n*TT + l)*CCH + c)*INDIM;
        const float* wr = Wfc + hc*INDIM;
        float acc = bfc[hc];
        #pragma unroll
        for (int i=0;i<INDIM;i++) acc += xr[i] * wr[i];
        v = acc;
    } else {
        v = cls[(size_t)((l-TT)*CCH + c)*HD + hc];
    }
    v += pos[(size_t)(l*CCH + c)*HD + hc];
    h[(size_t)bid*HD + hc] = f2bf(v);
}

// ---------------- graph constructor ----------------
__global__ __launch_bounds__(256)
void k_graph_m(const float* __restrict__ emb, const float* __restrict__ Wl,
               const float* __restrict__ bl, float* __restrict__ m)
{
    int r = blockIdx.x, o = threadIdx.x;
    __shared__ float e[HD];
    e[o] = emb[r*HD + o];
    __syncthreads();
    const float* w = Wl + (size_t)o*HD;
    float acc = bl[o];
    for (int k=0;k<HD;k++) acc += e[k]*w[k];
    m[r*HD + o] = tanhf(acc);
}

__global__ __launch_bounds__(256)
void k_graph_a(const float* __restrict__ m1, const float* __restrict__ m2,
               float* __restrict__ a)
{
    int t = threadIdx.x; int v = t >> 4, w = t & 15;
    __shared__ float adj[16][17];
    float s1=0.f, s2=0.f;
    for (int k=0;k<HD;k++){
        s1 += m1[v*HD+k]*m2[w*HD+k];
        s2 += m2[v*HD+k]*m1[w*HD+k];
    }
    float g = tanhf(s1 - s2); g = g > 0.f ? g : 0.f;
    adj[v][w] = g + (v==w ? 1.f : 0.f);
    __syncthreads();
    float rs = 0.f;
    #pragma unroll
    for (int j=0;j<16;j++) rs += adj[v][j];
    a[t] = adj[v][w] / rs;
}

// ---------------- MFMA GEMM: C[M,N](bf16) = A @ W^T + bias, opt ReLU ----------------
// BM=128, BN=128, BK=32; 256 threads = 4 waves, each 64x64 via 4x4 MFMA 16x16x32 tiles.
__global__ __launch_bounds__(256)
void k_gemmA(const u16* __restrict__ A, int lda,
             const u16* __restrict__ W, const float* __restrict__ bias,
             u16* __restrict__ C, int ldc, int K, int relu)
{
    __shared__ u16 As[128*40];
    __shared__ u16 Ws[128*40];
    int t = threadIdx.x;
    int lane = t & 63, w = t >> 6;
    int wm = (w & 1)*64, wn = (w >> 1)*64;
    int fr = lane & 15, quad = lane >> 4;
    size_t mb = (size_t)blockIdx.x * 128;
    int nb = blockIdx.y * 128;
    int lrow = t >> 2, lch = (t & 3) << 3;

    f32x4 acc[4][4] = {};
    for (int k0 = 0; k0 < K; k0 += 32){
        uint4 av0 = *(const uint4*)&A[(mb + lrow     )*(size_t)lda + k0 + lch];
        uint4 av1 = *(const uint4*)&A[(mb + lrow + 64)*(size_t)lda + k0 + lch];
        uint4 wv0 = *(const uint4*)&W[(size_t)(nb + lrow     )*K + k0 + lch];
        uint4 wv1 = *(const uint4*)&W[(size_t)(nb + lrow + 64)*K + k0 + lch];
        __syncthreads();
        *(uint4*)&As[ lrow      *40 + lch] = av0;
        *(uint4*)&As[(lrow + 64)*40 + lch] = av1;
        *(uint4*)&Ws[ lrow      *40 + lch] = wv0;
        *(uint4*)&Ws[(lrow + 64)*40 + lch] = wv1;
        __syncthreads();
        short8 af[4], bf[4];
        #pragma unroll
        for (int mt=0; mt<4; mt++)
            af[mt] = *(const short8*)&As[(wm + mt*16 + fr)*40 + quad*8];
        #pragma unroll
        for (int nt=0; nt<4; nt++)
            bf[nt] = *(const short8*)&Ws[(wn + nt*16 + fr)*40 + quad*8];
        #pragma unroll
        for (int mt=0; mt<4; mt++)
            #pragma unroll
            for (int nt=0; nt<4; nt++)
                acc[mt][nt] = __builtin_amdgcn_mfma_f32_16x16x32_bf16(
                    af[mt], bf[nt], acc[mt][nt], 0, 0, 0);
    }
    float bb[4];
    #pragma unroll
    for (int nt=0; nt<4; nt++) bb[nt] = bias[nb + wn + nt*16 + fr];
    #pragma unroll
    for (int mt=0; mt<4; mt++){
        #pragma unroll
        for (int nt=0; nt<4; nt++){
            #pragma unroll
            for (int r=0; r<4; r++){
                float v = acc[mt][nt][r] + bb[nt];
                if (relu) v = v > 0.f ? v : 0.f;
                size_t rg = mb + wm + mt*16 + quad*4 + r;
                C[rg*(size_t)ldc + nb + wn + nt*16 + fr] = f2bf(v);
            }
        }
    }
}

// ---------------- attention: thread-per-query-row, online softmax, o -> q slot ----------------
__global__ __launch_bounds__(256)
void k_attn(u16* __restrict__ qkv)
{
    __shared__ float kf[2][3200];
    __shared__ float vf[2][3200];
    int t = threadIdx.x;
    int p = t >> 7, t2 = t & 127;
    int gp = blockIdx.x*2 + p;
    int s = gp >> 3, hh = gp & 7;
    size_t base = (size_t)s*LSEQ*768 + hh*32;
    for (int idx=t2; idx<1600; idx+=128){
        int i = idx >> 4, d2 = (idx & 15) << 1;
        u32 kk = *(const u32*)&qkv[base + (size_t)i*768 + 256 + d2];
        u32 vv = *(const u32*)&qkv[base + (size_t)i*768 + 512 + d2];
        kf[p][i*32+d2]   = lo16(kk); kf[p][i*32+d2+1] = hi16(kk);
        vf[p][i*32+d2]   = lo16(vv); vf[p][i*32+d2+1] = hi16(vv);
    }
    const float scale = 0.17677669529663687f;  // 1/sqrt(32)
    float q[32];
    int i = t2;
    if (i < LSEQ){
        const u16* qp = &qkv[base + (size_t)i*768];
        #pragma unroll
        for (int c=0;c<4;c++){
            uint4 r4 = *(const uint4*)&qp[c*8];
            u32 rr[4] = {r4.x, r4.y, r4.z, r4.w};
            #pragma unroll
            for (int j=0;j<4;j++){
                q[c*8+2*j]   = lo16(rr[j])*scale;
                q[c*8+2*j+1] = hi16(rr[j])*scale;
            }
        }
    }
    __syncthreads();
    if (i < LSEQ){
        float m = -1e30f, l = 0.f, o[32];
        #pragma unroll
        for (int d=0;d<32;d++) o[d] = 0.f;
        int jmax = (i < TT) ? i : (LSEQ-1);
        for (int j=0; j<=jmax; j++){
            const float4* kr = (const float4*)&kf[p][j*32];
            float sc = 0.f;
            #pragma unroll
            for (int c=0;c<8;c++){
                float4 kk = kr[c];
                sc += q[4*c]*kk.x + q[4*c+1]*kk.y + q[4*c+2]*kk.z + q[4*c+3]*kk.w;
            }
            float mn = fmaxf(m, sc);
            float al = __expf(m - mn);
            float pj = __expf(sc - mn);
            l = l*al + pj;
            const float4* vr = (const float4*)&vf[p][j*32];
            #pragma unroll
            for (int c=0;c<8;c++){
                float4 vv = vr[c];
                o[4*c]   = o[4*c]*al   + pj*vv.x;
                o[4*c+1] = o[4*c+1]*al + pj*vv.y;
                o[4*c+2] = o[4*c+2]*al + pj*vv.z;
                o[4*c+3] = o[4*c+3]*al + pj*vv.w;
            }
            m = mn;
        }
        float inv = 1.f/l;
        #pragma unroll
        for (int d2=0; d2<32; d2+=2){
            u32 pk = (u32)f2bf(o[d2]*inv) | ((u32)f2bf(o[d2+1]*inv) << 16);
            *(u32*)&qkv[base + (size_t)i*768 + d2] = pk;
        }
    }
}

// ---------------- residual + LayerNorm: h[row] = LN(g[row_local] + h[row]) ----------------
// block = 256 threads = 8 rows x 32 lanes x 8 cols
__global__ __launch_bounds__(256)
void k_ln(const u16* __restrict__ g, u16* __restrict__ h,
          const float* __restrict__ gam, const float* __restrict__ bet,
          size_t row0)
{
    int t = threadIdx.x;
    int rl = t >> 5, lane32 = t & 31, c8 = lane32 << 3;
    size_t lrow = (size_t)blockIdx.x*8 + rl;
    size_t grow = row0 + lrow;
    uint4 g4 = *(const uint4*)&g[lrow*HD + c8];
    uint4 h4 = *(const uint4*)&h[grow*HD + c8];
    u32 gr[4] = {g4.x,g4.y,g4.z,g4.w};
    u32 hr[4] = {h4.x,h4.y,h4.z,h4.w};
    float v[8];
    #pragma unroll
    for (int j=0;j<4;j++){
        v[2*j]   = lo16(gr[j]) + lo16(hr[j]);
        v[2*j+1] = hi16(gr[j]) + hi16(hr[j]);
    }
    float s = 0.f;
    #pragma unroll
    for (int k=0;k<8;k++) s += v[k];
    #pragma unroll
    for (int msk=1; msk<32; msk<<=1) s += __shfl_xor(s, msk, 32);
    float mean = s * (1.f/256.f);
    float vv = 0.f;
    #pragma unroll
    for (int k=0;k<8;k++){ float d = v[k]-mean; vv += d*d; }
    #pragma unroll
    for (int msk=1; msk<32; msk<<=1) vv += __shfl_xor(vv, msk, 32);
    float inv = rsqrtf(vv*(1.f/256.f) + EPSV);
    float4 g0 = *(const float4*)&gam[c8];
    float4 g1 = *(const float4*)&gam[c8+4];
    float4 b0 = *(const float4*)&bet[c8];
    float4 b1 = *(const float4*)&bet[c8+4];
    float gg[8] = {g0.x,g0.y,g0.z,g0.w,g1.x,g1.y,g1.z,g1.w};
    float bb[8] = {b0.x,b0.y,b0.z,b0.w,b1.x,b1.y,b1.z,b1.w};
    u32 out[4];
    #pragma unroll
    for (int j=0;j<4;j++){
        u16 a = f2bf((v[2*j]-mean)*inv*gg[2*j] + bb[2*j]);
        u16 b = f2bf((v[2*j+1]-mean)*inv*gg[2*j+1] + bb[2*j+1]);
        out[j] = (u32)a | ((u32)b << 16);
    }
    uint4 o4 = {out[0], out[1], out[2], out[3]};
    *(uint4*)&h[grow*HD + c8] = o4;
}

// ---------------- mixprop on cls tokens (coalesced WmT reads), in-place h ----------------
__global__ __launch_bounds__(256)
void k_mixprop(u16* __restrict__ h, const float* __restrict__ a,
               const u16* __restrict__ wmT, const float* __restrict__ bm)
{
    int n = blockIdx.x >> 2, tt = blockIdx.x & 3;
    __shared__ float xs[256][17], h1s[256][17], h2s[256][17];
    __shared__ float as[16][17];
    int t = threadIdx.x;
    as[t>>4][t&15] = a[t];
    for (int idx=t; idx<4096; idx+=256){
        int w = idx >> 8, hc = idx & 255;
        xs[hc][w] = bf2f(h[((size_t)(n*16 + w)*LSEQ + TT + tt)*HD + hc]);
    }
    __syncthreads();
    for (int idx=t; idx<4096; idx+=256){
        int v = idx & 15, hc = idx >> 4;
        float acc = 0.f;
        #pragma unroll
        for (int w=0;w<16;w++) acc += as[v][w]*xs[hc][w];
        h1s[hc][v] = acc;
    }
    __syncthreads();
    for (int idx=t; idx<4096; idx+=256){
        int v = idx & 15, hc = idx >> 4;
        float acc = 0.f;
        #pragma unroll
        for (int w=0;w<16;w++) acc += as[v][w]*h1s[hc][w];
        h2s[hc][v] = acc;
    }
    __syncthreads();
    int o = t;
    float acc[16];
    #pragma unroll
    for (int w=0;w<16;w++) acc[w] = 0.f;
    for (int hc=0; hc<256; hc++){
        float w0 = bf2f(wmT[hc*256 + o]);            // coalesced: lanes = consecutive o
        float w1 = bf2f(wmT[(256+hc)*256 + o]);
        float w2 = bf2f(wmT[(512+hc)*256 + o]);
        #pragma unroll
        for (int w=0;w<16;w++)
            acc[w] += xs[hc][w]*w0 + h1s[hc][w]*w1 + h2s[hc][w]*w2;
    }
    float bb = bm[o];
    #pragma unroll
    for (int w=0;w<16;w++)
        h[((size_t)(n*16 + w)*LSEQ + TT + tt)*HD + o] = f2bf(acc[w] + bb);
}

// ---------------- head ----------------
__global__ __launch_bounds__(256)
void k_z(const u16* __restrict__ h, u16* __restrict__ z)
{
    int bid = blockIdx.x, t = threadIdx.x;     // bid = n*16+c
    #pragma unroll
    for (int tc=0;tc<4;tc++)
        z[((size_t)bid*4 + tc)*HD + t] = f2bf(tanhf(bf2f(h[((size_t)bid*LSEQ + TT + tc)*HD + t])));
}

// head1 partial: grid (nb 0..15, kb 0..15); partial over K-chunk of 1024; Wd1 read fp32
__global__ __launch_bounds__(256)
void k_head1p(const u16* __restrict__ z, const float* __restrict__ Wd1,
              float* __restrict__ d1p)
{
    __shared__ float zch[64][137];
    __shared__ float wt[16][137];
    int t = threadIdx.x;
    int col = t & 15, rgrp = t >> 4;
    int ob = blockIdx.x * 16;
    int kb = blockIdx.y;
    float acc[4] = {0.f,0.f,0.f,0.f};
    for (int kc=0; kc<1024; kc+=128){
        int base_k = kb*1024 + kc;
        #pragma unroll
        for (int jj=0; jj<16; jj++){
            int idx = t + jj*256;
            int n = idx >> 6, k2 = (idx & 63) << 1;
            u32 r = *(const u32*)&z[(size_t)n*16384 + base_k + k2];
            zch[n][k2] = lo16(r); zch[n][k2+1] = hi16(r);
        }
        #pragma unroll
        for (int jj=0; jj<2; jj++){
            int idx = t + jj*256;
            int r = idx >> 5, k4 = (idx & 31) << 2;
            float4 w4 = *(const float4*)&Wd1[(size_t)(ob + r)*16384 + base_k + k4];
            wt[r][k4] = w4.x; wt[r][k4+1] = w4.y; wt[r][k4+2] = w4.z; wt[r][k4+3] = w4.w;
        }
        __syncthreads();
        for (int k=0;k<128;k++){
            float wv = wt[col][k];
            #pragma unroll
            for (int u=0;u<4;u++) acc[u] += zch[rgrp + 16*u][k]*wv;
        }
        __syncthreads();
    }
    #pragma unroll
    for (int u=0;u<4;u++)
        d1p[(size_t)(kb*64 + rgrp + 16*u)*HD + ob + col] = acc[u];
}

__global__ __launch_bounds__(256)
void k_head1r(const float* __restrict__ d1p, const float* __restrict__ bd1,
              float* __restrict__ d1)
{
    int e = blockIdx.x*256 + threadIdx.x;      // 16384
    int r = e >> 8, c = e & 255;
    float s = 0.f;
    #pragma unroll
    for (int kb=0; kb<16; kb++) s += d1p[(size_t)(kb*64 + r)*HD + c];
    float xx = s + bd1[c];
    float ge = 0.5f*xx*(1.f + erff(xx*0.70710678118654752f));
    d1[(size_t)r*HD + c] = ge;
}

__global__ __launch_bounds__(64)
void k_head2(const float* __restrict__ d1, const float* __restrict__ Wd2,
             const float* __restrict__ bd2, float* __restrict__ out)
{
    int n = blockIdx.x, lane = threadIdx.x;
    float p = 0.f;
    #pragma unroll
    for (int j=0;j<4;j++){
        int k = lane*4 + j;
        p += d1[(size_t)n*HD + k]*Wd2[k];
    }
    #pragma unroll
    for (int m=1;m<64;m<<=1) p += __shfl_xor(p, m, 64);
    if (lane==0) out[n] = p + bd2[0];
}

// ---------------- launch ----------------
extern "C" void kernel_launch(void* const* d_in, const int* in_sizes, int n_in,
                              void* d_out, int out_size, void* d_ws, size_t ws_size,
                              hipStream_t stream)
{
    const float* x    = (const float*)d_in[0];
    const float* Wfc  = (const float*)d_in[3];
    const float* bfc  = (const float*)d_in[4];
    const float* cls  = (const float*)d_in[5];
    const float* pos  = (const float*)d_in[6];
    const float* emb1 = (const float*)d_in[7];
    const float* emb2 = (const float*)d_in[8];
    const float* Wl1  = (const float*)d_in[9];
    const float* bl1  = (const float*)d_in[10];
    const float* Wl2  = (const float*)d_in[11];
    const float* bl2  = (const float*)d_in[12];
    const float* Wqkv = (const float*)d_in[13];
    const float* bqkv = (const float*)d_in[14];
    const float* Wo   = (const float*)d_in[15];
    const float* bo   = (const float*)d_in[16];
    const float* W1   = (const float*)d_in[17];
    const float* b1   = (const float*)d_in[18];
    const float* W2   = (const float*)d_in[19];
    const float* b2   = (const float*)d_in[20];
    const float* ln1g = (const float*)d_in[21];
    const float* ln1b = (const float*)d_in[22];
    const float* ln2g = (const float*)d_in[23];
    const float* ln2b = (const float*)d_in[24];
    const float* Wmlp = (const float*)d_in[25];
    const float* bmlp = (const float*)d_in[26];
    const float* Wd1  = (const float*)d_in[27];
    const float* bd1  = (const float*)d_in[28];
    const float* Wd2  = (const float*)d_in[29];
    const float* bd2  = (const float*)d_in[30];

    // workspace layout (~96 MB)
    u16* h    = (u16*)d_ws;                    // 26,214,400 u16
    u16* buf  = h    + (size_t)MTOK*HD;        // 13,107,200  (qkv 12800x768 / ff1 12800x1024)
    u16* buf2 = buf  + (size_t)RCH*1024;       //  3,276,800  (12800x256 gemm out)
    u16* wq   = buf2 + (size_t)RCH*256;        //    786,432  (all 4 layers)
    u16* wo   = wq   + (size_t)4*768*256;      //    262,144
    u16* w1   = wo   + (size_t)4*256*256;      //  1,048,576
    u16* w2   = w1   + (size_t)4*1024*256;     //  1,048,576
    u16* wmT  = w2   + (size_t)4*256*1024;     //    589,824  (3 layers x 768 x 256)
    u16* zb   = wmT  + (size_t)3*768*256;      //  1,048,576
    float* fp = (float*)(zb + (size_t)BSZ*16384);
    float* m1  = fp;                           // 4096
    float* m2  = m1 + CCH*HD;                  // 4096
    float* an  = m2 + CCH*HD;                  // 256
    float* d1p = an + CCH*CCH;                 // 16*64*256 = 262144
    float* d1  = d1p + (size_t)16*64*HD;       // 16384

    // one-time weight prep
    k_cvt<<<512, 256, 0, stream>>>(Wqkv, wq, 4*768*256);
    k_cvt<<<256, 256, 0, stream>>>(Wo,   wo, 4*256*256);
    k_cvt<<<512, 256, 0, stream>>>(W1,   w1, 4*1024*256);
    k_cvt<<<512, 256, 0, stream>>>(W2,   w2, 4*256*1024);
    k_wmT<<<3*768, 256, 0, stream>>>(Wmlp, wmT);

    k_embed<<<MTOK, 256, 0, stream>>>(x, Wfc, bfc, cls, pos, h);
    k_graph_m<<<16, 256, 0, stream>>>(emb1, Wl1, bl1, m1);
    k_graph_m<<<16, 256, 0, stream>>>(emb2, Wl2, bl2, m2);
    k_graph_a<<<1, 256, 0, stream>>>(m1, m2, an);

    for (int l=0; l<NLAY; l++){
        if (l > 0)
            k_mixprop<<<BSZ*NCLS, 256, 0, stream>>>(h, an,
                wmT + (size_t)(l-1)*768*256, bmlp + (size_t)(l-1)*HD);

        for (int c=0; c<NCH; c++){
            size_t row0 = (size_t)c * RCH;
            // qkv projection: (12800x256) @ (768x256)^T -> buf
            k_gemmA<<<dim3(RCH/128, 768/128), 256, 0, stream>>>(
                h + row0*HD, HD, wq + (size_t)l*768*256, bqkv + (size_t)l*768,
                buf, 768, HD, 0);
            // attention (o -> q slot)
            k_attn<<<SCH*NHEAD/2, 256, 0, stream>>>(buf);
            // out-proj: (12800x256 [q-slot, lda=768]) @ (256x256)^T -> buf2
            k_gemmA<<<dim3(RCH/128, 256/128), 256, 0, stream>>>(
                buf, 768, wo + (size_t)l*256*256, bo + (size_t)l*HD, buf2, 256, HD, 0);
            k_ln<<<RCH/8, 256, 0, stream>>>(buf2, h,
                ln1g + (size_t)l*HD, ln1b + (size_t)l*HD, row0);
            // FF1: (12800x256) @ (1024x256)^T -> buf, relu
            k_gemmA<<<dim3(RCH/128, 1024/128), 256, 0, stream>>>(
                h + row0*HD, HD, w1 + (size_t)l*1024*256, b1 + (size_t)l*1024,
                buf, 1024, HD, 1);
            // FF2: (12800x1024) @ (256x1024)^T -> buf2
            k_gemmA<<<dim3(RCH/128, 256/128), 256, 0, stream>>>(
                buf, 1024, w2 + (size_t)l*256*1024, b2 + (size_t)l*HD, buf2, 256, 1024, 0);
            k_ln<<<RCH/8, 256, 0, stream>>>(buf2, h,
                ln2g + (size_t)l*HD, ln2b + (size_t)l*HD, row0);
        }
    }

    k_z<<<BSZ*CCH, 256, 0, stream>>>(h, zb);
    k_head1p<<<dim3(16, 16), 256, 0, stream>>>(zb, Wd1, d1p);
    k_head1r<<<64, 256, 0, stream>>>(d1p, bd1, d1);
    k_head2<<<BSZ, 64, 0, stream>>>(d1, Wd2, bd2, (float*)d_out);
}

// Round 7
// 5069.816 us; speedup vs baseline: 1.3111x; 1.0056x over previous
//
#include <hip/hip_runtime.h>
#include <hip/hip_bf16.h>
#include <math.h>

typedef unsigned short u16;
typedef unsigned int   u32;
typedef __attribute__((ext_vector_type(8))) short short8;   // 8 bf16 = 4 VGPRs
typedef __attribute__((ext_vector_type(4))) float f32x4;

// ---- model dims ----
#define BSZ   64
#define TT    96
#define CCH   16
#define INDIM 16
#define HD    256
#define NHEAD 8
#define DHEAD 32
#define NCLS  4
#define LSEQ  100      // TT + NCLS
#define NLAY  4
#define EPSV  1e-5f
#define BSEQ  (BSZ*CCH)        // 1024 sequences
#define MTOK  (BSEQ*LSEQ)      // 102400 tokens
#define NCH   8                // pipeline chunks
#define SCH   (BSEQ/NCH)       // 128 sequences per chunk
#define RCH   (MTOK/NCH)       // 12800 rows per chunk

__device__ __forceinline__ float bf2f(u16 x){ return __uint_as_float(((u32)x)<<16); }
__device__ __forceinline__ u16 f2bf(float f){
    u32 u = __float_as_uint(f);
    u32 r = (u + 0x7fffu + ((u>>16)&1u)) >> 16;
    return (u16)r;
}
__device__ __forceinline__ float lo16(u32 r){ return __uint_as_float(r<<16); }
__device__ __forceinline__ float hi16(u32 r){ return __uint_as_float(r&0xffff0000u); }

// async global->LDS, 16B per lane; LDS dest = (wave-uniform base) + lane*16
__device__ __forceinline__ void gload_lds16(const u16* g, u16* l){
    __builtin_amdgcn_global_load_lds(
        (const __attribute__((address_space(1))) unsigned int*)g,
        (__attribute__((address_space(3))) unsigned int*)l, 16, 0, 0);
}

// ---------------- f32 -> bf16 bulk convert ----------------
__global__ __launch_bounds__(256)
void k_cvt(const float* __restrict__ src, u16* __restrict__ dst, int n)
{
    for (int i = blockIdx.x*256 + threadIdx.x; i < n; i += gridDim.x*256)
        dst[i] = f2bf(src[i]);
}

// ---------------- Wmlp transpose: WmT[l][j][o] = bf16(Wmlp[l][o][j]) ----------------
__global__ __launch_bounds__(256)
void k_wmT(const float* __restrict__ Wm, u16* __restrict__ wmT)
{
    int b = blockIdx.x;           // l*768 + j
    int l = b / 768, j = b - l*768;
    int o = threadIdx.x;
    wmT[(size_t)b*256 + o] = f2bf(Wm[(size_t)(l*256 + o)*768 + j]);
}

// ---------------- embed ----------------
__global__ __launch_bounds__(256)
void k_embed(const float* __restrict__ x, const float* __restrict__ Wfc,
             const float* __restrict__ bfc, const float* __restrict__ cls,
             const float* __restrict__ pos, u16* __restrict__ h)
{
    int bid = blockIdx.x;              // s*LSEQ + l
    int s = bid / LSEQ, l = bid - s*LSEQ;
    int n = s >> 4, c = s & 15;
    int hc = threadIdx.x;
    float v;
    if (l < TT) {
        const float* xr = x + (size_t)((n*TT + l)*CCH + c)*INDIM;
        const float* wr = Wfc + hc*INDIM;
        float acc = bfc[hc];
        #pragma unroll
        for (int i=0;i<INDIM;i++) acc += xr[i] * wr[i];
        v = acc;
    } else {
        v = cls[(size_t)((l-TT)*CCH + c)*HD + hc];
    }
    v += pos[(size_t)(l*CCH + c)*HD + hc];
    h[(size_t)bid*HD + hc] = f2bf(v);
}

// ---------------- graph constructor ----------------
__global__ __launch_bounds__(256)
void k_graph_m(const float* __restrict__ emb, const float* __restrict__ Wl,
               const float* __restrict__ bl, float* __restrict__ m)
{
    int r = blockIdx.x, o = threadIdx.x;
    __shared__ float e[HD];
    e[o] = emb[r*HD + o];
    __syncthreads();
    const float* w = Wl + (size_t)o*HD;
    float acc = bl[o];
    for (int k=0;k<HD;k++) acc += e[k]*w[k];
    m[r*HD + o] = tanhf(acc);
}

__global__ __launch_bounds__(256)
void k_graph_a(const float* __restrict__ m1, const float* __restrict__ m2,
               float* __restrict__ a)
{
    int t = threadIdx.x; int v = t >> 4, w = t & 15;
    __shared__ float adj[16][17];
    float s1=0.f, s2=0.f;
    for (int k=0;k<HD;k++){
        s1 += m1[v*HD+k]*m2[w*HD+k];
        s2 += m2[v*HD+k]*m1[w*HD+k];
    }
    float g = tanhf(s1 - s2); g = g > 0.f ? g : 0.f;
    adj[v][w] = g + (v==w ? 1.f : 0.f);
    __syncthreads();
    float rs = 0.f;
    #pragma unroll
    for (int j=0;j<16;j++) rs += adj[v][j];
    a[t] = adj[v][w] / rs;
}

// ---------------- MFMA GEMM with async global->LDS staging ----------------
// BM=128, BN=128, BK=32; 256 threads = 4 waves, each 64x64 via 4x4 MFMA 16x16x32 tiles.
// LDS tiles unpadded (32 elem = 64B rows) as required by global_load_lds; bank conflicts
// broken by XOR-swizzling the 16B chunk position with ((row>>1)&3) on the global-fetch side.
__global__ __launch_bounds__(256)
void k_gemmA(const u16* __restrict__ A, int lda,
             const u16* __restrict__ W, const float* __restrict__ bias,
             u16* __restrict__ C, int ldc, int K, int relu)
{
    __shared__ u16 As[128*32];
    __shared__ u16 Ws[128*32];
    int t = threadIdx.x;
    int lane = t & 63, w = t >> 6;
    int wm = (w & 1)*64, wn = (w >> 1)*64;
    int fr = lane & 15, quad = lane >> 4;
    size_t mb = (size_t)blockIdx.x * 128;
    int nb = blockIdx.y * 128;
    int srow = lane >> 2;            // 0..15 row within the 16-row group this instr covers
    int sslot = lane & 3;            // which 16B slot this lane fills

    f32x4 acc[4][4] = {};
    for (int k0 = 0; k0 < K; k0 += 32){
        __syncthreads();   // previous compute done before DMA overwrites LDS
        #pragma unroll
        for (int i=0;i<2;i++){
            int r = w*32 + i*16 + srow;                 // tile row 0..127
            int cw = sslot ^ ((r>>1)&3);                // global chunk for this slot
            gload_lds16(&A[(mb + r)*(size_t)lda + k0 + cw*8], &As[(w*32 + i*16)*32]);
            gload_lds16(&W[(size_t)(nb + r)*K     + k0 + cw*8], &Ws[(w*32 + i*16)*32]);
        }
        __syncthreads();   // barrier drains vmcnt -> DMA complete
        short8 af[4], bf[4];
        #pragma unroll
        for (int mt=0; mt<4; mt++){
            int r = wm + mt*16 + fr;
            af[mt] = *(const short8*)&As[r*32 + ((quad ^ ((r>>1)&3))<<3)];
        }
        #pragma unroll
        for (int nt=0; nt<4; nt++){
            int r = wn + nt*16 + fr;
            bf[nt] = *(const short8*)&Ws[r*32 + ((quad ^ ((r>>1)&3))<<3)];
        }
        #pragma unroll
        for (int mt=0; mt<4; mt++)
            #pragma unroll
            for (int nt=0; nt<4; nt++)
                acc[mt][nt] = __builtin_amdgcn_mfma_f32_16x16x32_bf16(
                    af[mt], bf[nt], acc[mt][nt], 0, 0, 0);
    }
    float bb[4];
    #pragma unroll
    for (int nt=0; nt<4; nt++) bb[nt] = bias[nb + wn + nt*16 + fr];
    #pragma unroll
    for (int mt=0; mt<4; mt++){
        #pragma unroll
        for (int nt=0; nt<4; nt++){
            #pragma unroll
            for (int r=0; r<4; r++){
                float v = acc[mt][nt][r] + bb[nt];
                if (relu) v = v > 0.f ? v : 0.f;
                size_t rg = mb + wm + mt*16 + quad*4 + r;
                C[rg*(size_t)ldc + nb + wn + nt*16 + fr] = f2bf(v);
            }
        }
    }
}

// ---------------- attention: thread-per-query-row, online softmax, o -> q slot ----------------
__global__ __launch_bounds__(256)
void k_attn(u16* __restrict__ qkv)
{
    __shared__ float kf[2][3200];
    __shared__ float vf[2][3200];
    int t = threadIdx.x;
    int p = t >> 7, t2 = t & 127;
    int gp = blockIdx.x*2 + p;
    int s = gp >> 3, hh = gp & 7;
    size_t base = (size_t)s*LSEQ*768 + hh*32;
    for (int idx=t2; idx<1600; idx+=128){
        int i = idx >> 4, d2 = (idx & 15) << 1;
        u32 kk = *(const u32*)&qkv[base + (size_t)i*768 + 256 + d2];
        u32 vv = *(const u32*)&qkv[base + (size_t)i*768 + 512 + d2];
        kf[p][i*32+d2]   = lo16(kk); kf[p][i*32+d2+1] = hi16(kk);
        vf[p][i*32+d2]   = lo16(vv); vf[p][i*32+d2+1] = hi16(vv);
    }
    const float scale = 0.17677669529663687f;  // 1/sqrt(32)
    float q[32];
    int i = t2;
    if (i < LSEQ){
        const u16* qp = &qkv[base + (size_t)i*768];
        #pragma unroll
        for (int c=0;c<4;c++){
            uint4 r4 = *(const uint4*)&qp[c*8];
            u32 rr[4] = {r4.x, r4.y, r4.z, r4.w};
            #pragma unroll
            for (int j=0;j<4;j++){
                q[c*8+2*j]   = lo16(rr[j])*scale;
                q[c*8+2*j+1] = hi16(rr[j])*scale;
            }
        }
    }
    __syncthreads();
    if (i < LSEQ){
        float m = -1e30f, l = 0.f, o[32];
        #pragma unroll
        for (int d=0;d<32;d++) o[d] = 0.f;
        int jmax = (i < TT) ? i : (LSEQ-1);
        for (int j=0; j<=jmax; j++){
            const float4* kr = (const float4*)&kf[p][j*32];
            float sc = 0.f;
            #pragma unroll
            for (int c=0;c<8;c++){
                float4 kk = kr[c];
                sc += q[4*c]*kk.x + q[4*c+1]*kk.y + q[4*c+2]*kk.z + q[4*c+3]*kk.w;
            }
            float mn = fmaxf(m, sc);
            float al = __expf(m - mn);
            float pj = __expf(sc - mn);
            l = l*al + pj;
            const float4* vr = (const float4*)&vf[p][j*32];
            #pragma unroll
            for (int c=0;c<8;c++){
                float4 vv = vr[c];
                o[4*c]   = o[4*c]*al   + pj*vv.x;
                o[4*c+1] = o[4*c+1]*al + pj*vv.y;
                o[4*c+2] = o[4*c+2]*al + pj*vv.z;
                o[4*c+3] = o[4*c+3]*al + pj*vv.w;
            }
            m = mn;
        }
        float inv = 1.f/l;
        #pragma unroll
        for (int d2=0; d2<32; d2+=2){
            u32 pk = (u32)f2bf(o[d2]*inv) | ((u32)f2bf(o[d2+1]*inv) << 16);
            *(u32*)&qkv[base + (size_t)i*768 + d2] = pk;
        }
    }
}

// ---------------- residual + LayerNorm: h[row] = LN(g[row_local] + h[row]) ----------------
__global__ __launch_bounds__(256)
void k_ln(const u16* __restrict__ g, u16* __restrict__ h,
          const float* __restrict__ gam, const float* __restrict__ bet,
          size_t row0)
{
    int t = threadIdx.x;
    int rl = t >> 5, lane32 = t & 31, c8 = lane32 << 3;
    size_t lrow = (size_t)blockIdx.x*8 + rl;
    size_t grow = row0 + lrow;
    uint4 g4 = *(const uint4*)&g[lrow*HD + c8];
    uint4 h4 = *(const uint4*)&h[grow*HD + c8];
    u32 gr[4] = {g4.x,g4.y,g4.z,g4.w};
    u32 hr[4] = {h4.x,h4.y,h4.z,h4.w};
    float v[8];
    #pragma unroll
    for (int j=0;j<4;j++){
        v[2*j]   = lo16(gr[j]) + lo16(hr[j]);
        v[2*j+1] = hi16(gr[j]) + hi16(hr[j]);
    }
    float s = 0.f;
    #pragma unroll
    for (int k=0;k<8;k++) s += v[k];
    #pragma unroll
    for (int msk=1; msk<32; msk<<=1) s += __shfl_xor(s, msk, 32);
    float mean = s * (1.f/256.f);
    float vv = 0.f;
    #pragma unroll
    for (int k=0;k<8;k++){ float d = v[k]-mean; vv += d*d; }
    #pragma unroll
    for (int msk=1; msk<32; msk<<=1) vv += __shfl_xor(vv, msk, 32);
    float inv = rsqrtf(vv*(1.f/256.f) + EPSV);
    float4 g0 = *(const float4*)&gam[c8];
    float4 g1 = *(const float4*)&gam[c8+4];
    float4 b0 = *(const float4*)&bet[c8];
    float4 b1 = *(const float4*)&bet[c8+4];
    float gg[8] = {g0.x,g0.y,g0.z,g0.w,g1.x,g1.y,g1.z,g1.w};
    float bb[8] = {b0.x,b0.y,b0.z,b0.w,b1.x,b1.y,b1.z,b1.w};
    u32 out[4];
    #pragma unroll
    for (int j=0;j<4;j++){
        u16 a = f2bf((v[2*j]-mean)*inv*gg[2*j] + bb[2*j]);
        u16 b = f2bf((v[2*j+1]-mean)*inv*gg[2*j+1] + bb[2*j+1]);
        out[j] = (u32)a | ((u32)b << 16);
    }
    uint4 o4 = {out[0], out[1], out[2], out[3]};
    *(uint4*)&h[grow*HD + c8] = o4;
}

// ---------------- mixprop on cls tokens (coalesced WmT reads), in-place h ----------------
__global__ __launch_bounds__(256)
void k_mixprop(u16* __restrict__ h, const float* __restrict__ a,
               const u16* __restrict__ wmT, const float* __restrict__ bm)
{
    int n = blockIdx.x >> 2, tt = blockIdx.x & 3;
    __shared__ float xs[256][17], h1s[256][17], h2s[256][17];
    __shared__ float as[16][17];
    int t = threadIdx.x;
    as[t>>4][t&15] = a[t];
    for (int idx=t; idx<4096; idx+=256){
        int w = idx >> 8, hc = idx & 255;
        xs[hc][w] = bf2f(h[((size_t)(n*16 + w)*LSEQ + TT + tt)*HD + hc]);
    }
    __syncthreads();
    for (int idx=t; idx<4096; idx+=256){
        int v = idx & 15, hc = idx >> 4;
        float acc = 0.f;
        #pragma unroll
        for (int w=0;w<16;w++) acc += as[v][w]*xs[hc][w];
        h1s[hc][v] = acc;
    }
    __syncthreads();
    for (int idx=t; idx<4096; idx+=256){
        int v = idx & 15, hc = idx >> 4;
        float acc = 0.f;
        #pragma unroll
        for (int w=0;w<16;w++) acc += as[v][w]*h1s[hc][w];
        h2s[hc][v] = acc;
    }
    __syncthreads();
    int o = t;
    float acc[16];
    #pragma unroll
    for (int w=0;w<16;w++) acc[w] = 0.f;
    for (int hc=0; hc<256; hc++){
        float w0 = bf2f(wmT[hc*256 + o]);            // coalesced: lanes = consecutive o
        float w1 = bf2f(wmT[(256+hc)*256 + o]);
        float w2 = bf2f(wmT[(512+hc)*256 + o]);
        #pragma unroll
        for (int w=0;w<16;w++)
            acc[w] += xs[hc][w]*w0 + h1s[hc][w]*w1 + h2s[hc][w]*w2;
    }
    float bb = bm[o];
    #pragma unroll
    for (int w=0;w<16;w++)
        h[((size_t)(n*16 + w)*LSEQ + TT + tt)*HD + o] = f2bf(acc[w] + bb);
}

// ---------------- head ----------------
__global__ __launch_bounds__(256)
void k_z(const u16* __restrict__ h, u16* __restrict__ z)
{
    int bid = blockIdx.x, t = threadIdx.x;     // bid = n*16+c
    #pragma unroll
    for (int tc=0;tc<4;tc++)
        z[((size_t)bid*4 + tc)*HD + t] = f2bf(tanhf(bf2f(h[((size_t)bid*LSEQ + TT + tc)*HD + t])));
}

// head1 partial: grid (nb 0..15, kb 0..15); partial over K-chunk of 1024; Wd1 read fp32
__global__ __launch_bounds__(256)
void k_head1p(const u16* __restrict__ z, const float* __restrict__ Wd1,
              float* __restrict__ d1p)
{
    __shared__ float zch[64][137];
    __shared__ float wt[16][137];
    int t = threadIdx.x;
    int col = t & 15, rgrp = t >> 4;
    int ob = blockIdx.x * 16;
    int kb = blockIdx.y;
    float acc[4] = {0.f,0.f,0.f,0.f};
    for (int kc=0; kc<1024; kc+=128){
        int base_k = kb*1024 + kc;
        #pragma unroll
        for (int jj=0; jj<16; jj++){
            int idx = t + jj*256;
            int n = idx >> 6, k2 = (idx & 63) << 1;
            u32 r = *(const u32*)&z[(size_t)n*16384 + base_k + k2];
            zch[n][k2] = lo16(r); zch[n][k2+1] = hi16(r);
        }
        #pragma unroll
        for (int jj=0; jj<2; jj++){
            int idx = t + jj*256;
            int r = idx >> 5, k4 = (idx & 31) << 2;
            float4 w4 = *(const float4*)&Wd1[(size_t)(ob + r)*16384 + base_k + k4];
            wt[r][k4] = w4.x; wt[r][k4+1] = w4.y; wt[r][k4+2] = w4.z; wt[r][k4+3] = w4.w;
        }
        __syncthreads();
        for (int k=0;k<128;k++){
            float wv = wt[col][k];
            #pragma unroll
            for (int u=0;u<4;u++) acc[u] += zch[rgrp + 16*u][k]*wv;
        }
        __syncthreads();
    }
    #pragma unroll
    for (int u=0;u<4;u++)
        d1p[(size_t)(kb*64 + rgrp + 16*u)*HD + ob + col] = acc[u];
}

__global__ __launch_bounds__(256)
void k_head1r(const float* __restrict__ d1p, const float* __restrict__ bd1,
              float* __restrict__ d1)
{
    int e = blockIdx.x*256 + threadIdx.x;      // 16384
    int r = e >> 8, c = e & 255;
    float s = 0.f;
    #pragma unroll
    for (int kb=0; kb<16; kb++) s += d1p[(size_t)(kb*64 + r)*HD + c];
    float xx = s + bd1[c];
    float ge = 0.5f*xx*(1.f + erff(xx*0.70710678118654752f));
    d1[(size_t)r*HD + c] = ge;
}

__global__ __launch_bounds__(64)
void k_head2(const float* __restrict__ d1, const float* __restrict__ Wd2,
             const float* __restrict__ bd2, float* __restrict__ out)
{
    int n = blockIdx.x, lane = threadIdx.x;
    float p = 0.f;
    #pragma unroll
    for (int j=0;j<4;j++){
        int k = lane*4 + j;
        p += d1[(size_t)n*HD + k]*Wd2[k];
    }
    #pragma unroll
    for (int m=1;m<64;m<<=1) p += __shfl_xor(p, m, 64);
    if (lane==0) out[n] = p + bd2[0];
}

// ---------------- launch ----------------
extern "C" void kernel_launch(void* const* d_in, const int* in_sizes, int n_in,
                              void* d_out, int out_size, void* d_ws, size_t ws_size,
                              hipStream_t stream)
{
    const float* x    = (const float*)d_in[0];
    const float* Wfc  = (const float*)d_in[3];
    const float* bfc  = (const float*)d_in[4];
    const float* cls  = (const float*)d_in[5];
    const float* pos  = (const float*)d_in[6];
    const float* emb1 = (const float*)d_in[7];
    const float* emb2 = (const float*)d_in[8];
    const float* Wl1  = (const float*)d_in[9];
    const float* bl1  = (const float*)d_in[10];
    const float* Wl2  = (const float*)d_in[11];
    const float* bl2  = (const float*)d_in[12];
    const float* Wqkv = (const float*)d_in[13];
    const float* bqkv = (const float*)d_in[14];
    const float* Wo   = (const float*)d_in[15];
    const float* bo   = (const float*)d_in[16];
    const float* W1   = (const float*)d_in[17];
    const float* b1   = (const float*)d_in[18];
    const float* W2   = (const float*)d_in[19];
    const float* b2   = (const float*)d_in[20];
    const float* ln1g = (const float*)d_in[21];
    const float* ln1b = (const float*)d_in[22];
    const float* ln2g = (const float*)d_in[23];
    const float* ln2b = (const float*)d_in[24];
    const float* Wmlp = (const float*)d_in[25];
    const float* bmlp = (const float*)d_in[26];
    const float* Wd1  = (const float*)d_in[27];
    const float* bd1  = (const float*)d_in[28];
    const float* Wd2  = (const float*)d_in[29];
    const float* bd2  = (const float*)d_in[30];

    // workspace layout (~96 MB)
    u16* h    = (u16*)d_ws;                    // 26,214,400 u16
    u16* buf  = h    + (size_t)MTOK*HD;        // 13,107,200  (qkv 12800x768 / ff1 12800x1024)
    u16* buf2 = buf  + (size_t)RCH*1024;       //  3,276,800  (12800x256 gemm out)
    u16* wq   = buf2 + (size_t)RCH*256;        //    786,432  (all 4 layers)
    u16* wo   = wq   + (size_t)4*768*256;      //    262,144
    u16* w1   = wo   + (size_t)4*256*256;      //  1,048,576
    u16* w2   = w1   + (size_t)4*1024*256;     //  1,048,576
    u16* wmT  = w2   + (size_t)4*256*1024;     //    589,824  (3 layers x 768 x 256)
    u16* zb   = wmT  + (size_t)3*768*256;      //  1,048,576
    float* fp = (float*)(zb + (size_t)BSZ*16384);
    float* m1  = fp;                           // 4096
    float* m2  = m1 + CCH*HD;                  // 4096
    float* an  = m2 + CCH*HD;                  // 256
    float* d1p = an + CCH*CCH;                 // 16*64*256 = 262144
    float* d1  = d1p + (size_t)16*64*HD;       // 16384

    // one-time weight prep
    k_cvt<<<512, 256, 0, stream>>>(Wqkv, wq, 4*768*256);
    k_cvt<<<256, 256, 0, stream>>>(Wo,   wo, 4*256*256);
    k_cvt<<<512, 256, 0, stream>>>(W1,   w1, 4*1024*256);
    k_cvt<<<512, 256, 0, stream>>>(W2,   w2, 4*256*1024);
    k_wmT<<<3*768, 256, 0, stream>>>(Wmlp, wmT);

    k_embed<<<MTOK, 256, 0, stream>>>(x, Wfc, bfc, cls, pos, h);
    k_graph_m<<<16, 256, 0, stream>>>(emb1, Wl1, bl1, m1);
    k_graph_m<<<16, 256, 0, stream>>>(emb2, Wl2, bl2, m2);
    k_graph_a<<<1, 256, 0, stream>>>(m1, m2, an);

    for (int l=0; l<NLAY; l++){
        if (l > 0)
            k_mixprop<<<BSZ*NCLS, 256, 0, stream>>>(h, an,
                wmT + (size_t)(l-1)*768*256, bmlp + (size_t)(l-1)*HD);

        for (int c=0; c<NCH; c++){
            size_t row0 = (size_t)c * RCH;
            // qkv projection: (12800x256) @ (768x256)^T -> buf
            k_gemmA<<<dim3(RCH/128, 768/128), 256, 0, stream>>>(
                h + row0*HD, HD, wq + (size_t)l*768*256, bqkv + (size_t)l*768,
                buf, 768, HD, 0);
            // attention (o -> q slot)
            k_attn<<<SCH*NHEAD/2, 256, 0, stream>>>(buf);
            // out-proj: (12800x256 [q-slot, lda=768]) @ (256x256)^T -> buf2
            k_gemmA<<<dim3(RCH/128, 256/128), 256, 0, stream>>>(
                buf, 768, wo + (size_t)l*256*256, bo + (size_t)l*HD, buf2, 256, HD, 0);
            k_ln<<<RCH/8, 256, 0, stream>>>(buf2, h,
                ln1g + (size_t)l*HD, ln1b + (size_t)l*HD, row0);
            // FF1: (12800x256) @ (1024x256)^T -> buf, relu
            k_gemmA<<<dim3(RCH/128, 1024/128), 256, 0, stream>>>(
                h + row0*HD, HD, w1 + (size_t)l*1024*256, b1 + (size_t)l*1024,
                buf, 1024, HD, 1);
            // FF2: (12800x1024) @ (256x1024)^T -> buf2
            k_gemmA<<<dim3(RCH/128, 256/128), 256, 0, stream>>>(
                buf, 1024, w2 + (size_t)l*256*1024, b2 + (size_t)l*HD, buf2, 256, 1024, 0);
            k_ln<<<RCH/8, 256, 0, stream>>>(buf2, h,
                ln2g + (size_t)l*HD, ln2b + (size_t)l*HD, row0);
        }
    }

    k_z<<<BSZ*CCH, 256, 0, stream>>>(h, zb);
    k_head1p<<<dim3(16, 16), 256, 0, stream>>>(zb, Wd1, d1p);
    k_head1r<<<64, 256, 0, stream>>>(d1p, bd1, d1);
    k_head2<<<BSZ, 64, 0, stream>>>(d1, Wd2, bd2, (float*)d_out);
}

// Round 8
// 3588.466 us; speedup vs baseline: 1.8523x; 1.4128x over previous
//
#include <hip/hip_runtime.h>
#include <hip/hip_bf16.h>
#include <math.h>

typedef unsigned short u16;
typedef unsigned int   u32;
typedef __attribute__((ext_vector_type(8))) short short8;   // 8 bf16 = 4 VGPRs
typedef __attribute__((ext_vector_type(4))) float f32x4;

// ---- model dims ----
#define BSZ   64
#define TT    96
#define CCH   16
#define INDIM 16
#define HD    256
#define NHEAD 8
#define DHEAD 32
#define NCLS  4
#define LSEQ  100      // TT + NCLS
#define NLAY  4
#define EPSV  1e-5f
#define BSEQ  (BSZ*CCH)        // 1024 sequences
#define MTOK  (BSEQ*LSEQ)      // 102400 tokens

__device__ __forceinline__ float bf2f(u16 x){ return __uint_as_float(((u32)x)<<16); }
__device__ __forceinline__ u16 f2bf(float f){
    u32 u = __float_as_uint(f);
    u32 r = (u + 0x7fffu + ((u>>16)&1u)) >> 16;
    return (u16)r;
}
__device__ __forceinline__ float lo16(u32 r){ return __uint_as_float(r<<16); }
__device__ __forceinline__ float hi16(u32 r){ return __uint_as_float(r&0xffff0000u); }

// async global->LDS, 16B per lane; LDS dest = (wave-uniform base) + lane*16
__device__ __forceinline__ void gload_lds16(const u16* g, u16* l){
    __builtin_amdgcn_global_load_lds(
        (const __attribute__((address_space(1))) unsigned int*)g,
        (__attribute__((address_space(3))) unsigned int*)l, 16, 0, 0);
}

// ---------------- f32 -> bf16 bulk convert ----------------
__global__ __launch_bounds__(256)
void k_cvt(const float* __restrict__ src, u16* __restrict__ dst, int n)
{
    for (int i = blockIdx.x*256 + threadIdx.x; i < n; i += gridDim.x*256)
        dst[i] = f2bf(src[i]);
}

// ---------------- Wmlp transpose: WmT[l][j][o] = bf16(Wmlp[l][o][j]) ----------------
__global__ __launch_bounds__(256)
void k_wmT(const float* __restrict__ Wm, u16* __restrict__ wmT)
{
    int b = blockIdx.x;           // l*768 + j
    int l = b / 768, j = b - l*768;
    int o = threadIdx.x;
    wmT[(size_t)b*256 + o] = f2bf(Wm[(size_t)(l*256 + o)*768 + j]);
}

// ---------------- embed ----------------
__global__ __launch_bounds__(256)
void k_embed(const float* __restrict__ x, const float* __restrict__ Wfc,
             const float* __restrict__ bfc, const float* __restrict__ cls,
             const float* __restrict__ pos, u16* __restrict__ h)
{
    int bid = blockIdx.x;              // s*LSEQ + l
    int s = bid / LSEQ, l = bid - s*LSEQ;
    int n = s >> 4, c = s & 15;
    int hc = threadIdx.x;
    float v;
    if (l < TT) {
        const float* xr = x + (size_t)((n*TT + l)*CCH + c)*INDIM;
        const float* wr = Wfc + hc*INDIM;
        float acc = bfc[hc];
        #pragma unroll
        for (int i=0;i<INDIM;i++) acc += xr[i] * wr[i];
        v = acc;
    } else {
        v = cls[(size_t)((l-TT)*CCH + c)*HD + hc];
    }
    v += pos[(size_t)(l*CCH + c)*HD + hc];
    h[(size_t)bid*HD + hc] = f2bf(v);
}

// ---------------- graph constructor ----------------
__global__ __launch_bounds__(256)
void k_graph_m(const float* __restrict__ emb, const float* __restrict__ Wl,
               const float* __restrict__ bl, float* __restrict__ m)
{
    int r = blockIdx.x, o = threadIdx.x;
    __shared__ float e[HD];
    e[o] = emb[r*HD + o];
    __syncthreads();
    const float* w = Wl + (size_t)o*HD;
    float acc = bl[o];
    for (int k=0;k<HD;k++) acc += e[k]*w[k];
    m[r*HD + o] = tanhf(acc);
}

__global__ __launch_bounds__(256)
void k_graph_a(const float* __restrict__ m1, const float* __restrict__ m2,
               float* __restrict__ a)
{
    int t = threadIdx.x; int v = t >> 4, w = t & 15;
    __shared__ float adj[16][17];
    float s1=0.f, s2=0.f;
    for (int k=0;k<HD;k++){
        s1 += m1[v*HD+k]*m2[w*HD+k];
        s2 += m2[v*HD+k]*m1[w*HD+k];
    }
    float g = tanhf(s1 - s2); g = g > 0.f ? g : 0.f;
    adj[v][w] = g + (v==w ? 1.f : 0.f);
    __syncthreads();
    float rs = 0.f;
    #pragma unroll
    for (int j=0;j<16;j++) rs += adj[v][j];
    a[t] = adj[v][w] / rs;
}

// ---------------- MFMA GEMM with async global->LDS staging ----------------
// BM=128, BN=128, BK=32; 256 threads = 4 waves, each 64x64 via 4x4 MFMA 16x16x32 tiles.
__global__ __launch_bounds__(256)
void k_gemmA(const u16* __restrict__ A, int lda,
             const u16* __restrict__ W, const float* __restrict__ bias,
             u16* __restrict__ C, int ldc, int K, int relu)
{
    __shared__ u16 As[128*32];
    __shared__ u16 Ws[128*32];
    int t = threadIdx.x;
    int lane = t & 63, w = t >> 6;
    int wm = (w & 1)*64, wn = (w >> 1)*64;
    int fr = lane & 15, quad = lane >> 4;
    size_t mb = (size_t)blockIdx.x * 128;
    int nb = blockIdx.y * 128;
    int srow = lane >> 2;            // 0..15 row within the 16-row group this instr covers
    int sslot = lane & 3;            // which 16B slot this lane fills

    f32x4 acc[4][4] = {};
    for (int k0 = 0; k0 < K; k0 += 32){
        __syncthreads();   // previous compute done before DMA overwrites LDS
        #pragma unroll
        for (int i=0;i<2;i++){
            int r = w*32 + i*16 + srow;                 // tile row 0..127
            int cw = sslot ^ ((r>>1)&3);                // global chunk for this slot
            gload_lds16(&A[(mb + r)*(size_t)lda + k0 + cw*8], &As[(w*32 + i*16)*32]);
            gload_lds16(&W[(size_t)(nb + r)*K     + k0 + cw*8], &Ws[(w*32 + i*16)*32]);
        }
        __syncthreads();   // barrier drains vmcnt -> DMA complete
        short8 af[4], bf[4];
        #pragma unroll
        for (int mt=0; mt<4; mt++){
            int r = wm + mt*16 + fr;
            af[mt] = *(const short8*)&As[r*32 + ((quad ^ ((r>>1)&3))<<3)];
        }
        #pragma unroll
        for (int nt=0; nt<4; nt++){
            int r = wn + nt*16 + fr;
            bf[nt] = *(const short8*)&Ws[r*32 + ((quad ^ ((r>>1)&3))<<3)];
        }
        #pragma unroll
        for (int mt=0; mt<4; mt++)
            #pragma unroll
            for (int nt=0; nt<4; nt++)
                acc[mt][nt] = __builtin_amdgcn_mfma_f32_16x16x32_bf16(
                    af[mt], bf[nt], acc[mt][nt], 0, 0, 0);
    }
    float bb[4];
    #pragma unroll
    for (int nt=0; nt<4; nt++) bb[nt] = bias[nb + wn + nt*16 + fr];
    #pragma unroll
    for (int mt=0; mt<4; mt++){
        #pragma unroll
        for (int nt=0; nt<4; nt++){
            #pragma unroll
            for (int r=0; r<4; r++){
                float v = acc[mt][nt][r] + bb[nt];
                if (relu) v = v > 0.f ? v : 0.f;
                size_t rg = mb + wm + mt*16 + quad*4 + r;
                C[rg*(size_t)ldc + nb + wn + nt*16 + fr] = f2bf(v);
            }
        }
    }
}

// ---------------- attention: thread-per-query-row, online softmax, o -> q slot ----------------
__global__ __launch_bounds__(256)
void k_attn(u16* __restrict__ qkv)
{
    __shared__ float kf[2][3200];
    __shared__ float vf[2][3200];
    int t = threadIdx.x;
    int p = t >> 7, t2 = t & 127;
    int gp = blockIdx.x*2 + p;
    int s = gp >> 3, hh = gp & 7;
    size_t base = (size_t)s*LSEQ*768 + hh*32;
    for (int idx=t2; idx<1600; idx+=128){
        int i = idx >> 4, d2 = (idx & 15) << 1;
        u32 kk = *(const u32*)&qkv[base + (size_t)i*768 + 256 + d2];
        u32 vv = *(const u32*)&qkv[base + (size_t)i*768 + 512 + d2];
        kf[p][i*32+d2]   = lo16(kk); kf[p][i*32+d2+1] = hi16(kk);
        vf[p][i*32+d2]   = lo16(vv); vf[p][i*32+d2+1] = hi16(vv);
    }
    const float scale = 0.17677669529663687f;  // 1/sqrt(32)
    float q[32];
    int i = t2;
    if (i < LSEQ){
        const u16* qp = &qkv[base + (size_t)i*768];
        #pragma unroll
        for (int c=0;c<4;c++){
            uint4 r4 = *(const uint4*)&qp[c*8];
            u32 rr[4] = {r4.x, r4.y, r4.z, r4.w};
            #pragma unroll
            for (int j=0;j<4;j++){
                q[c*8+2*j]   = lo16(rr[j])*scale;
                q[c*8+2*j+1] = hi16(rr[j])*scale;
            }
        }
    }
    __syncthreads();
    if (i < LSEQ){
        float m = -1e30f, l = 0.f, o[32];
        #pragma unroll
        for (int d=0;d<32;d++) o[d] = 0.f;
        int jmax = (i < TT) ? i : (LSEQ-1);
        for (int j=0; j<=jmax; j++){
            const float4* kr = (const float4*)&kf[p][j*32];
            float sc = 0.f;
            #pragma unroll
            for (int c=0;c<8;c++){
                float4 kk = kr[c];
                sc += q[4*c]*kk.x + q[4*c+1]*kk.y + q[4*c+2]*kk.z + q[4*c+3]*kk.w;
            }
            float mn = fmaxf(m, sc);
            float al = __expf(m - mn);
            float pj = __expf(sc - mn);
            l = l*al + pj;
            const float4* vr = (const float4*)&vf[p][j*32];
            #pragma unroll
            for (int c=0;c<8;c++){
                float4 vv = vr[c];
                o[4*c]   = o[4*c]*al   + pj*vv.x;
                o[4*c+1] = o[4*c+1]*al + pj*vv.y;
                o[4*c+2] = o[4*c+2]*al + pj*vv.z;
                o[4*c+3] = o[4*c+3]*al + pj*vv.w;
            }
            m = mn;
        }
        float inv = 1.f/l;
        #pragma unroll
        for (int d2=0; d2<32; d2+=2){
            u32 pk = (u32)f2bf(o[d2]*inv) | ((u32)f2bf(o[d2+1]*inv) << 16);
            *(u32*)&qkv[base + (size_t)i*768 + d2] = pk;
        }
    }
}

// ---------------- residual + LayerNorm: h[row] = LN(g[row_local] + h[row]) ----------------
__global__ __launch_bounds__(256)
void k_ln(const u16* __restrict__ g, u16* __restrict__ h,
          const float* __restrict__ gam, const float* __restrict__ bet,
          size_t row0)
{
    int t = threadIdx.x;
    int rl = t >> 5, lane32 = t & 31, c8 = lane32 << 3;
    size_t lrow = (size_t)blockIdx.x*8 + rl;
    size_t grow = row0 + lrow;
    uint4 g4 = *(const uint4*)&g[lrow*HD + c8];
    uint4 h4 = *(const uint4*)&h[grow*HD + c8];
    u32 gr[4] = {g4.x,g4.y,g4.z,g4.w};
    u32 hr[4] = {h4.x,h4.y,h4.z,h4.w};
    float v[8];
    #pragma unroll
    for (int j=0;j<4;j++){
        v[2*j]   = lo16(gr[j]) + lo16(hr[j]);
        v[2*j+1] = hi16(gr[j]) + hi16(hr[j]);
    }
    float s = 0.f;
    #pragma unroll
    for (int k=0;k<8;k++) s += v[k];
    #pragma unroll
    for (int msk=1; msk<32; msk<<=1) s += __shfl_xor(s, msk, 32);
    float mean = s * (1.f/256.f);
    float vv = 0.f;
    #pragma unroll
    for (int k=0;k<8;k++){ float d = v[k]-mean; vv += d*d; }
    #pragma unroll
    for (int msk=1; msk<32; msk<<=1) vv += __shfl_xor(vv, msk, 32);
    float inv = rsqrtf(vv*(1.f/256.f) + EPSV);
    float4 g0 = *(const float4*)&gam[c8];
    float4 g1 = *(const float4*)&gam[c8+4];
    float4 b0 = *(const float4*)&bet[c8];
    float4 b1 = *(const float4*)&bet[c8+4];
    float gg[8] = {g0.x,g0.y,g0.z,g0.w,g1.x,g1.y,g1.z,g1.w};
    float bb[8] = {b0.x,b0.y,b0.z,b0.w,b1.x,b1.y,b1.z,b1.w};
    u32 out[4];
    #pragma unroll
    for (int j=0;j<4;j++){
        u16 a = f2bf((v[2*j]-mean)*inv*gg[2*j] + bb[2*j]);
        u16 b = f2bf((v[2*j+1]-mean)*inv*gg[2*j+1] + bb[2*j+1]);
        out[j] = (u32)a | ((u32)b << 16);
    }
    uint4 o4 = {out[0], out[1], out[2], out[3]};
    *(uint4*)&h[grow*HD + c8] = o4;
}

// ---------------- mixprop on cls tokens (coalesced WmT reads), in-place h ----------------
__global__ __launch_bounds__(256)
void k_mixprop(u16* __restrict__ h, const float* __restrict__ a,
               const u16* __restrict__ wmT, const float* __restrict__ bm)
{
    int n = blockIdx.x >> 2, tt = blockIdx.x & 3;
    __shared__ float xs[256][17], h1s[256][17], h2s[256][17];
    __shared__ float as[16][17];
    int t = threadIdx.x;
    as[t>>4][t&15] = a[t];
    for (int idx=t; idx<4096; idx+=256){
        int w = idx >> 8, hc = idx & 255;
        xs[hc][w] = bf2f(h[((size_t)(n*16 + w)*LSEQ + TT + tt)*HD + hc]);
    }
    __syncthreads();
    for (int idx=t; idx<4096; idx+=256){
        int v = idx & 15, hc = idx >> 4;
        float acc = 0.f;
        #pragma unroll
        for (int w=0;w<16;w++) acc += as[v][w]*xs[hc][w];
        h1s[hc][v] = acc;
    }
    __syncthreads();
    for (int idx=t; idx<4096; idx+=256){
        int v = idx & 15, hc = idx >> 4;
        float acc = 0.f;
        #pragma unroll
        for (int w=0;w<16;w++) acc += as[v][w]*h1s[hc][w];
        h2s[hc][v] = acc;
    }
    __syncthreads();
    int o = t;
    float acc[16];
    #pragma unroll
    for (int w=0;w<16;w++) acc[w] = 0.f;
    for (int hc=0; hc<256; hc++){
        float w0 = bf2f(wmT[hc*256 + o]);            // coalesced: lanes = consecutive o
        float w1 = bf2f(wmT[(256+hc)*256 + o]);
        float w2 = bf2f(wmT[(512+hc)*256 + o]);
        #pragma unroll
        for (int w=0;w<16;w++)
            acc[w] += xs[hc][w]*w0 + h1s[hc][w]*w1 + h2s[hc][w]*w2;
    }
    float bb = bm[o];
    #pragma unroll
    for (int w=0;w<16;w++)
        h[((size_t)(n*16 + w)*LSEQ + TT + tt)*HD + o] = f2bf(acc[w] + bb);
}

// ---------------- head ----------------
__global__ __launch_bounds__(256)
void k_z(const u16* __restrict__ h, u16* __restrict__ z)
{
    int bid = blockIdx.x, t = threadIdx.x;     // bid = n*16+c
    #pragma unroll
    for (int tc=0;tc<4;tc++)
        z[((size_t)bid*4 + tc)*HD + t] = f2bf(tanhf(bf2f(h[((size_t)bid*LSEQ + TT + tc)*HD + t])));
}

// head1 partial: grid (nb 0..15, kb 0..15); partial over K-chunk of 1024; Wd1 read fp32
__global__ __launch_bounds__(256)
void k_head1p(const u16* __restrict__ z, const float* __restrict__ Wd1,
              float* __restrict__ d1p)
{
    __shared__ float zch[64][137];
    __shared__ float wt[16][137];
    int t = threadIdx.x;
    int col = t & 15, rgrp = t >> 4;
    int ob = blockIdx.x * 16;
    int kb = blockIdx.y;
    float acc[4] = {0.f,0.f,0.f,0.f};
    for (int kc=0; kc<1024; kc+=128){
        int base_k = kb*1024 + kc;
        #pragma unroll
        for (int jj=0; jj<16; jj++){
            int idx = t + jj*256;
            int n = idx >> 6, k2 = (idx & 63) << 1;
            u32 r = *(const u32*)&z[(size_t)n*16384 + base_k + k2];
            zch[n][k2] = lo16(r); zch[n][k2+1] = hi16(r);
        }
        #pragma unroll
        for (int jj=0; jj<2; jj++){
            int idx = t + jj*256;
            int r = idx >> 5, k4 = (idx & 31) << 2;
            float4 w4 = *(const float4*)&Wd1[(size_t)(ob + r)*16384 + base_k + k4];
            wt[r][k4] = w4.x; wt[r][k4+1] = w4.y; wt[r][k4+2] = w4.z; wt[r][k4+3] = w4.w;
        }
        __syncthreads();
        for (int k=0;k<128;k++){
            float wv = wt[col][k];
            #pragma unroll
            for (int u=0;u<4;u++) acc[u] += zch[rgrp + 16*u][k]*wv;
        }
        __syncthreads();
    }
    #pragma unroll
    for (int u=0;u<4;u++)
        d1p[(size_t)(kb*64 + rgrp + 16*u)*HD + ob + col] = acc[u];
}

// fused: reduce d1p partials -> GELU -> dot with Wd2 -> out (one block per sample)
__global__ __launch_bounds__(256)
void k_headf(const float* __restrict__ d1p, const float* __restrict__ bd1,
             const float* __restrict__ Wd2, const float* __restrict__ bd2,
             float* __restrict__ out)
{
    __shared__ float red[4];
    int n = blockIdx.x, c = threadIdx.x;
    float s = 0.f;
    #pragma unroll
    for (int kb=0; kb<16; kb++) s += d1p[(size_t)(kb*64 + n)*HD + c];
    float xx = s + bd1[c];
    float ge = 0.5f*xx*(1.f + erff(xx*0.70710678118654752f));
    float p = ge * Wd2[c];
    #pragma unroll
    for (int m=1;m<64;m<<=1) p += __shfl_xor(p, m, 64);
    if ((c & 63) == 0) red[c >> 6] = p;
    __syncthreads();
    if (c == 0) out[n] = red[0]+red[1]+red[2]+red[3] + bd2[0];
}

// ---------------- launch ----------------
extern "C" void kernel_launch(void* const* d_in, const int* in_sizes, int n_in,
                              void* d_out, int out_size, void* d_ws, size_t ws_size,
                              hipStream_t stream)
{
    const float* x    = (const float*)d_in[0];
    const float* Wfc  = (const float*)d_in[3];
    const float* bfc  = (const float*)d_in[4];
    const float* cls  = (const float*)d_in[5];
    const float* pos  = (const float*)d_in[6];
    const float* emb1 = (const float*)d_in[7];
    const float* emb2 = (const float*)d_in[8];
    const float* Wl1  = (const float*)d_in[9];
    const float* bl1  = (const float*)d_in[10];
    const float* Wl2  = (const float*)d_in[11];
    const float* bl2  = (const float*)d_in[12];
    const float* Wqkv = (const float*)d_in[13];
    const float* bqkv = (const float*)d_in[14];
    const float* Wo   = (const float*)d_in[15];
    const float* bo   = (const float*)d_in[16];
    const float* W1   = (const float*)d_in[17];
    const float* b1   = (const float*)d_in[18];
    const float* W2   = (const float*)d_in[19];
    const float* b2   = (const float*)d_in[20];
    const float* ln1g = (const float*)d_in[21];
    const float* ln1b = (const float*)d_in[22];
    const float* ln2g = (const float*)d_in[23];
    const float* ln2b = (const float*)d_in[24];
    const float* Wmlp = (const float*)d_in[25];
    const float* bmlp = (const float*)d_in[26];
    const float* Wd1  = (const float*)d_in[27];
    const float* bd1  = (const float*)d_in[28];
    const float* Wd2  = (const float*)d_in[29];
    const float* bd2  = (const float*)d_in[30];

    // dynamic chunk selection: bytes(NCH) = fixed + RCH*2560; pick smallest NCH that fits
    int NCH = 8;
    {
        const size_t fixed = 63145088 + (1<<20);   // buffers below + 1MB slack
        if      (fixed + (size_t)MTOK    *2560 <= ws_size) NCH = 1;
        else if (fixed + (size_t)(MTOK/2)*2560 <= ws_size) NCH = 2;
        else if (fixed + (size_t)(MTOK/4)*2560 <= ws_size) NCH = 4;
    }
    const int RCH = MTOK / NCH;        // rows per chunk
    const int SCH = BSEQ / NCH;        // sequences per chunk

    // workspace layout
    u16* h    = (u16*)d_ws;                    // 26,214,400 u16
    u16* buf  = h    + (size_t)MTOK*HD;        // RCH*1024  (qkv / ff1 hidden)
    u16* buf2 = buf  + (size_t)RCH*1024;       // RCH*256   (gemm out)
    u16* wq   = buf2 + (size_t)RCH*256;        //    786,432  (all 4 layers)
    u16* wo   = wq   + (size_t)4*768*256;      //    262,144
    u16* w1   = wo   + (size_t)4*256*256;      //  1,048,576
    u16* w2   = w1   + (size_t)4*1024*256;     //  1,048,576
    u16* wmT  = w2   + (size_t)4*256*1024;     //    589,824  (3 layers x 768 x 256)
    u16* zb   = wmT  + (size_t)3*768*256;      //  1,048,576
    float* fp = (float*)(zb + (size_t)BSZ*16384);
    float* m1  = fp;                           // 4096
    float* m2  = m1 + CCH*HD;                  // 4096
    float* an  = m2 + CCH*HD;                  // 256
    float* d1p = an + CCH*CCH;                 // 16*64*256 = 262144
    // (d1 no longer needed: k_headf fuses reduce+gelu+dot)

    // one-time weight prep
    k_cvt<<<512, 256, 0, stream>>>(Wqkv, wq, 4*768*256);
    k_cvt<<<256, 256, 0, stream>>>(Wo,   wo, 4*256*256);
    k_cvt<<<512, 256, 0, stream>>>(W1,   w1, 4*1024*256);
    k_cvt<<<512, 256, 0, stream>>>(W2,   w2, 4*256*1024);
    k_wmT<<<3*768, 256, 0, stream>>>(Wmlp, wmT);

    k_embed<<<MTOK, 256, 0, stream>>>(x, Wfc, bfc, cls, pos, h);
    k_graph_m<<<16, 256, 0, stream>>>(emb1, Wl1, bl1, m1);
    k_graph_m<<<16, 256, 0, stream>>>(emb2, Wl2, bl2, m2);
    k_graph_a<<<1, 256, 0, stream>>>(m1, m2, an);

    for (int l=0; l<NLAY; l++){
        if (l > 0)
            k_mixprop<<<BSZ*NCLS, 256, 0, stream>>>(h, an,
                wmT + (size_t)(l-1)*768*256, bmlp + (size_t)(l-1)*HD);

        for (int c=0; c<NCH; c++){
            size_t row0 = (size_t)c * RCH;
            // qkv projection: (RCH x 256) @ (768x256)^T -> buf
            k_gemmA<<<dim3(RCH/128, 768/128), 256, 0, stream>>>(
                h + row0*HD, HD, wq + (size_t)l*768*256, bqkv + (size_t)l*768,
                buf, 768, HD, 0);
            // attention (o -> q slot)
            k_attn<<<SCH*NHEAD/2, 256, 0, stream>>>(buf);
            // out-proj: (RCH x 256 [q-slot, lda=768]) @ (256x256)^T -> buf2
            k_gemmA<<<dim3(RCH/128, 256/128), 256, 0, stream>>>(
                buf, 768, wo + (size_t)l*256*256, bo + (size_t)l*HD, buf2, 256, HD, 0);
            k_ln<<<RCH/8, 256, 0, stream>>>(buf2, h,
                ln1g + (size_t)l*HD, ln1b + (size_t)l*HD, row0);
            // FF1: (RCH x 256) @ (1024x256)^T -> buf, relu
            k_gemmA<<<dim3(RCH/128, 1024/128), 256, 0, stream>>>(
                h + row0*HD, HD, w1 + (size_t)l*1024*256, b1 + (size_t)l*1024,
                buf, 1024, HD, 1);
            // FF2: (RCH x 1024) @ (256x1024)^T -> buf2
            k_gemmA<<<dim3(RCH/128, 256/128), 256, 0, stream>>>(
                buf, 1024, w2 + (size_t)l*256*1024, b2 + (size_t)l*HD, buf2, 256, 1024, 0);
            k_ln<<<RCH/8, 256, 0, stream>>>(buf2, h,
                ln2g + (size_t)l*HD, ln2b + (size_t)l*HD, row0);
        }
    }

    k_z<<<BSZ*CCH, 256, 0, stream>>>(h, zb);
    k_head1p<<<dim3(16, 16), 256, 0, stream>>>(zb, Wd1, d1p);
    k_headf<<<BSZ, 256, 0, stream>>>(d1p, bd1, Wd2, bd2, (float*)d_out);
}

// Round 11
// 2584.511 us; speedup vs baseline: 2.5718x; 1.3885x over previous
//
#include <hip/hip_runtime.h>
#include <hip/hip_bf16.h>
#include <math.h>

typedef unsigned short u16;
typedef unsigned int   u32;
typedef __attribute__((ext_vector_type(8))) short short8;   // 8 bf16 = 4 VGPRs
typedef __attribute__((ext_vector_type(4))) float f32x4;

// ---- model dims ----
#define BSZ   64
#define TT    96
#define CCH   16
#define INDIM 16
#define HD    256
#define NHEAD 8
#define DHEAD 32
#define NCLS  4
#define LSEQ  100      // TT + NCLS
#define NLAY  4
#define EPSV  1e-5f
#define BSEQ  (BSZ*CCH)        // 1024 sequences
#define MTOK  (BSEQ*LSEQ)      // 102400 tokens

__device__ __forceinline__ float bf2f(u16 x){ return __uint_as_float(((u32)x)<<16); }
__device__ __forceinline__ u16 f2bf(float f){
    u32 u = __float_as_uint(f);
    u32 r = (u + 0x7fffu + ((u>>16)&1u)) >> 16;
    return (u16)r;
}
__device__ __forceinline__ float lo16(u32 r){ return __uint_as_float(r<<16); }
__device__ __forceinline__ float hi16(u32 r){ return __uint_as_float(r&0xffff0000u); }

// async global->LDS, 16B per lane; LDS dest = (wave-uniform base) + lane*16
__device__ __forceinline__ void gload_lds16(const u16* g, u16* l){
    __builtin_amdgcn_global_load_lds(
        (const __attribute__((address_space(1))) unsigned int*)g,
        (__attribute__((address_space(3))) unsigned int*)l, 16, 0, 0);
}

// ---------------- f32 -> bf16 bulk convert ----------------
__global__ __launch_bounds__(256)
void k_cvt(const float* __restrict__ src, u16* __restrict__ dst, int n)
{
    for (int i = blockIdx.x*256 + threadIdx.x; i < n; i += gridDim.x*256)
        dst[i] = f2bf(src[i]);
}

// ---------------- Wmlp transpose: WmT[l][j][o] = bf16(Wmlp[l][o][j]) ----------------
__global__ __launch_bounds__(256)
void k_wmT(const float* __restrict__ Wm, u16* __restrict__ wmT)
{
    int b = blockIdx.x;           // l*768 + j
    int l = b / 768, j = b - l*768;
    int o = threadIdx.x;
    wmT[(size_t)b*256 + o] = f2bf(Wm[(size_t)(l*256 + o)*768 + j]);
}

// ---------------- embed ----------------
__global__ __launch_bounds__(256)
void k_embed(const float* __restrict__ x, const float* __restrict__ Wfc,
             const float* __restrict__ bfc, const float* __restrict__ cls,
             const float* __restrict__ pos, u16* __restrict__ h)
{
    int bid = blockIdx.x;              // s*LSEQ + l
    int s = bid / LSEQ, l = bid - s*LSEQ;
    int n = s >> 4, c = s & 15;
    int hc = threadIdx.x;
    float v;
    if (l < TT) {
        const float* xr = x + (size_t)((n*TT + l)*CCH + c)*INDIM;
        const float* wr = Wfc + hc*INDIM;
        float acc = bfc[hc];
        #pragma unroll
        for (int i=0;i<INDIM;i++) acc += xr[i] * wr[i];
        v = acc;
    } else {
        v = cls[(size_t)((l-TT)*CCH + c)*HD + hc];
    }
    v += pos[(size_t)(l*CCH + c)*HD + hc];
    h[(size_t)bid*HD + hc] = f2bf(v);
}

// ---------------- graph constructor ----------------
__global__ __launch_bounds__(256)
void k_graph_m(const float* __restrict__ emb, const float* __restrict__ Wl,
               const float* __restrict__ bl, float* __restrict__ m)
{
    int r = blockIdx.x, o = threadIdx.x;
    __shared__ float e[HD];
    e[o] = emb[r*HD + o];
    __syncthreads();
    const float* w = Wl + (size_t)o*HD;
    float acc = bl[o];
    for (int k=0;k<HD;k++) acc += e[k]*w[k];
    m[r*HD + o] = tanhf(acc);
}

__global__ __launch_bounds__(256)
void k_graph_a(const float* __restrict__ m1, const float* __restrict__ m2,
               float* __restrict__ a)
{
    int t = threadIdx.x; int v = t >> 4, w = t & 15;
    __shared__ float adj[16][17];
    float s1=0.f, s2=0.f;
    for (int k=0;k<HD;k++){
        s1 += m1[v*HD+k]*m2[w*HD+k];
        s2 += m2[v*HD+k]*m1[w*HD+k];
    }
    float g = tanhf(s1 - s2); g = g > 0.f ? g : 0.f;
    adj[v][w] = g + (v==w ? 1.f : 0.f);
    __syncthreads();
    float rs = 0.f;
    #pragma unroll
    for (int j=0;j<16;j++) rs += adj[v][j];
    a[t] = adj[v][w] / rs;
}

// ---------------- MFMA GEMM with async global->LDS staging ----------------
__global__ __launch_bounds__(256)
void k_gemmA(const u16* __restrict__ A, int lda,
             const u16* __restrict__ W, const float* __restrict__ bias,
             u16* __restrict__ C, int ldc, int K, int relu)
{
    __shared__ u16 As[128*32];
    __shared__ u16 Ws[128*32];
    int t = threadIdx.x;
    int lane = t & 63, w = t >> 6;
    int wm = (w & 1)*64, wn = (w >> 1)*64;
    int fr = lane & 15, quad = lane >> 4;
    size_t mb = (size_t)blockIdx.x * 128;
    int nb = blockIdx.y * 128;
    int srow = lane >> 2;
    int sslot = lane & 3;

    f32x4 acc[4][4] = {};
    for (int k0 = 0; k0 < K; k0 += 32){
        __syncthreads();
        #pragma unroll
        for (int i=0;i<2;i++){
            int r = w*32 + i*16 + srow;
            int cw = sslot ^ ((r>>1)&3);
            gload_lds16(&A[(mb + r)*(size_t)lda + k0 + cw*8], &As[(w*32 + i*16)*32]);
            gload_lds16(&W[(size_t)(nb + r)*K     + k0 + cw*8], &Ws[(w*32 + i*16)*32]);
        }
        __syncthreads();
        short8 af[4], bf[4];
        #pragma unroll
        for (int mt=0; mt<4; mt++){
            int r = wm + mt*16 + fr;
            af[mt] = *(const short8*)&As[r*32 + ((quad ^ ((r>>1)&3))<<3)];
        }
        #pragma unroll
        for (int nt=0; nt<4; nt++){
            int r = wn + nt*16 + fr;
            bf[nt] = *(const short8*)&Ws[r*32 + ((quad ^ ((r>>1)&3))<<3)];
        }
        #pragma unroll
        for (int mt=0; mt<4; mt++)
            #pragma unroll
            for (int nt=0; nt<4; nt++)
                acc[mt][nt] = __builtin_amdgcn_mfma_f32_16x16x32_bf16(
                    af[mt], bf[nt], acc[mt][nt], 0, 0, 0);
    }
    float bb[4];
    #pragma unroll
    for (int nt=0; nt<4; nt++) bb[nt] = bias[nb + wn + nt*16 + fr];
    #pragma unroll
    for (int mt=0; mt<4; mt++){
        #pragma unroll
        for (int nt=0; nt<4; nt++){
            #pragma unroll
            for (int r=0; r<4; r++){
                float v = acc[mt][nt][r] + bb[nt];
                if (relu) v = v > 0.f ? v : 0.f;
                size_t rg = mb + wm + mt*16 + quad*4 + r;
                C[rg*(size_t)ldc + nb + wn + nt*16 + fr] = f2bf(v);
            }
        }
    }
}

// ---------------- MFMA attention: 2 (seq,head) pairs per block, 2 waves per pair ----------------
// S = Q K^T via MFMA; softmax fp32 in C-layout regs; PV via split-P (hi+lo bf16) two-pass MFMA
// so P retains ~fp32 precision. Vt staged for full 128-key range (>=LSEQ zeroed). o -> q slot.
#define KS_STR 40
#define VT_STR 136
#define PL_STR 136
__global__ __launch_bounds__(256)
void k_attn(u16* __restrict__ qkv)
{
    __shared__ u16 smem[26368];          // Ks 2x4480 | Vt 2x4352 | Pl 4x2176 (u16 counts)
    int t = threadIdx.x;
    int w = t >> 6, lane = t & 63;
    int fr = lane & 15, quad = lane >> 4;
    int p = t >> 7, t2 = t & 127;        // staging: half-block per pair
    u16* Ks = smem + p*4480;
    u16* Vt = smem + 8960 + p*4352;
    u16* Pl = smem + 17664 + w*2176;

    // staging
    {
        int gp = blockIdx.x*2 + p;
        size_t base = (size_t)(gp >> 3)*LSEQ*768 + (gp & 7)*32;
        // K rows: 112 keys x 32 d (keys >= LSEQ zero)
        for (int idx = t2; idx < 1792; idx += 128){
            int key = idx >> 4, d2 = (idx & 15) << 1;
            u32 kv = (key < LSEQ) ? *(const u32*)&qkv[base + (size_t)key*768 + 256 + d2] : 0u;
            *(u32*)&Ks[key*KS_STR + d2] = kv;
        }
        // V transposed: 32 d x 128 keys (keys >= LSEQ zero — PV reads keys up to 127)
        for (int idx = t2; idx < 2048; idx += 128){
            int key = idx >> 4, d2 = (idx & 15) << 1;
            u32 vv = (key < LSEQ) ? *(const u32*)&qkv[base + (size_t)key*768 + 512 + d2] : 0u;
            Vt[ d2   *VT_STR + key] = (u16)(vv & 0xffffu);
            Vt[(d2+1)*VT_STR + key] = (u16)(vv >> 16);
        }
    }
    __syncthreads();

    // per-wave pair
    int wp = w >> 1;
    int gp = blockIdx.x*2 + wp;
    size_t base = (size_t)(gp >> 3)*LSEQ*768 + (gp & 7)*32;
    u16* Ksw = smem + wp*4480;
    u16* Vtw = smem + 8960 + wp*4352;

    // hoist K and V fragments
    short8 kf[7];
    #pragma unroll
    for (int nt=0; nt<7; nt++)
        kf[nt] = *(const short8*)&Ksw[(nt*16 + fr)*KS_STR + quad*8];
    short8 vfr[4][2];
    #pragma unroll
    for (int ks=0; ks<4; ks++)
        #pragma unroll
        for (int nt=0; nt<2; nt++)
            vfr[ks][nt] = *(const short8*)&Vtw[(nt*16 + fr)*VT_STR + ks*32 + quad*8];

    const float scale = 0.17677669529663687f;  // 1/sqrt(32)
    int st0 = (w & 1) ? 4 : 0, st1 = (w & 1) ? 7 : 4;
    for (int st = st0; st < st1; ++st){
        int q = st*16 + fr;
        short8 qf = {};
        if (q < LSEQ) qf = *(const short8*)&qkv[base + (size_t)q*768 + quad*8];
        f32x4 S[7];
        #pragma unroll
        for (int nt=0; nt<7; nt++){
            f32x4 z = {};
            S[nt] = __builtin_amdgcn_mfma_f32_16x16x32_bf16(qf, kf[nt], z, 0,0,0);
        }
        float mx[4] = {-1e30f,-1e30f,-1e30f,-1e30f};
        #pragma unroll
        for (int r=0;r<4;r++){
            int qr = st*16 + quad*4 + r;
            int jmax = (qr < TT) ? qr : (LSEQ-1);
            #pragma unroll
            for (int nt=0;nt<7;nt++){
                int j = nt*16 + fr;
                float s = (j <= jmax) ? S[nt][r]*scale : -1e30f;
                S[nt][r] = s;
                mx[r] = fmaxf(mx[r], s);
            }
        }
        #pragma unroll
        for (int r=0;r<4;r++){
            #pragma unroll
            for (int m=1;m<16;m<<=1) mx[r] = fmaxf(mx[r], __shfl_xor(mx[r], m, 64));
        }
        float l4[4] = {0.f,0.f,0.f,0.f};
        #pragma unroll
        for (int r=0;r<4;r++){
            #pragma unroll
            for (int nt=0;nt<7;nt++){
                float pv = __expf(S[nt][r] - mx[r]);
                S[nt][r] = pv;
                l4[r] += pv;
            }
        }
        #pragma unroll
        for (int r=0;r<4;r++){
            #pragma unroll
            for (int m=1;m<16;m<<=1) l4[r] += __shfl_xor(l4[r], m, 64);
        }
        // pass 1: P_hi = bf16(P); keep residual in S for pass 2
        #pragma unroll
        for (int nt=0;nt<7;nt++)
            #pragma unroll
            for (int r=0;r<4;r++){
                u16 hb = f2bf(S[nt][r]);
                Pl[(quad*4+r)*PL_STR + nt*16 + fr] = hb;
                S[nt][r] -= bf2f(hb);      // exact fp32 residual
            }
        #pragma unroll
        for (int r=0;r<4;r++)
            Pl[(quad*4+r)*PL_STR + 112 + fr] = 0;
        __builtin_amdgcn_s_waitcnt(0);   // drain ds writes before cross-lane P reads
        f32x4 D[2] = {};
        #pragma unroll
        for (int ks=0; ks<4; ks++){
            short8 pf = *(const short8*)&Pl[fr*PL_STR + ks*32 + quad*8];
            #pragma unroll
            for (int nt=0; nt<2; nt++)
                D[nt] = __builtin_amdgcn_mfma_f32_16x16x32_bf16(pf, vfr[ks][nt], D[nt], 0,0,0);
        }
        __builtin_amdgcn_s_waitcnt(0);   // P_hi reads done before overwrite
        // pass 2: P_lo accumulated into same D (pad cols still zero)
        #pragma unroll
        for (int nt=0;nt<7;nt++)
            #pragma unroll
            for (int r=0;r<4;r++)
                Pl[(quad*4+r)*PL_STR + nt*16 + fr] = f2bf(S[nt][r]);
        __builtin_amdgcn_s_waitcnt(0);
        #pragma unroll
        for (int ks=0; ks<4; ks++){
            short8 pf = *(const short8*)&Pl[fr*PL_STR + ks*32 + quad*8];
            #pragma unroll
            for (int nt=0; nt<2; nt++)
                D[nt] = __builtin_amdgcn_mfma_f32_16x16x32_bf16(pf, vfr[ks][nt], D[nt], 0,0,0);
        }
        #pragma unroll
        for (int r=0;r<4;r++){
            int qr = st*16 + quad*4 + r;
            if (qr < LSEQ){
                float inv = 1.f / l4[r];
                #pragma unroll
                for (int nt=0; nt<2; nt++)
                    qkv[base + (size_t)qr*768 + nt*16 + fr] = f2bf(D[nt][r]*inv);
            }
        }
        __builtin_amdgcn_s_waitcnt(0);   // P reads done before next strip overwrites
    }
}

// ---------------- residual + LayerNorm: h[row] = LN(g[row_local] + h[row]) ----------------
__global__ __launch_bounds__(256)
void k_ln(const u16* __restrict__ g, u16* __restrict__ h,
          const float* __restrict__ gam, const float* __restrict__ bet,
          size_t row0)
{
    int t = threadIdx.x;
    int rl = t >> 5, lane32 = t & 31, c8 = lane32 << 3;
    size_t lrow = (size_t)blockIdx.x*8 + rl;
    size_t grow = row0 + lrow;
    uint4 g4 = *(const uint4*)&g[lrow*HD + c8];
    uint4 h4 = *(const uint4*)&h[grow*HD + c8];
    u32 gr[4] = {g4.x,g4.y,g4.z,g4.w};
    u32 hr[4] = {h4.x,h4.y,h4.z,h4.w};
    float v[8];
    #pragma unroll
    for (int j=0;j<4;j++){
        v[2*j]   = lo16(gr[j]) + lo16(hr[j]);
        v[2*j+1] = hi16(gr[j]) + hi16(hr[j]);
    }
    float s = 0.f;
    #pragma unroll
    for (int k=0;k<8;k++) s += v[k];
    #pragma unroll
    for (int msk=1; msk<32; msk<<=1) s += __shfl_xor(s, msk, 32);
    float mean = s * (1.f/256.f);
    float vv = 0.f;
    #pragma unroll
    for (int k=0;k<8;k++){ float d = v[k]-mean; vv += d*d; }
    #pragma unroll
    for (int msk=1; msk<32; msk<<=1) vv += __shfl_xor(vv, msk, 32);
    float inv = rsqrtf(vv*(1.f/256.f) + EPSV);
    float4 g0 = *(const float4*)&gam[c8];
    float4 g1 = *(const float4*)&gam[c8+4];
    float4 b0 = *(const float4*)&bet[c8];
    float4 b1 = *(const float4*)&bet[c8+4];
    float gg[8] = {g0.x,g0.y,g0.z,g0.w,g1.x,g1.y,g1.z,g1.w};
    float bb[8] = {b0.x,b0.y,b0.z,b0.w,b1.x,b1.y,b1.z,b1.w};
    u32 out[4];
    #pragma unroll
    for (int j=0;j<4;j++){
        u16 a = f2bf((v[2*j]-mean)*inv*gg[2*j] + bb[2*j]);
        u16 b = f2bf((v[2*j+1]-mean)*inv*gg[2*j+1] + bb[2*j+1]);
        out[j] = (u32)a | ((u32)b << 16);
    }
    uint4 o4 = {out[0], out[1], out[2], out[3]};
    *(uint4*)&h[grow*HD + c8] = o4;
}

// ---------------- mixprop on cls tokens (coalesced WmT reads), in-place h ----------------
__global__ __launch_bounds__(256)
void k_mixprop(u16* __restrict__ h, const float* __restrict__ a,
               const u16* __restrict__ wmT, const float* __restrict__ bm)
{
    int n = blockIdx.x >> 2, tt = blockIdx.x & 3;
    __shared__ float xs[256][17], h1s[256][17], h2s[256][17];
    __shared__ float as[16][17];
    int t = threadIdx.x;
    as[t>>4][t&15] = a[t];
    for (int idx=t; idx<4096; idx+=256){
        int w = idx >> 8, hc = idx & 255;
        xs[hc][w] = bf2f(h[((size_t)(n*16 + w)*LSEQ + TT + tt)*HD + hc]);
    }
    __syncthreads();
    for (int idx=t; idx<4096; idx+=256){
        int v = idx & 15, hc = idx >> 4;
        float acc = 0.f;
        #pragma unroll
        for (int w=0;w<16;w++) acc += as[v][w]*xs[hc][w];
        h1s[hc][v] = acc;
    }
    __syncthreads();
    for (int idx=t; idx<4096; idx+=256){
        int v = idx & 15, hc = idx >> 4;
        float acc = 0.f;
        #pragma unroll
        for (int w=0;w<16;w++) acc += as[v][w]*h1s[hc][w];
        h2s[hc][v] = acc;
    }
    __syncthreads();
    int o = t;
    float acc[16];
    #pragma unroll
    for (int w=0;w<16;w++) acc[w] = 0.f;
    for (int hc=0; hc<256; hc++){
        float w0 = bf2f(wmT[hc*256 + o]);
        float w1 = bf2f(wmT[(256+hc)*256 + o]);
        float w2 = bf2f(wmT[(512+hc)*256 + o]);
        #pragma unroll
        for (int w=0;w<16;w++)
            acc[w] += xs[hc][w]*w0 + h1s[hc][w]*w1 + h2s[hc][w]*w2;
    }
    float bb = bm[o];
    #pragma unroll
    for (int w=0;w<16;w++)
        h[((size_t)(n*16 + w)*LSEQ + TT + tt)*HD + o] = f2bf(acc[w] + bb);
}

// ---------------- head ----------------
__global__ __launch_bounds__(256)
void k_z(const u16* __restrict__ h, u16* __restrict__ z)
{
    int bid = blockIdx.x, t = threadIdx.x;     // bid = n*16+c
    #pragma unroll
    for (int tc=0;tc<4;tc++)
        z[((size_t)bid*4 + tc)*HD + t] = f2bf(tanhf(bf2f(h[((size_t)bid*LSEQ + TT + tc)*HD + t])));
}

// head1 partial: grid (nb 0..15, kb 0..15); partial over K-chunk of 1024; Wd1 read fp32
__global__ __launch_bounds__(256)
void k_head1p(const u16* __restrict__ z, const float* __restrict__ Wd1,
              float* __restrict__ d1p)
{
    __shared__ float zch[64][137];
    __shared__ float wt[16][137];
    int t = threadIdx.x;
    int col = t & 15, rgrp = t >> 4;
    int ob = blockIdx.x * 16;
    int kb = blockIdx.y;
    float acc[4] = {0.f,0.f,0.f,0.f};
    for (int kc=0; kc<1024; kc+=128){
        int base_k = kb*1024 + kc;
        #pragma unroll
        for (int jj=0; jj<16; jj++){
            int idx = t + jj*256;
            int n = idx >> 6, k2 = (idx & 63) << 1;
            u32 r = *(const u32*)&z[(size_t)n*16384 + base_k + k2];
            zch[n][k2] = lo16(r); zch[n][k2+1] = hi16(r);
        }
        #pragma unroll
        for (int jj=0; jj<2; jj++){
            int idx = t + jj*256;
            int r = idx >> 5, k4 = (idx & 31) << 2;
            float4 w4 = *(const float4*)&Wd1[(size_t)(ob + r)*16384 + base_k + k4];
            wt[r][k4] = w4.x; wt[r][k4+1] = w4.y; wt[r][k4+2] = w4.z; wt[r][k4+3] = w4.w;
        }
        __syncthreads();
        for (int k=0;k<128;k++){
            float wv = wt[col][k];
            #pragma unroll
            for (int u=0;u<4;u++) acc[u] += zch[rgrp + 16*u][k]*wv;
        }
        __syncthreads();
    }
    #pragma unroll
    for (int u=0;u<4;u++)
        d1p[(size_t)(kb*64 + rgrp + 16*u)*HD + ob + col] = acc[u];
}

// fused: reduce d1p partials -> GELU -> dot with Wd2 -> out
__global__ __launch_bounds__(256)
void k_headf(const float* __restrict__ d1p, const float* __restrict__ bd1,
             const float* __restrict__ Wd2, const float* __restrict__ bd2,
             float* __restrict__ out)
{
    __shared__ float red[4];
    int n = blockIdx.x, c = threadIdx.x;
    float s = 0.f;
    #pragma unroll
    for (int kb=0; kb<16; kb++) s += d1p[(size_t)(kb*64 + n)*HD + c];
    float xx = s + bd1[c];
    float ge = 0.5f*xx*(1.f + erff(xx*0.70710678118654752f));
    float p = ge * Wd2[c];
    #pragma unroll
    for (int m=1;m<64;m<<=1) p += __shfl_xor(p, m, 64);
    if ((c & 63) == 0) red[c >> 6] = p;
    __syncthreads();
    if (c == 0) out[n] = red[0]+red[1]+red[2]+red[3] + bd2[0];
}

// ---------------- launch ----------------
extern "C" void kernel_launch(void* const* d_in, const int* in_sizes, int n_in,
                              void* d_out, int out_size, void* d_ws, size_t ws_size,
                              hipStream_t stream)
{
    const float* x    = (const float*)d_in[0];
    const float* Wfc  = (const float*)d_in[3];
    const float* bfc  = (const float*)d_in[4];
    const float* cls  = (const float*)d_in[5];
    const float* pos  = (const float*)d_in[6];
    const float* emb1 = (const float*)d_in[7];
    const float* emb2 = (const float*)d_in[8];
    const float* Wl1  = (const float*)d_in[9];
    const float* bl1  = (const float*)d_in[10];
    const float* Wl2  = (const float*)d_in[11];
    const float* bl2  = (const float*)d_in[12];
    const float* Wqkv = (const float*)d_in[13];
    const float* bqkv = (const float*)d_in[14];
    const float* Wo   = (const float*)d_in[15];
    const float* bo   = (const float*)d_in[16];
    const float* W1   = (const float*)d_in[17];
    const float* b1   = (const float*)d_in[18];
    const float* W2   = (const float*)d_in[19];
    const float* b2   = (const float*)d_in[20];
    const float* ln1g = (const float*)d_in[21];
    const float* ln1b = (const float*)d_in[22];
    const float* ln2g = (const float*)d_in[23];
    const float* ln2b = (const float*)d_in[24];
    const float* Wmlp = (const float*)d_in[25];
    const float* bmlp = (const float*)d_in[26];
    const float* Wd1  = (const float*)d_in[27];
    const float* bd1  = (const float*)d_in[28];
    const float* Wd2  = (const float*)d_in[29];
    const float* bd2  = (const float*)d_in[30];

    // dynamic chunk selection
    int NCH = 8;
    {
        const size_t fixed = 63145088 + (1<<20);
        if      (fixed + (size_t)MTOK    *2560 <= ws_size) NCH = 1;
        else if (fixed + (size_t)(MTOK/2)*2560 <= ws_size) NCH = 2;
        else if (fixed + (size_t)(MTOK/4)*2560 <= ws_size) NCH = 4;
    }
    const int RCH = MTOK / NCH;
    const int SCH = BSEQ / NCH;

    // workspace layout
    u16* h    = (u16*)d_ws;                    // 26,214,400 u16
    u16* buf  = h    + (size_t)MTOK*HD;        // RCH*1024
    u16* buf2 = buf  + (size_t)RCH*1024;       // RCH*256
    u16* wq   = buf2 + (size_t)RCH*256;        //    786,432
    u16* wo   = wq   + (size_t)4*768*256;      //    262,144
    u16* w1   = wo   + (size_t)4*256*256;      //  1,048,576
    u16* w2   = w1   + (size_t)4*1024*256;     //  1,048,576
    u16* wmT  = w2   + (size_t)4*256*1024;     //    589,824
    u16* zb   = wmT  + (size_t)3*768*256;      //  1,048,576
    float* fp = (float*)(zb + (size_t)BSZ*16384);
    float* m1  = fp;
    float* m2  = m1 + CCH*HD;
    float* an  = m2 + CCH*HD;
    float* d1p = an + CCH*CCH;                 // 16*64*256

    // one-time weight prep
    k_cvt<<<512, 256, 0, stream>>>(Wqkv, wq, 4*768*256);
    k_cvt<<<256, 256, 0, stream>>>(Wo,   wo, 4*256*256);
    k_cvt<<<512, 256, 0, stream>>>(W1,   w1, 4*1024*256);
    k_cvt<<<512, 256, 0, stream>>>(W2,   w2, 4*256*1024);
    k_wmT<<<3*768, 256, 0, stream>>>(Wmlp, wmT);

    k_embed<<<MTOK, 256, 0, stream>>>(x, Wfc, bfc, cls, pos, h);
    k_graph_m<<<16, 256, 0, stream>>>(emb1, Wl1, bl1, m1);
    k_graph_m<<<16, 256, 0, stream>>>(emb2, Wl2, bl2, m2);
    k_graph_a<<<1, 256, 0, stream>>>(m1, m2, an);

    for (int l=0; l<NLAY; l++){
        if (l > 0)
            k_mixprop<<<BSZ*NCLS, 256, 0, stream>>>(h, an,
                wmT + (size_t)(l-1)*768*256, bmlp + (size_t)(l-1)*HD);

        for (int c=0; c<NCH; c++){
            size_t row0 = (size_t)c * RCH;
            k_gemmA<<<dim3(RCH/128, 768/128), 256, 0, stream>>>(
                h + row0*HD, HD, wq + (size_t)l*768*256, bqkv + (size_t)l*768,
                buf, 768, HD, 0);
            k_attn<<<SCH*NHEAD/2, 256, 0, stream>>>(buf);
            k_gemmA<<<dim3(RCH/128, 256/128), 256, 0, stream>>>(
                buf, 768, wo + (size_t)l*256*256, bo + (size_t)l*HD, buf2, 256, HD, 0);
            k_ln<<<RCH/8, 256, 0, stream>>>(buf2, h,
                ln1g + (size_t)l*HD, ln1b + (size_t)l*HD, row0);
            k_gemmA<<<dim3(RCH/128, 1024/128), 256, 0, stream>>>(
                h + row0*HD, HD, w1 + (size_t)l*1024*256, b1 + (size_t)l*1024,
                buf, 1024, HD, 1);
            k_gemmA<<<dim3(RCH/128, 256/128), 256, 0, stream>>>(
                buf, 1024, w2 + (size_t)l*256*1024, b2 + (size_t)l*HD, buf2, 256, 1024, 0);
            k_ln<<<RCH/8, 256, 0, stream>>>(buf2, h,
                ln2g + (size_t)l*HD, ln2b + (size_t)l*HD, row0);
        }
    }

    k_z<<<BSZ*CCH, 256, 0, stream>>>(h, zb);
    k_head1p<<<dim3(16, 16), 256, 0, stream>>>(zb, Wd1, d1p);
    k_headf<<<BSZ, 256, 0, stream>>>(d1p, bd1, Wd2, bd2, (float*)d_out);
}

// Round 12
// 2475.256 us; speedup vs baseline: 2.6854x; 1.0441x over previous
//
#include <hip/hip_runtime.h>
#include <hip/hip_bf16.h>
#include <math.h>

typedef unsigned short u16;
typedef unsigned int   u32;
typedef __attribute__((ext_vector_type(8))) short short8;   // 8 bf16 = 4 VGPRs
typedef __attribute__((ext_vector_type(4))) float f32x4;

// ---- model dims ----
#define BSZ   64
#define TT    96
#define CCH   16
#define INDIM 16
#define HD    256
#define NHEAD 8
#define DHEAD 32
#define NCLS  4
#define LSEQ  100      // TT + NCLS
#define NLAY  4
#define EPSV  1e-5f
#define BSEQ  (BSZ*CCH)        // 1024 sequences
#define MTOK  (BSEQ*LSEQ)      // 102400 tokens

__device__ __forceinline__ float bf2f(u16 x){ return __uint_as_float(((u32)x)<<16); }
__device__ __forceinline__ u16 f2bf(float f){
    u32 u = __float_as_uint(f);
    u32 r = (u + 0x7fffu + ((u>>16)&1u)) >> 16;
    return (u16)r;
}
__device__ __forceinline__ float lo16(u32 r){ return __uint_as_float(r<<16); }
__device__ __forceinline__ float hi16(u32 r){ return __uint_as_float(r&0xffff0000u); }

// async global->LDS, 16B per lane; LDS dest = (wave-uniform base) + lane*16
__device__ __forceinline__ void gload_lds16(const u16* g, u16* l){
    __builtin_amdgcn_global_load_lds(
        (const __attribute__((address_space(1))) unsigned int*)g,
        (__attribute__((address_space(3))) unsigned int*)l, 16, 0, 0);
}

// ---------------- f32 -> bf16 bulk convert ----------------
__global__ __launch_bounds__(256)
void k_cvt(const float* __restrict__ src, u16* __restrict__ dst, int n)
{
    for (int i = blockIdx.x*256 + threadIdx.x; i < n; i += gridDim.x*256)
        dst[i] = f2bf(src[i]);
}

// ---------------- Wmlp transpose: WmT[l][j][o] = bf16(Wmlp[l][o][j]) ----------------
__global__ __launch_bounds__(256)
void k_wmT(const float* __restrict__ Wm, u16* __restrict__ wmT)
{
    int b = blockIdx.x;           // l*768 + j
    int l = b / 768, j = b - l*768;
    int o = threadIdx.x;
    wmT[(size_t)b*256 + o] = f2bf(Wm[(size_t)(l*256 + o)*768 + j]);
}

// ---------------- embed: one block per sequence, Wfc row in registers ----------------
__global__ __launch_bounds__(256)
void k_embed(const float* __restrict__ x, const float* __restrict__ Wfc,
             const float* __restrict__ bfc, const float* __restrict__ cls,
             const float* __restrict__ pos, u16* __restrict__ h)
{
    int s = blockIdx.x;                // 0..1023 = n*16 + c
    int n = s >> 4, c = s & 15;
    int hc = threadIdx.x;
    float wr[INDIM];
    #pragma unroll
    for (int i=0;i<INDIM;i++) wr[i] = Wfc[hc*INDIM + i];
    float bb = bfc[hc];
    for (int l=0; l<TT; l++){
        const float* xr = x + (size_t)((n*TT + l)*CCH + c)*INDIM;
        float acc = bb;
        #pragma unroll
        for (int i=0;i<INDIM;i++) acc += xr[i]*wr[i];
        acc += pos[(size_t)(l*CCH + c)*HD + hc];
        h[((size_t)s*LSEQ + l)*HD + hc] = f2bf(acc);
    }
    #pragma unroll
    for (int l=TT; l<LSEQ; l++){
        float v = cls[(size_t)((l-TT)*CCH + c)*HD + hc]
                + pos[(size_t)(l*CCH + c)*HD + hc];
        h[((size_t)s*LSEQ + l)*HD + hc] = f2bf(v);
    }
}

// ---------------- graph constructor ----------------
__global__ __launch_bounds__(256)
void k_graph_m(const float* __restrict__ emb, const float* __restrict__ Wl,
               const float* __restrict__ bl, float* __restrict__ m)
{
    int r = blockIdx.x, o = threadIdx.x;
    __shared__ float e[HD];
    e[o] = emb[r*HD + o];
    __syncthreads();
    const float* w = Wl + (size_t)o*HD;
    float acc = bl[o];
    for (int k=0;k<HD;k++) acc += e[k]*w[k];
    m[r*HD + o] = tanhf(acc);
}

__global__ __launch_bounds__(256)
void k_graph_a(const float* __restrict__ m1, const float* __restrict__ m2,
               float* __restrict__ a)
{
    int t = threadIdx.x; int v = t >> 4, w = t & 15;
    __shared__ float adj[16][17];
    float s1=0.f, s2=0.f;
    for (int k=0;k<HD;k++){
        s1 += m1[v*HD+k]*m2[w*HD+k];
        s2 += m2[v*HD+k]*m1[w*HD+k];
    }
    float g = tanhf(s1 - s2); g = g > 0.f ? g : 0.f;
    adj[v][w] = g + (v==w ? 1.f : 0.f);
    __syncthreads();
    float rs = 0.f;
    #pragma unroll
    for (int j=0;j<16;j++) rs += adj[v][j];
    a[t] = adj[v][w] / rs;
}

// ---------------- MFMA GEMM, BK=64 (two 32-col sub-tiles per barrier pair) ----------------
// BM=128, BN=128; 256 threads = 4 waves, each 64x64. K must be a multiple of 64.
__global__ __launch_bounds__(256)
void k_gemmA(const u16* __restrict__ A, int lda,
             const u16* __restrict__ W, const float* __restrict__ bias,
             u16* __restrict__ C, int ldc, int K, int relu)
{
    __shared__ u16 As0[128*32], As1[128*32];
    __shared__ u16 Ws0[128*32], Ws1[128*32];
    int t = threadIdx.x;
    int lane = t & 63, w = t >> 6;
    int wm = (w & 1)*64, wn = (w >> 1)*64;
    int fr = lane & 15, quad = lane >> 4;
    size_t mb = (size_t)blockIdx.x * 128;
    int nb = blockIdx.y * 128;
    int srow = lane >> 2;            // 0..15
    int sslot = lane & 3;

    f32x4 acc[4][4] = {};
    for (int k0 = 0; k0 < K; k0 += 64){
        __syncthreads();   // previous compute done before DMA overwrites LDS
        #pragma unroll
        for (int i=0;i<2;i++){
            int r = w*32 + i*16 + srow;                 // tile row 0..127
            int cw = sslot ^ ((r>>1)&3);
            gload_lds16(&A[(mb + r)*(size_t)lda + k0      + cw*8], &As0[(w*32 + i*16)*32]);
            gload_lds16(&A[(mb + r)*(size_t)lda + k0 + 32 + cw*8], &As1[(w*32 + i*16)*32]);
            gload_lds16(&W[(size_t)(nb + r)*K   + k0      + cw*8], &Ws0[(w*32 + i*16)*32]);
            gload_lds16(&W[(size_t)(nb + r)*K   + k0 + 32 + cw*8], &Ws1[(w*32 + i*16)*32]);
        }
        __syncthreads();   // barrier drains vmcnt -> DMA complete
        short8 af0[4], af1[4], bf0[4], bf1[4];
        #pragma unroll
        for (int mt=0; mt<4; mt++){
            int r = wm + mt*16 + fr;
            int sw = (quad ^ ((r>>1)&3)) << 3;
            af0[mt] = *(const short8*)&As0[r*32 + sw];
            af1[mt] = *(const short8*)&As1[r*32 + sw];
        }
        #pragma unroll
        for (int nt=0; nt<4; nt++){
            int r = wn + nt*16 + fr;
            int sw = (quad ^ ((r>>1)&3)) << 3;
            bf0[nt] = *(const short8*)&Ws0[r*32 + sw];
            bf1[nt] = *(const short8*)&Ws1[r*32 + sw];
        }
        #pragma unroll
        for (int mt=0; mt<4; mt++)
            #pragma unroll
            for (int nt=0; nt<4; nt++){
                acc[mt][nt] = __builtin_amdgcn_mfma_f32_16x16x32_bf16(
                    af0[mt], bf0[nt], acc[mt][nt], 0, 0, 0);
                acc[mt][nt] = __builtin_amdgcn_mfma_f32_16x16x32_bf16(
                    af1[mt], bf1[nt], acc[mt][nt], 0, 0, 0);
            }
    }
    float bb[4];
    #pragma unroll
    for (int nt=0; nt<4; nt++) bb[nt] = bias[nb + wn + nt*16 + fr];
    #pragma unroll
    for (int mt=0; mt<4; mt++){
        #pragma unroll
        for (int nt=0; nt<4; nt++){
            #pragma unroll
            for (int r=0; r<4; r++){
                float v = acc[mt][nt][r] + bb[nt];
                if (relu) v = v > 0.f ? v : 0.f;
                size_t rg = mb + wm + mt*16 + quad*4 + r;
                C[rg*(size_t)ldc + nb + wn + nt*16 + fr] = f2bf(v);
            }
        }
    }
}

// ---------------- MFMA attention: 2 (seq,head) pairs per block, 2 waves per pair ----------------
// S = Q K^T via MFMA; softmax fp32 in C-layout regs; PV via split-P (hi+lo bf16) two-pass MFMA.
#define KS_STR 40
#define VT_STR 136
#define PL_STR 136
__global__ __launch_bounds__(256)
void k_attn(u16* __restrict__ qkv)
{
    __shared__ u16 smem[26368];          // Ks 2x4480 | Vt 2x4352 | Pl 4x2176 (u16 counts)
    int t = threadIdx.x;
    int w = t >> 6, lane = t & 63;
    int fr = lane & 15, quad = lane >> 4;
    int p = t >> 7, t2 = t & 127;
    u16* Ks = smem + p*4480;
    u16* Vt = smem + 8960 + p*4352;
    u16* Pl = smem + 17664 + w*2176;

    {
        int gp = blockIdx.x*2 + p;
        size_t base = (size_t)(gp >> 3)*LSEQ*768 + (gp & 7)*32;
        for (int idx = t2; idx < 1792; idx += 128){
            int key = idx >> 4, d2 = (idx & 15) << 1;
            u32 kv = (key < LSEQ) ? *(const u32*)&qkv[base + (size_t)key*768 + 256 + d2] : 0u;
            *(u32*)&Ks[key*KS_STR + d2] = kv;
        }
        for (int idx = t2; idx < 2048; idx += 128){
            int key = idx >> 4, d2 = (idx & 15) << 1;
            u32 vv = (key < LSEQ) ? *(const u32*)&qkv[base + (size_t)key*768 + 512 + d2] : 0u;
            Vt[ d2   *VT_STR + key] = (u16)(vv & 0xffffu);
            Vt[(d2+1)*VT_STR + key] = (u16)(vv >> 16);
        }
    }
    __syncthreads();

    int wp = w >> 1;
    int gp = blockIdx.x*2 + wp;
    size_t base = (size_t)(gp >> 3)*LSEQ*768 + (gp & 7)*32;
    u16* Ksw = smem + wp*4480;
    u16* Vtw = smem + 8960 + wp*4352;

    short8 kf[7];
    #pragma unroll
    for (int nt=0; nt<7; nt++)
        kf[nt] = *(const short8*)&Ksw[(nt*16 + fr)*KS_STR + quad*8];
    short8 vfr[4][2];
    #pragma unroll
    for (int ks=0; ks<4; ks++)
        #pragma unroll
        for (int nt=0; nt<2; nt++)
            vfr[ks][nt] = *(const short8*)&Vtw[(nt*16 + fr)*VT_STR + ks*32 + quad*8];

    const float scale = 0.17677669529663687f;  // 1/sqrt(32)
    int st0 = (w & 1) ? 4 : 0, st1 = (w & 1) ? 7 : 4;
    for (int st = st0; st < st1; ++st){
        int q = st*16 + fr;
        short8 qf = {};
        if (q < LSEQ) qf = *(const short8*)&qkv[base + (size_t)q*768 + quad*8];
        f32x4 S[7];
        #pragma unroll
        for (int nt=0; nt<7; nt++){
            f32x4 z = {};
            S[nt] = __builtin_amdgcn_mfma_f32_16x16x32_bf16(qf, kf[nt], z, 0,0,0);
        }
        float mx[4] = {-1e30f,-1e30f,-1e30f,-1e30f};
        #pragma unroll
        for (int r=0;r<4;r++){
            int qr = st*16 + quad*4 + r;
            int jmax = (qr < TT) ? qr : (LSEQ-1);
            #pragma unroll
            for (int nt=0;nt<7;nt++){
                int j = nt*16 + fr;
                float s = (j <= jmax) ? S[nt][r]*scale : -1e30f;
                S[nt][r] = s;
                mx[r] = fmaxf(mx[r], s);
            }
        }
        #pragma unroll
        for (int r=0;r<4;r++){
            #pragma unroll
            for (int m=1;m<16;m<<=1) mx[r] = fmaxf(mx[r], __shfl_xor(mx[r], m, 64));
        }
        float l4[4] = {0.f,0.f,0.f,0.f};
        #pragma unroll
        for (int r=0;r<4;r++){
            #pragma unroll
            for (int nt=0;nt<7;nt++){
                float pv = __expf(S[nt][r] - mx[r]);
                S[nt][r] = pv;
                l4[r] += pv;
            }
        }
        #pragma unroll
        for (int r=0;r<4;r++){
            #pragma unroll
            for (int m=1;m<16;m<<=1) l4[r] += __shfl_xor(l4[r], m, 64);
        }
        // pass 1: P_hi
        #pragma unroll
        for (int nt=0;nt<7;nt++)
            #pragma unroll
            for (int r=0;r<4;r++){
                u16 hb = f2bf(S[nt][r]);
                Pl[(quad*4+r)*PL_STR + nt*16 + fr] = hb;
                S[nt][r] -= bf2f(hb);
            }
        #pragma unroll
        for (int r=0;r<4;r++)
            Pl[(quad*4+r)*PL_STR + 112 + fr] = 0;
        __builtin_amdgcn_s_waitcnt(0);
        f32x4 D[2] = {};
        #pragma unroll
        for (int ks=0; ks<4; ks++){
            short8 pf = *(const short8*)&Pl[fr*PL_STR + ks*32 + quad*8];
            #pragma unroll
            for (int nt=0; nt<2; nt++)
                D[nt] = __builtin_amdgcn_mfma_f32_16x16x32_bf16(pf, vfr[ks][nt], D[nt], 0,0,0);
        }
        __builtin_amdgcn_s_waitcnt(0);
        // pass 2: P_lo
        #pragma unroll
        for (int nt=0;nt<7;nt++)
            #pragma unroll
            for (int r=0;r<4;r++)
                Pl[(quad*4+r)*PL_STR + nt*16 + fr] = f2bf(S[nt][r]);
        __builtin_amdgcn_s_waitcnt(0);
        #pragma unroll
        for (int ks=0; ks<4; ks++){
            short8 pf = *(const short8*)&Pl[fr*PL_STR + ks*32 + quad*8];
            #pragma unroll
            for (int nt=0; nt<2; nt++)
                D[nt] = __builtin_amdgcn_mfma_f32_16x16x32_bf16(pf, vfr[ks][nt], D[nt], 0,0,0);
        }
        #pragma unroll
        for (int r=0;r<4;r++){
            int qr = st*16 + quad*4 + r;
            if (qr < LSEQ){
                float inv = 1.f / l4[r];
                #pragma unroll
                for (int nt=0; nt<2; nt++)
                    qkv[base + (size_t)qr*768 + nt*16 + fr] = f2bf(D[nt][r]*inv);
            }
        }
        __builtin_amdgcn_s_waitcnt(0);
    }
}

// ---------------- residual + LayerNorm: h[row] = LN(g[row_local] + h[row]) ----------------
__global__ __launch_bounds__(256)
void k_ln(const u16* __restrict__ g, u16* __restrict__ h,
          const float* __restrict__ gam, const float* __restrict__ bet,
          size_t row0)
{
    int t = threadIdx.x;
    int rl = t >> 5, lane32 = t & 31, c8 = lane32 << 3;
    size_t lrow = (size_t)blockIdx.x*8 + rl;
    size_t grow = row0 + lrow;
    uint4 g4 = *(const uint4*)&g[lrow*HD + c8];
    uint4 h4 = *(const uint4*)&h[grow*HD + c8];
    u32 gr[4] = {g4.x,g4.y,g4.z,g4.w};
    u32 hr[4] = {h4.x,h4.y,h4.z,h4.w};
    float v[8];
    #pragma unroll
    for (int j=0;j<4;j++){
        v[2*j]   = lo16(gr[j]) + lo16(hr[j]);
        v[2*j+1] = hi16(gr[j]) + hi16(hr[j]);
    }
    float s = 0.f;
    #pragma unroll
    for (int k=0;k<8;k++) s += v[k];
    #pragma unroll
    for (int msk=1; msk<32; msk<<=1) s += __shfl_xor(s, msk, 32);
    float mean = s * (1.f/256.f);
    float vv = 0.f;
    #pragma unroll
    for (int k=0;k<8;k++){ float d = v[k]-mean; vv += d*d; }
    #pragma unroll
    for (int msk=1; msk<32; msk<<=1) vv += __shfl_xor(vv, msk, 32);
    float inv = rsqrtf(vv*(1.f/256.f) + EPSV);
    float4 g0 = *(const float4*)&gam[c8];
    float4 g1 = *(const float4*)&gam[c8+4];
    float4 b0 = *(const float4*)&bet[c8];
    float4 b1 = *(const float4*)&bet[c8+4];
    float gg[8] = {g0.x,g0.y,g0.z,g0.w,g1.x,g1.y,g1.z,g1.w};
    float bb[8] = {b0.x,b0.y,b0.z,b0.w,b1.x,b1.y,b1.z,b1.w};
    u32 out[4];
    #pragma unroll
    for (int j=0;j<4;j++){
        u16 a = f2bf((v[2*j]-mean)*inv*gg[2*j] + bb[2*j]);
        u16 b = f2bf((v[2*j+1]-mean)*inv*gg[2*j+1] + bb[2*j+1]);
        out[j] = (u32)a | ((u32)b << 16);
    }
    uint4 o4 = {out[0], out[1], out[2], out[3]};
    *(uint4*)&h[grow*HD + c8] = o4;
}

// ---------------- mixprop on cls tokens (coalesced WmT reads), in-place h ----------------
__global__ __launch_bounds__(256)
void k_mixprop(u16* __restrict__ h, const float* __restrict__ a,
               const u16* __restrict__ wmT, const float* __restrict__ bm)
{
    int n = blockIdx.x >> 2, tt = blockIdx.x & 3;
    __shared__ float xs[256][17], h1s[256][17], h2s[256][17];
    __shared__ float as[16][17];
    int t = threadIdx.x;
    as[t>>4][t&15] = a[t];
    for (int idx=t; idx<4096; idx+=256){
        int w = idx >> 8, hc = idx & 255;
        xs[hc][w] = bf2f(h[((size_t)(n*16 + w)*LSEQ + TT + tt)*HD + hc]);
    }
    __syncthreads();
    for (int idx=t; idx<4096; idx+=256){
        int v = idx & 15, hc = idx >> 4;
        float acc = 0.f;
        #pragma unroll
        for (int w=0;w<16;w++) acc += as[v][w]*xs[hc][w];
        h1s[hc][v] = acc;
    }
    __syncthreads();
    for (int idx=t; idx<4096; idx+=256){
        int v = idx & 15, hc = idx >> 4;
        float acc = 0.f;
        #pragma unroll
        for (int w=0;w<16;w++) acc += as[v][w]*h1s[hc][w];
        h2s[hc][v] = acc;
    }
    __syncthreads();
    int o = t;
    float acc[16];
    #pragma unroll
    for (int w=0;w<16;w++) acc[w] = 0.f;
    for (int hc=0; hc<256; hc++){
        float w0 = bf2f(wmT[hc*256 + o]);
        float w1 = bf2f(wmT[(256+hc)*256 + o]);
        float w2 = bf2f(wmT[(512+hc)*256 + o]);
        #pragma unroll
        for (int w=0;w<16;w++)
            acc[w] += xs[hc][w]*w0 + h1s[hc][w]*w1 + h2s[hc][w]*w2;
    }
    float bb = bm[o];
    #pragma unroll
    for (int w=0;w<16;w++)
        h[((size_t)(n*16 + w)*LSEQ + TT + tt)*HD + o] = f2bf(acc[w] + bb);
}

// ---------------- head ----------------
__global__ __launch_bounds__(256)
void k_z(const u16* __restrict__ h, u16* __restrict__ z)
{
    int bid = blockIdx.x, t = threadIdx.x;     // bid = n*16+c
    #pragma unroll
    for (int tc=0;tc<4;tc++)
        z[((size_t)bid*4 + tc)*HD + t] = f2bf(tanhf(bf2f(h[((size_t)bid*LSEQ + TT + tc)*HD + t])));
}

// head1 partial: grid (nb 0..15, kb 0..15); partial over K-chunk of 1024; Wd1 read fp32
__global__ __launch_bounds__(256)
void k_head1p(const u16* __restrict__ z, const float* __restrict__ Wd1,
              float* __restrict__ d1p)
{
    __shared__ float zch[64][137];
    __shared__ float wt[16][137];
    int t = threadIdx.x;
    int col = t & 15, rgrp = t >> 4;
    int ob = blockIdx.x * 16;
    int kb = blockIdx.y;
    float acc[4] = {0.f,0.f,0.f,0.f};
    for (int kc=0; kc<1024; kc+=128){
        int base_k = kb*1024 + kc;
        #pragma unroll
        for (int jj=0; jj<16; jj++){
            int idx = t + jj*256;
            int n = idx >> 6, k2 = (idx & 63) << 1;
            u32 r = *(const u32*)&z[(size_t)n*16384 + base_k + k2];
            zch[n][k2] = lo16(r); zch[n][k2+1] = hi16(r);
        }
        #pragma unroll
        for (int jj=0; jj<2; jj++){
            int idx = t + jj*256;
            int r = idx >> 5, k4 = (idx & 31) << 2;
            float4 w4 = *(const float4*)&Wd1[(size_t)(ob + r)*16384 + base_k + k4];
            wt[r][k4] = w4.x; wt[r][k4+1] = w4.y; wt[r][k4+2] = w4.z; wt[r][k4+3] = w4.w;
        }
        __syncthreads();
        for (int k=0;k<128;k++){
            float wv = wt[col][k];
            #pragma unroll
            for (int u=0;u<4;u++) acc[u] += zch[rgrp + 16*u][k]*wv;
        }
        __syncthreads();
    }
    #pragma unroll
    for (int u=0;u<4;u++)
        d1p[(size_t)(kb*64 + rgrp + 16*u)*HD + ob + col] = acc[u];
}

// fused: reduce d1p partials -> GELU -> dot with Wd2 -> out
__global__ __launch_bounds__(256)
void k_headf(const float* __restrict__ d1p, const float* __restrict__ bd1,
             const float* __restrict__ Wd2, const float* __restrict__ bd2,
             float* __restrict__ out)
{
    __shared__ float red[4];
    int n = blockIdx.x, c = threadIdx.x;
    float s = 0.f;
    #pragma unroll
    for (int kb=0; kb<16; kb++) s += d1p[(size_t)(kb*64 + n)*HD + c];
    float xx = s + bd1[c];
    float ge = 0.5f*xx*(1.f + erff(xx*0.70710678118654752f));
    float p = ge * Wd2[c];
    #pragma unroll
    for (int m=1;m<64;m<<=1) p += __shfl_xor(p, m, 64);
    if ((c & 63) == 0) red[c >> 6] = p;
    __syncthreads();
    if (c == 0) out[n] = red[0]+red[1]+red[2]+red[3] + bd2[0];
}

// ---------------- launch ----------------
extern "C" void kernel_launch(void* const* d_in, const int* in_sizes, int n_in,
                              void* d_out, int out_size, void* d_ws, size_t ws_size,
                              hipStream_t stream)
{
    const float* x    = (const float*)d_in[0];
    const float* Wfc  = (const float*)d_in[3];
    const float* bfc  = (const float*)d_in[4];
    const float* cls  = (const float*)d_in[5];
    const float* pos  = (const float*)d_in[6];
    const float* emb1 = (const float*)d_in[7];
    const float* emb2 = (const float*)d_in[8];
    const float* Wl1  = (const float*)d_in[9];
    const float* bl1  = (const float*)d_in[10];
    const float* Wl2  = (const float*)d_in[11];
    const float* bl2  = (const float*)d_in[12];
    const float* Wqkv = (const float*)d_in[13];
    const float* bqkv = (const float*)d_in[14];
    const float* Wo   = (const float*)d_in[15];
    const float* bo   = (const float*)d_in[16];
    const float* W1   = (const float*)d_in[17];
    const float* b1   = (const float*)d_in[18];
    const float* W2   = (const float*)d_in[19];
    const float* b2   = (const float*)d_in[20];
    const float* ln1g = (const float*)d_in[21];
    const float* ln1b = (const float*)d_in[22];
    const float* ln2g = (const float*)d_in[23];
    const float* ln2b = (const float*)d_in[24];
    const float* Wmlp = (const float*)d_in[25];
    const float* bmlp = (const float*)d_in[26];
    const float* Wd1  = (const float*)d_in[27];
    const float* bd1  = (const float*)d_in[28];
    const float* Wd2  = (const float*)d_in[29];
    const float* bd2  = (const float*)d_in[30];

    // dynamic chunk selection
    int NCH = 8;
    {
        const size_t fixed = 63145088 + (1<<20);
        if      (fixed + (size_t)MTOK    *2560 <= ws_size) NCH = 1;
        else if (fixed + (size_t)(MTOK/2)*2560 <= ws_size) NCH = 2;
        else if (fixed + (size_t)(MTOK/4)*2560 <= ws_size) NCH = 4;
    }
    const int RCH = MTOK / NCH;
    const int SCH = BSEQ / NCH;

    // workspace layout
    u16* h    = (u16*)d_ws;                    // 26,214,400 u16
    u16* buf  = h    + (size_t)MTOK*HD;        // RCH*1024
    u16* buf2 = buf  + (size_t)RCH*1024;       // RCH*256
    u16* wq   = buf2 + (size_t)RCH*256;        //    786,432
    u16* wo   = wq   + (size_t)4*768*256;      //    262,144
    u16* w1   = wo   + (size_t)4*256*256;      //  1,048,576
    u16* w2   = w1   + (size_t)4*1024*256;     //  1,048,576
    u16* wmT  = w2   + (size_t)4*256*1024;     //    589,824
    u16* zb   = wmT  + (size_t)3*768*256;      //  1,048,576
    float* fp = (float*)(zb + (size_t)BSZ*16384);
    float* m1  = fp;
    float* m2  = m1 + CCH*HD;
    float* an  = m2 + CCH*HD;
    float* d1p = an + CCH*CCH;                 // 16*64*256

    // one-time weight prep
    k_cvt<<<512, 256, 0, stream>>>(Wqkv, wq, 4*768*256);
    k_cvt<<<256, 256, 0, stream>>>(Wo,   wo, 4*256*256);
    k_cvt<<<512, 256, 0, stream>>>(W1,   w1, 4*1024*256);
    k_cvt<<<512, 256, 0, stream>>>(W2,   w2, 4*256*1024);
    k_wmT<<<3*768, 256, 0, stream>>>(Wmlp, wmT);

    k_embed<<<BSEQ, 256, 0, stream>>>(x, Wfc, bfc, cls, pos, h);
    k_graph_m<<<16, 256, 0, stream>>>(emb1, Wl1, bl1, m1);
    k_graph_m<<<16, 256, 0, stream>>>(emb2, Wl2, bl2, m2);
    k_graph_a<<<1, 256, 0, stream>>>(m1, m2, an);

    for (int l=0; l<NLAY; l++){
        if (l > 0)
            k_mixprop<<<BSZ*NCLS, 256, 0, stream>>>(h, an,
                wmT + (size_t)(l-1)*768*256, bmlp + (size_t)(l-1)*HD);

        for (int c=0; c<NCH; c++){
            size_t row0 = (size_t)c * RCH;
            k_gemmA<<<dim3(RCH/128, 768/128), 256, 0, stream>>>(
                h + row0*HD, HD, wq + (size_t)l*768*256, bqkv + (size_t)l*768,
                buf, 768, HD, 0);
            k_attn<<<SCH*NHEAD/2, 256, 0, stream>>>(buf);
            k_gemmA<<<dim3(RCH/128, 256/128), 256, 0, stream>>>(
                buf, 768, wo + (size_t)l*256*256, bo + (size_t)l*HD, buf2, 256, HD, 0);
            k_ln<<<RCH/8, 256, 0, stream>>>(buf2, h,
                ln1g + (size_t)l*HD, ln1b + (size_t)l*HD, row0);
            k_gemmA<<<dim3(RCH/128, 1024/128), 256, 0, stream>>>(
                h + row0*HD, HD, w1 + (size_t)l*1024*256, b1 + (size_t)l*1024,
                buf, 1024, HD, 1);
            k_gemmA<<<dim3(RCH/128, 256/128), 256, 0, stream>>>(
                buf, 1024, w2 + (size_t)l*256*1024, b2 + (size_t)l*HD, buf2, 256, 1024, 0);
            k_ln<<<RCH/8, 256, 0, stream>>>(buf2, h,
                ln2g + (size_t)l*HD, ln2b + (size_t)l*HD, row0);
        }
    }

    k_z<<<BSZ*CCH, 256, 0, stream>>>(h, zb);
    k_head1p<<<dim3(16, 16), 256, 0, stream>>>(zb, Wd1, d1p);
    k_headf<<<BSZ, 256, 0, stream>>>(d1p, bd1, Wd2, bd2, (float*)d_out);
}

// Round 13
// 2413.149 us; speedup vs baseline: 2.7545x; 1.0257x over previous
//
#include <hip/hip_runtime.h>
#include <hip/hip_bf16.h>
#include <math.h>

typedef unsigned short u16;
typedef unsigned int   u32;
typedef __attribute__((ext_vector_type(8))) short short8;   // 8 bf16 = 4 VGPRs
typedef __attribute__((ext_vector_type(4))) float f32x4;

// ---- model dims ----
#define BSZ   64
#define TT    96
#define CCH   16
#define INDIM 16
#define HD    256
#define NHEAD 8
#define DHEAD 32
#define NCLS  4
#define LSEQ  100      // TT + NCLS
#define NLAY  4
#define EPSV  1e-5f
#define BSEQ  (BSZ*CCH)        // 1024 sequences
#define MTOK  (BSEQ*LSEQ)      // 102400 tokens

__device__ __forceinline__ float bf2f(u16 x){ return __uint_as_float(((u32)x)<<16); }
__device__ __forceinline__ u16 f2bf(float f){
    u32 u = __float_as_uint(f);
    u32 r = (u + 0x7fffu + ((u>>16)&1u)) >> 16;
    return (u16)r;
}
__device__ __forceinline__ float lo16(u32 r){ return __uint_as_float(r<<16); }
__device__ __forceinline__ float hi16(u32 r){ return __uint_as_float(r&0xffff0000u); }

// async global->LDS, 16B per lane; LDS dest = (wave-uniform base) + lane*16
__device__ __forceinline__ void gload_lds16(const u16* g, u16* l){
    __builtin_amdgcn_global_load_lds(
        (const __attribute__((address_space(1))) unsigned int*)g,
        (__attribute__((address_space(3))) unsigned int*)l, 16, 0, 0);
}

// ---------------- f32 -> bf16 bulk convert ----------------
__global__ __launch_bounds__(256)
void k_cvt(const float* __restrict__ src, u16* __restrict__ dst, int n)
{
    for (int i = blockIdx.x*256 + threadIdx.x; i < n; i += gridDim.x*256)
        dst[i] = f2bf(src[i]);
}

// ---------------- embed: one block per sequence, Wfc row in registers ----------------
__global__ __launch_bounds__(256)
void k_embed(const float* __restrict__ x, const float* __restrict__ Wfc,
             const float* __restrict__ bfc, const float* __restrict__ cls,
             const float* __restrict__ pos, u16* __restrict__ h)
{
    int s = blockIdx.x;                // 0..1023 = n*16 + c
    int n = s >> 4, c = s & 15;
    int hc = threadIdx.x;
    float wr[INDIM];
    #pragma unroll
    for (int i=0;i<INDIM;i++) wr[i] = Wfc[hc*INDIM + i];
    float bb = bfc[hc];
    for (int l=0; l<TT; l++){
        const float* xr = x + (size_t)((n*TT + l)*CCH + c)*INDIM;
        float acc = bb;
        #pragma unroll
        for (int i=0;i<INDIM;i++) acc += xr[i]*wr[i];
        acc += pos[(size_t)(l*CCH + c)*HD + hc];
        h[((size_t)s*LSEQ + l)*HD + hc] = f2bf(acc);
    }
    #pragma unroll
    for (int l=TT; l<LSEQ; l++){
        float v = cls[(size_t)((l-TT)*CCH + c)*HD + hc]
                + pos[(size_t)(l*CCH + c)*HD + hc];
        h[((size_t)s*LSEQ + l)*HD + hc] = f2bf(v);
    }
}

// ---------------- graph constructor ----------------
__global__ __launch_bounds__(256)
void k_graph_m(const float* __restrict__ emb, const float* __restrict__ Wl,
               const float* __restrict__ bl, float* __restrict__ m)
{
    int r = blockIdx.x, o = threadIdx.x;
    __shared__ float e[HD];
    e[o] = emb[r*HD + o];
    __syncthreads();
    const float* w = Wl + (size_t)o*HD;
    float acc = bl[o];
    for (int k=0;k<HD;k++) acc += e[k]*w[k];
    m[r*HD + o] = tanhf(acc);
}

__global__ __launch_bounds__(256)
void k_graph_a(const float* __restrict__ m1, const float* __restrict__ m2,
               float* __restrict__ a)
{
    int t = threadIdx.x; int v = t >> 4, w = t & 15;
    __shared__ float adj[16][17];
    float s1=0.f, s2=0.f;
    for (int k=0;k<HD;k++){
        s1 += m1[v*HD+k]*m2[w*HD+k];
        s2 += m2[v*HD+k]*m1[w*HD+k];
    }
    float g = tanhf(s1 - s2); g = g > 0.f ? g : 0.f;
    adj[v][w] = g + (v==w ? 1.f : 0.f);
    __syncthreads();
    float rs = 0.f;
    #pragma unroll
    for (int j=0;j<16;j++) rs += adj[v][j];
    a[t] = adj[v][w] / rs;
}

// ---------------- MFMA GEMM, BK=64; optional cls-scatter output mapping ----------------
// BM=128, BN=128; 256 threads = 4 waves, each 64x64. K multiple of 64.
// scat=1: output row rg is remapped (rg>>2)*LSEQ + TT + (rg&3)  (cls-token write-back).
__global__ __launch_bounds__(256)
void k_gemmA(const u16* __restrict__ A, int lda,
             const u16* __restrict__ W, const float* __restrict__ bias,
             u16* __restrict__ C, int ldc, int K, int relu, int scat)
{
    __shared__ u16 As0[128*32], As1[128*32];
    __shared__ u16 Ws0[128*32], Ws1[128*32];
    int t = threadIdx.x;
    int lane = t & 63, w = t >> 6;
    int wm = (w & 1)*64, wn = (w >> 1)*64;
    int fr = lane & 15, quad = lane >> 4;
    size_t mb = (size_t)blockIdx.x * 128;
    int nb = blockIdx.y * 128;
    int srow = lane >> 2;            // 0..15
    int sslot = lane & 3;

    f32x4 acc[4][4] = {};
    for (int k0 = 0; k0 < K; k0 += 64){
        __syncthreads();
        #pragma unroll
        for (int i=0;i<2;i++){
            int r = w*32 + i*16 + srow;
            int cw = sslot ^ ((r>>1)&3);
            gload_lds16(&A[(mb + r)*(size_t)lda + k0      + cw*8], &As0[(w*32 + i*16)*32]);
            gload_lds16(&A[(mb + r)*(size_t)lda + k0 + 32 + cw*8], &As1[(w*32 + i*16)*32]);
            gload_lds16(&W[(size_t)(nb + r)*K   + k0      + cw*8], &Ws0[(w*32 + i*16)*32]);
            gload_lds16(&W[(size_t)(nb + r)*K   + k0 + 32 + cw*8], &Ws1[(w*32 + i*16)*32]);
        }
        __syncthreads();
        short8 af0[4], af1[4], bf0[4], bf1[4];
        #pragma unroll
        for (int mt=0; mt<4; mt++){
            int r = wm + mt*16 + fr;
            int sw = (quad ^ ((r>>1)&3)) << 3;
            af0[mt] = *(const short8*)&As0[r*32 + sw];
            af1[mt] = *(const short8*)&As1[r*32 + sw];
        }
        #pragma unroll
        for (int nt=0; nt<4; nt++){
            int r = wn + nt*16 + fr;
            int sw = (quad ^ ((r>>1)&3)) << 3;
            bf0[nt] = *(const short8*)&Ws0[r*32 + sw];
            bf1[nt] = *(const short8*)&Ws1[r*32 + sw];
        }
        #pragma unroll
        for (int mt=0; mt<4; mt++)
            #pragma unroll
            for (int nt=0; nt<4; nt++){
                acc[mt][nt] = __builtin_amdgcn_mfma_f32_16x16x32_bf16(
                    af0[mt], bf0[nt], acc[mt][nt], 0, 0, 0);
                acc[mt][nt] = __builtin_amdgcn_mfma_f32_16x16x32_bf16(
                    af1[mt], bf1[nt], acc[mt][nt], 0, 0, 0);
            }
    }
    float bb[4];
    #pragma unroll
    for (int nt=0; nt<4; nt++) bb[nt] = bias[nb + wn + nt*16 + fr];
    #pragma unroll
    for (int mt=0; mt<4; mt++){
        #pragma unroll
        for (int nt=0; nt<4; nt++){
            #pragma unroll
            for (int r=0; r<4; r++){
                float v = acc[mt][nt][r] + bb[nt];
                if (relu) v = v > 0.f ? v : 0.f;
                size_t rg = mb + wm + mt*16 + quad*4 + r;
                if (scat) rg = (rg >> 2)*LSEQ + TT + (rg & 3);
                C[rg*(size_t)ldc + nb + wn + nt*16 + fr] = f2bf(v);
            }
        }
    }
}

// ---------------- MFMA attention: 2 (seq,head) pairs per block, 2 waves per pair ----------------
// S = Q K^T via MFMA; softmax fp32 in C-layout regs; PV via split-P (hi+lo bf16) two-pass MFMA.
#define KS_STR 40
#define VT_STR 136
#define PL_STR 136
__global__ __launch_bounds__(256)
void k_attn(u16* __restrict__ qkv)
{
    __shared__ u16 smem[26368];          // Ks 2x4480 | Vt 2x4352 | Pl 4x2176 (u16 counts)
    int t = threadIdx.x;
    int w = t >> 6, lane = t & 63;
    int fr = lane & 15, quad = lane >> 4;
    int p = t >> 7, t2 = t & 127;
    u16* Ks = smem + p*4480;
    u16* Vt = smem + 8960 + p*4352;
    u16* Pl = smem + 17664 + w*2176;

    {
        int gp = blockIdx.x*2 + p;
        size_t base = (size_t)(gp >> 3)*LSEQ*768 + (gp & 7)*32;
        for (int idx = t2; idx < 1792; idx += 128){
            int key = idx >> 4, d2 = (idx & 15) << 1;
            u32 kv = (key < LSEQ) ? *(const u32*)&qkv[base + (size_t)key*768 + 256 + d2] : 0u;
            *(u32*)&Ks[key*KS_STR + d2] = kv;
        }
        for (int idx = t2; idx < 2048; idx += 128){
            int key = idx >> 4, d2 = (idx & 15) << 1;
            u32 vv = (key < LSEQ) ? *(const u32*)&qkv[base + (size_t)key*768 + 512 + d2] : 0u;
            Vt[ d2   *VT_STR + key] = (u16)(vv & 0xffffu);
            Vt[(d2+1)*VT_STR + key] = (u16)(vv >> 16);
        }
    }
    __syncthreads();

    int wp = w >> 1;
    int gp = blockIdx.x*2 + wp;
    size_t base = (size_t)(gp >> 3)*LSEQ*768 + (gp & 7)*32;
    u16* Ksw = smem + wp*4480;
    u16* Vtw = smem + 8960 + wp*4352;

    short8 kf[7];
    #pragma unroll
    for (int nt=0; nt<7; nt++)
        kf[nt] = *(const short8*)&Ksw[(nt*16 + fr)*KS_STR + quad*8];
    short8 vfr[4][2];
    #pragma unroll
    for (int ks=0; ks<4; ks++)
        #pragma unroll
        for (int nt=0; nt<2; nt++)
            vfr[ks][nt] = *(const short8*)&Vtw[(nt*16 + fr)*VT_STR + ks*32 + quad*8];

    const float scale = 0.17677669529663687f;  // 1/sqrt(32)
    int st0 = (w & 1) ? 4 : 0, st1 = (w & 1) ? 7 : 4;
    for (int st = st0; st < st1; ++st){
        int q = st*16 + fr;
        short8 qf = {};
        if (q < LSEQ) qf = *(const short8*)&qkv[base + (size_t)q*768 + quad*8];
        f32x4 S[7];
        #pragma unroll
        for (int nt=0; nt<7; nt++){
            f32x4 z = {};
            S[nt] = __builtin_amdgcn_mfma_f32_16x16x32_bf16(qf, kf[nt], z, 0,0,0);
        }
        float mx[4] = {-1e30f,-1e30f,-1e30f,-1e30f};
        #pragma unroll
        for (int r=0;r<4;r++){
            int qr = st*16 + quad*4 + r;
            int jmax = (qr < TT) ? qr : (LSEQ-1);
            #pragma unroll
            for (int nt=0;nt<7;nt++){
                int j = nt*16 + fr;
                float s = (j <= jmax) ? S[nt][r]*scale : -1e30f;
                S[nt][r] = s;
                mx[r] = fmaxf(mx[r], s);
            }
        }
        #pragma unroll
        for (int r=0;r<4;r++){
            #pragma unroll
            for (int m=1;m<16;m<<=1) mx[r] = fmaxf(mx[r], __shfl_xor(mx[r], m, 64));
        }
        float l4[4] = {0.f,0.f,0.f,0.f};
        #pragma unroll
        for (int r=0;r<4;r++){
            #pragma unroll
            for (int nt=0;nt<7;nt++){
                float pv = __expf(S[nt][r] - mx[r]);
                S[nt][r] = pv;
                l4[r] += pv;
            }
        }
        #pragma unroll
        for (int r=0;r<4;r++){
            #pragma unroll
            for (int m=1;m<16;m<<=1) l4[r] += __shfl_xor(l4[r], m, 64);
        }
        // pass 1: P_hi
        #pragma unroll
        for (int nt=0;nt<7;nt++)
            #pragma unroll
            for (int r=0;r<4;r++){
                u16 hb = f2bf(S[nt][r]);
                Pl[(quad*4+r)*PL_STR + nt*16 + fr] = hb;
                S[nt][r] -= bf2f(hb);
            }
        #pragma unroll
        for (int r=0;r<4;r++)
            Pl[(quad*4+r)*PL_STR + 112 + fr] = 0;
        __builtin_amdgcn_s_waitcnt(0);
        f32x4 D[2] = {};
        #pragma unroll
        for (int ks=0; ks<4; ks++){
            short8 pf = *(const short8*)&Pl[fr*PL_STR + ks*32 + quad*8];
            #pragma unroll
            for (int nt=0; nt<2; nt++)
                D[nt] = __builtin_amdgcn_mfma_f32_16x16x32_bf16(pf, vfr[ks][nt], D[nt], 0,0,0);
        }
        __builtin_amdgcn_s_waitcnt(0);
        // pass 2: P_lo
        #pragma unroll
        for (int nt=0;nt<7;nt++)
            #pragma unroll
            for (int r=0;r<4;r++)
                Pl[(quad*4+r)*PL_STR + nt*16 + fr] = f2bf(S[nt][r]);
        __builtin_amdgcn_s_waitcnt(0);
        #pragma unroll
        for (int ks=0; ks<4; ks++){
            short8 pf = *(const short8*)&Pl[fr*PL_STR + ks*32 + quad*8];
            #pragma unroll
            for (int nt=0; nt<2; nt++)
                D[nt] = __builtin_amdgcn_mfma_f32_16x16x32_bf16(pf, vfr[ks][nt], D[nt], 0,0,0);
        }
        #pragma unroll
        for (int r=0;r<4;r++){
            int qr = st*16 + quad*4 + r;
            if (qr < LSEQ){
                float inv = 1.f / l4[r];
                #pragma unroll
                for (int nt=0; nt<2; nt++)
                    qkv[base + (size_t)qr*768 + nt*16 + fr] = f2bf(D[nt][r]*inv);
            }
        }
        __builtin_amdgcn_s_waitcnt(0);
    }
}

// ---------------- residual + LayerNorm: h[row] = LN(g[row_local] + h[row]) ----------------
__global__ __launch_bounds__(256)
void k_ln(const u16* __restrict__ g, u16* __restrict__ h,
          const float* __restrict__ gam, const float* __restrict__ bet,
          size_t row0)
{
    int t = threadIdx.x;
    int rl = t >> 5, lane32 = t & 31, c8 = lane32 << 3;
    size_t lrow = (size_t)blockIdx.x*8 + rl;
    size_t grow = row0 + lrow;
    uint4 g4 = *(const uint4*)&g[lrow*HD + c8];
    uint4 h4 = *(const uint4*)&h[grow*HD + c8];
    u32 gr[4] = {g4.x,g4.y,g4.z,g4.w};
    u32 hr[4] = {h4.x,h4.y,h4.z,h4.w};
    float v[8];
    #pragma unroll
    for (int j=0;j<4;j++){
        v[2*j]   = lo16(gr[j]) + lo16(hr[j]);
        v[2*j+1] = hi16(gr[j]) + hi16(hr[j]);
    }
    float s = 0.f;
    #pragma unroll
    for (int k=0;k<8;k++) s += v[k];
    #pragma unroll
    for (int msk=1; msk<32; msk<<=1) s += __shfl_xor(s, msk, 32);
    float mean = s * (1.f/256.f);
    float vv = 0.f;
    #pragma unroll
    for (int k=0;k<8;k++){ float d = v[k]-mean; vv += d*d; }
    #pragma unroll
    for (int msk=1; msk<32; msk<<=1) vv += __shfl_xor(vv, msk, 32);
    float inv = rsqrtf(vv*(1.f/256.f) + EPSV);
    float4 g0 = *(const float4*)&gam[c8];
    float4 g1 = *(const float4*)&gam[c8+4];
    float4 b0 = *(const float4*)&bet[c8];
    float4 b1 = *(const float4*)&bet[c8+4];
    float gg[8] = {g0.x,g0.y,g0.z,g0.w,g1.x,g1.y,g1.z,g1.w};
    float bb[8] = {b0.x,b0.y,b0.z,b0.w,b1.x,b1.y,b1.z,b1.w};
    u32 out[4];
    #pragma unroll
    for (int j=0;j<4;j++){
        u16 a = f2bf((v[2*j]-mean)*inv*gg[2*j] + bb[2*j]);
        u16 b = f2bf((v[2*j+1]-mean)*inv*gg[2*j+1] + bb[2*j+1]);
        out[j] = (u32)a | ((u32)b << 16);
    }
    uint4 o4 = {out[0], out[1], out[2], out[3]};
    *(uint4*)&h[grow*HD + c8] = o4;
}

// ---------------- mixprop prep: graph propagation -> amid rows (bf16) ----------------
// block = (n,tt); amid[row=(n*16+w)*4+tt][c] = concat(x, h1, h2)[c] for c in [0,768)
__global__ __launch_bounds__(256)
void k_mixprep(const u16* __restrict__ h, const float* __restrict__ a,
               u16* __restrict__ amid)
{
    int n = blockIdx.x >> 2, tt = blockIdx.x & 3;
    __shared__ float xs[256][17], h1s[256][17], h2s[256][17];
    __shared__ float as[16][17];
    int t = threadIdx.x;
    as[t>>4][t&15] = a[t];
    for (int idx=t; idx<4096; idx+=256){
        int w = idx >> 8, hc = idx & 255;
        xs[hc][w] = bf2f(h[((size_t)(n*16 + w)*LSEQ + TT + tt)*HD + hc]);
    }
    __syncthreads();
    for (int idx=t; idx<4096; idx+=256){
        int v = idx & 15, hc = idx >> 4;
        float acc = 0.f;
        #pragma unroll
        for (int w=0;w<16;w++) acc += as[v][w]*xs[hc][w];
        h1s[hc][v] = acc;
    }
    __syncthreads();
    for (int idx=t; idx<4096; idx+=256){
        int v = idx & 15, hc = idx >> 4;
        float acc = 0.f;
        #pragma unroll
        for (int w=0;w<16;w++) acc += as[v][w]*h1s[hc][w];
        h2s[hc][v] = acc;
    }
    __syncthreads();
    int hc = t;
    #pragma unroll
    for (int w=0;w<16;w++){
        size_t row = (size_t)((n*16 + w)*4 + tt);
        amid[row*768 +       hc] = f2bf(xs[hc][w]);
        amid[row*768 + 256 + hc] = f2bf(h1s[hc][w]);
        amid[row*768 + 512 + hc] = f2bf(h2s[hc][w]);
    }
}

// ---------------- head ----------------
__global__ __launch_bounds__(256)
void k_z(const u16* __restrict__ h, u16* __restrict__ z)
{
    int bid = blockIdx.x, t = threadIdx.x;     // bid = n*16+c
    #pragma unroll
    for (int tc=0;tc<4;tc++)
        z[((size_t)bid*4 + tc)*HD + t] = f2bf(tanhf(bf2f(h[((size_t)bid*LSEQ + TT + tc)*HD + t])));
}

// head1 partial: grid (nb 0..15, kb 0..15); partial over K-chunk of 1024; Wd1 read fp32
__global__ __launch_bounds__(256)
void k_head1p(const u16* __restrict__ z, const float* __restrict__ Wd1,
              float* __restrict__ d1p)
{
    __shared__ float zch[64][137];
    __shared__ float wt[16][137];
    int t = threadIdx.x;
    int col = t & 15, rgrp = t >> 4;
    int ob = blockIdx.x * 16;
    int kb = blockIdx.y;
    float acc[4] = {0.f,0.f,0.f,0.f};
    for (int kc=0; kc<1024; kc+=128){
        int base_k = kb*1024 + kc;
        #pragma unroll
        for (int jj=0; jj<16; jj++){
            int idx = t + jj*256;
            int n = idx >> 6, k2 = (idx & 63) << 1;
            u32 r = *(const u32*)&z[(size_t)n*16384 + base_k + k2];
            zch[n][k2] = lo16(r); zch[n][k2+1] = hi16(r);
        }
        #pragma unroll
        for (int jj=0; jj<2; jj++){
            int idx = t + jj*256;
            int r = idx >> 5, k4 = (idx & 31) << 2;
            float4 w4 = *(const float4*)&Wd1[(size_t)(ob + r)*16384 + base_k + k4];
            wt[r][k4] = w4.x; wt[r][k4+1] = w4.y; wt[r][k4+2] = w4.z; wt[r][k4+3] = w4.w;
        }
        __syncthreads();
        for (int k=0;k<128;k++){
            float wv = wt[col][k];
            #pragma unroll
            for (int u=0;u<4;u++) acc[u] += zch[rgrp + 16*u][k]*wv;
        }
        __syncthreads();
    }
    #pragma unroll
    for (int u=0;u<4;u++)
        d1p[(size_t)(kb*64 + rgrp + 16*u)*HD + ob + col] = acc[u];
}

// fused: reduce d1p partials -> GELU -> dot with Wd2 -> out
__global__ __launch_bounds__(256)
void k_headf(const float* __restrict__ d1p, const float* __restrict__ bd1,
             const float* __restrict__ Wd2, const float* __restrict__ bd2,
             float* __restrict__ out)
{
    __shared__ float red[4];
    int n = blockIdx.x, c = threadIdx.x;
    float s = 0.f;
    #pragma unroll
    for (int kb=0; kb<16; kb++) s += d1p[(size_t)(kb*64 + n)*HD + c];
    float xx = s + bd1[c];
    float ge = 0.5f*xx*(1.f + erff(xx*0.70710678118654752f));
    float p = ge * Wd2[c];
    #pragma unroll
    for (int m=1;m<64;m<<=1) p += __shfl_xor(p, m, 64);
    if ((c & 63) == 0) red[c >> 6] = p;
    __syncthreads();
    if (c == 0) out[n] = red[0]+red[1]+red[2]+red[3] + bd2[0];
}

// ---------------- launch ----------------
extern "C" void kernel_launch(void* const* d_in, const int* in_sizes, int n_in,
                              void* d_out, int out_size, void* d_ws, size_t ws_size,
                              hipStream_t stream)
{
    const float* x    = (const float*)d_in[0];
    const float* Wfc  = (const float*)d_in[3];
    const float* bfc  = (const float*)d_in[4];
    const float* cls  = (const float*)d_in[5];
    const float* pos  = (const float*)d_in[6];
    const float* emb1 = (const float*)d_in[7];
    const float* emb2 = (const float*)d_in[8];
    const float* Wl1  = (const float*)d_in[9];
    const float* bl1  = (const float*)d_in[10];
    const float* Wl2  = (const float*)d_in[11];
    const float* bl2  = (const float*)d_in[12];
    const float* Wqkv = (const float*)d_in[13];
    const float* bqkv = (const float*)d_in[14];
    const float* Wo   = (const float*)d_in[15];
    const float* bo   = (const float*)d_in[16];
    const float* W1   = (const float*)d_in[17];
    const float* b1   = (const float*)d_in[18];
    const float* W2   = (const float*)d_in[19];
    const float* b2   = (const float*)d_in[20];
    const float* ln1g = (const float*)d_in[21];
    const float* ln1b = (const float*)d_in[22];
    const float* ln2g = (const float*)d_in[23];
    const float* ln2b = (const float*)d_in[24];
    const float* Wmlp = (const float*)d_in[25];
    const float* bmlp = (const float*)d_in[26];
    const float* Wd1  = (const float*)d_in[27];
    const float* bd1  = (const float*)d_in[28];
    const float* Wd2  = (const float*)d_in[29];
    const float* bd2  = (const float*)d_in[30];

    // dynamic chunk selection
    int NCH = 8;
    {
        const size_t fixed = 63145088 + (1<<20);
        if      (fixed + (size_t)MTOK    *2560 <= ws_size) NCH = 1;
        else if (fixed + (size_t)(MTOK/2)*2560 <= ws_size) NCH = 2;
        else if (fixed + (size_t)(MTOK/4)*2560 <= ws_size) NCH = 4;
    }
    const int RCH = MTOK / NCH;
    const int SCH = BSEQ / NCH;

    // workspace layout
    u16* h    = (u16*)d_ws;                    // 26,214,400 u16
    u16* buf  = h    + (size_t)MTOK*HD;        // RCH*1024  (qkv / ff1 / mixprop amid)
    u16* buf2 = buf  + (size_t)RCH*1024;       // RCH*256
    u16* wq   = buf2 + (size_t)RCH*256;        //    786,432
    u16* wo   = wq   + (size_t)4*768*256;      //    262,144
    u16* w1   = wo   + (size_t)4*256*256;      //  1,048,576
    u16* w2   = w1   + (size_t)4*1024*256;     //  1,048,576
    u16* wmb  = w2   + (size_t)4*256*1024;     //    589,824  (3 layers x 256 x 768, orig layout)
    u16* zb   = wmb  + (size_t)3*256*768;      //  1,048,576
    float* fp = (float*)(zb + (size_t)BSZ*16384);
    float* m1  = fp;
    float* m2  = m1 + CCH*HD;
    float* an  = m2 + CCH*HD;
    float* d1p = an + CCH*CCH;                 // 16*64*256

    // one-time weight prep
    k_cvt<<<512, 256, 0, stream>>>(Wqkv, wq, 4*768*256);
    k_cvt<<<256, 256, 0, stream>>>(Wo,   wo, 4*256*256);
    k_cvt<<<512, 256, 0, stream>>>(W1,   w1, 4*1024*256);
    k_cvt<<<512, 256, 0, stream>>>(W2,   w2, 4*256*1024);
    k_cvt<<<256, 256, 0, stream>>>(Wmlp, wmb, 3*256*768);

    k_embed<<<BSEQ, 256, 0, stream>>>(x, Wfc, bfc, cls, pos, h);
    k_graph_m<<<16, 256, 0, stream>>>(emb1, Wl1, bl1, m1);
    k_graph_m<<<16, 256, 0, stream>>>(emb2, Wl2, bl2, m2);
    k_graph_a<<<1, 256, 0, stream>>>(m1, m2, an);

    for (int l=0; l<NLAY; l++){
        if (l > 0){
            // mixprop: prep (graph propagation) -> MFMA GEMM (M=4096,K=768,N=256) -> h (scatter)
            k_mixprep<<<BSZ*NCLS, 256, 0, stream>>>(h, an, buf);
            k_gemmA<<<dim3(4096/128, 256/128), 256, 0, stream>>>(
                buf, 768, wmb + (size_t)(l-1)*256*768, bmlp + (size_t)(l-1)*HD,
                h, HD, 768, 0, 1);
        }

        for (int c=0; c<NCH; c++){
            size_t row0 = (size_t)c * RCH;
            k_gemmA<<<dim3(RCH/128, 768/128), 256, 0, stream>>>(
                h + row0*HD, HD, wq + (size_t)l*768*256, bqkv + (size_t)l*768,
                buf, 768, HD, 0, 0);
            k_attn<<<SCH*NHEAD/2, 256, 0, stream>>>(buf);
            k_gemmA<<<dim3(RCH/128, 256/128), 256, 0, stream>>>(
                buf, 768, wo + (size_t)l*256*256, bo + (size_t)l*HD, buf2, 256, HD, 0, 0);
            k_ln<<<RCH/8, 256, 0, stream>>>(buf2, h,
                ln1g + (size_t)l*HD, ln1b + (size_t)l*HD, row0);
            k_gemmA<<<dim3(RCH/128, 1024/128), 256, 0, stream>>>(
                h + row0*HD, HD, w1 + (size_t)l*1024*256, b1 + (size_t)l*1024,
                buf, 1024, HD, 1, 0);
            k_gemmA<<<dim3(RCH/128, 256/128), 256, 0, stream>>>(
                buf, 1024, w2 + (size_t)l*256*1024, b2 + (size_t)l*HD, buf2, 256, 1024, 0, 0);
            k_ln<<<RCH/8, 256, 0, stream>>>(buf2, h,
                ln2g + (size_t)l*HD, ln2b + (size_t)l*HD, row0);
        }
    }

    k_z<<<BSZ*CCH, 256, 0, stream>>>(h, zb);
    k_head1p<<<dim3(16, 16), 256, 0, stream>>>(zb, Wd1, d1p);
    k_headf<<<BSZ, 256, 0, stream>>>(d1p, bd1, Wd2, bd2, (float*)d_out);
}

// Round 14
// 2302.222 us; speedup vs baseline: 2.8872x; 1.0482x over previous
//
#include <hip/hip_runtime.h>
#include <hip/hip_bf16.h>
#include <math.h>

typedef unsigned short u16;
typedef unsigned int   u32;
typedef __attribute__((ext_vector_type(8))) short short8;   // 8 bf16 = 4 VGPRs
typedef __attribute__((ext_vector_type(4))) float f32x4;

// ---- model dims ----
#define BSZ   64
#define TT    96
#define CCH   16
#define INDIM 16
#define HD    256
#define NHEAD 8
#define DHEAD 32
#define NCLS  4
#define LSEQ  100      // TT + NCLS
#define NLAY  4
#define EPSV  1e-5f
#define BSEQ  (BSZ*CCH)        // 1024 sequences
#define MTOK  (BSEQ*LSEQ)      // 102400 tokens

__device__ __forceinline__ float bf2f(u16 x){ return __uint_as_float(((u32)x)<<16); }
__device__ __forceinline__ u16 f2bf(float f){
    u32 u = __float_as_uint(f);
    u32 r = (u + 0x7fffu + ((u>>16)&1u)) >> 16;
    return (u16)r;
}
__device__ __forceinline__ float lo16(u32 r){ return __uint_as_float(r<<16); }
__device__ __forceinline__ float hi16(u32 r){ return __uint_as_float(r&0xffff0000u); }

// async global->LDS, 16B per lane; LDS dest = (wave-uniform base) + lane*16
__device__ __forceinline__ void gload_lds16(const u16* g, u16* l){
    __builtin_amdgcn_global_load_lds(
        (const __attribute__((address_space(1))) unsigned int*)g,
        (__attribute__((address_space(3))) unsigned int*)l, 16, 0, 0);
}

// ---------------- f32 -> bf16 bulk convert ----------------
__global__ __launch_bounds__(256)
void k_cvt(const float* __restrict__ src, u16* __restrict__ dst, int n)
{
    for (int i = blockIdx.x*256 + threadIdx.x; i < n; i += gridDim.x*256)
        dst[i] = f2bf(src[i]);
}

// ---------------- embed: one block per sequence, Wfc row in registers ----------------
__global__ __launch_bounds__(256)
void k_embed(const float* __restrict__ x, const float* __restrict__ Wfc,
             const float* __restrict__ bfc, const float* __restrict__ cls,
             const float* __restrict__ pos, u16* __restrict__ h)
{
    int s = blockIdx.x;                // 0..1023 = n*16 + c
    int n = s >> 4, c = s & 15;
    int hc = threadIdx.x;
    float wr[INDIM];
    #pragma unroll
    for (int i=0;i<INDIM;i++) wr[i] = Wfc[hc*INDIM + i];
    float bb = bfc[hc];
    for (int l=0; l<TT; l++){
        const float* xr = x + (size_t)((n*TT + l)*CCH + c)*INDIM;
        float acc = bb;
        #pragma unroll
        for (int i=0;i<INDIM;i++) acc += xr[i]*wr[i];
        acc += pos[(size_t)(l*CCH + c)*HD + hc];
        h[((size_t)s*LSEQ + l)*HD + hc] = f2bf(acc);
    }
    #pragma unroll
    for (int l=TT; l<LSEQ; l++){
        float v = cls[(size_t)((l-TT)*CCH + c)*HD + hc]
                + pos[(size_t)(l*CCH + c)*HD + hc];
        h[((size_t)s*LSEQ + l)*HD + hc] = f2bf(v);
    }
}

// ---------------- graph constructor ----------------
__global__ __launch_bounds__(256)
void k_graph_m(const float* __restrict__ emb, const float* __restrict__ Wl,
               const float* __restrict__ bl, float* __restrict__ m)
{
    int r = blockIdx.x, o = threadIdx.x;
    __shared__ float e[HD];
    e[o] = emb[r*HD + o];
    __syncthreads();
    const float* w = Wl + (size_t)o*HD;
    float acc = bl[o];
    for (int k=0;k<HD;k++) acc += e[k]*w[k];
    m[r*HD + o] = tanhf(acc);
}

__global__ __launch_bounds__(256)
void k_graph_a(const float* __restrict__ m1, const float* __restrict__ m2,
               float* __restrict__ a)
{
    int t = threadIdx.x; int v = t >> 4, w = t & 15;
    __shared__ float adj[16][17];
    float s1=0.f, s2=0.f;
    for (int k=0;k<HD;k++){
        s1 += m1[v*HD+k]*m2[w*HD+k];
        s2 += m2[v*HD+k]*m1[w*HD+k];
    }
    float g = tanhf(s1 - s2); g = g > 0.f ? g : 0.f;
    adj[v][w] = g + (v==w ? 1.f : 0.f);
    __syncthreads();
    float rs = 0.f;
    #pragma unroll
    for (int j=0;j<16;j++) rs += adj[v][j];
    a[t] = adj[v][w] / rs;
}

// ---------------- MFMA GEMM, BK=64; optional cls-scatter output mapping ----------------
// BM=128, BN=128; 256 threads = 4 waves, each 64x64. K multiple of 64.
__global__ __launch_bounds__(256)
void k_gemmA(const u16* __restrict__ A, int lda,
             const u16* __restrict__ W, const float* __restrict__ bias,
             u16* __restrict__ C, int ldc, int K, int relu, int scat)
{
    __shared__ u16 As0[128*32], As1[128*32];
    __shared__ u16 Ws0[128*32], Ws1[128*32];
    int t = threadIdx.x;
    int lane = t & 63, w = t >> 6;
    int wm = (w & 1)*64, wn = (w >> 1)*64;
    int fr = lane & 15, quad = lane >> 4;
    size_t mb = (size_t)blockIdx.x * 128;
    int nb = blockIdx.y * 128;
    int srow = lane >> 2;
    int sslot = lane & 3;

    f32x4 acc[4][4] = {};
    for (int k0 = 0; k0 < K; k0 += 64){
        __syncthreads();
        #pragma unroll
        for (int i=0;i<2;i++){
            int r = w*32 + i*16 + srow;
            int cw = sslot ^ ((r>>1)&3);
            gload_lds16(&A[(mb + r)*(size_t)lda + k0      + cw*8], &As0[(w*32 + i*16)*32]);
            gload_lds16(&A[(mb + r)*(size_t)lda + k0 + 32 + cw*8], &As1[(w*32 + i*16)*32]);
            gload_lds16(&W[(size_t)(nb + r)*K   + k0      + cw*8], &Ws0[(w*32 + i*16)*32]);
            gload_lds16(&W[(size_t)(nb + r)*K   + k0 + 32 + cw*8], &Ws1[(w*32 + i*16)*32]);
        }
        __syncthreads();
        short8 af0[4], af1[4], bf0[4], bf1[4];
        #pragma unroll
        for (int mt=0; mt<4; mt++){
            int r = wm + mt*16 + fr;
            int sw = (quad ^ ((r>>1)&3)) << 3;
            af0[mt] = *(const short8*)&As0[r*32 + sw];
            af1[mt] = *(const short8*)&As1[r*32 + sw];
        }
        #pragma unroll
        for (int nt=0; nt<4; nt++){
            int r = wn + nt*16 + fr;
            int sw = (quad ^ ((r>>1)&3)) << 3;
            bf0[nt] = *(const short8*)&Ws0[r*32 + sw];
            bf1[nt] = *(const short8*)&Ws1[r*32 + sw];
        }
        #pragma unroll
        for (int mt=0; mt<4; mt++)
            #pragma unroll
            for (int nt=0; nt<4; nt++){
                acc[mt][nt] = __builtin_amdgcn_mfma_f32_16x16x32_bf16(
                    af0[mt], bf0[nt], acc[mt][nt], 0, 0, 0);
                acc[mt][nt] = __builtin_amdgcn_mfma_f32_16x16x32_bf16(
                    af1[mt], bf1[nt], acc[mt][nt], 0, 0, 0);
            }
    }
    float bb[4];
    #pragma unroll
    for (int nt=0; nt<4; nt++) bb[nt] = bias[nb + wn + nt*16 + fr];
    #pragma unroll
    for (int mt=0; mt<4; mt++){
        #pragma unroll
        for (int nt=0; nt<4; nt++){
            #pragma unroll
            for (int r=0; r<4; r++){
                float v = acc[mt][nt][r] + bb[nt];
                if (relu) v = v > 0.f ? v : 0.f;
                size_t rg = mb + wm + mt*16 + quad*4 + r;
                if (scat) rg = (rg >> 2)*LSEQ + TT + (rg & 3);
                C[rg*(size_t)ldc + nb + wn + nt*16 + fr] = f2bf(v);
            }
        }
    }
}

// ------- MFMA GEMM (N=256) + bias + residual + LayerNorm fused, in-place h -------
// BM=64, BN=256, BK=64; 256 threads = 4 waves; wave w owns rows w*16..w*16+15, all 256 cols.
// Epilogue entirely in registers: C-layout rows reduced by 16-lane shuffles. No Cs LDS.
__global__ __launch_bounds__(256)
void k_gemmC(const u16* __restrict__ A, int lda, int K,
             const u16* __restrict__ W, const float* __restrict__ bias,
             u16* __restrict__ h, const float* __restrict__ gam,
             const float* __restrict__ bet, size_t row0)
{
    __shared__ u16 As0[64*32], As1[64*32];
    __shared__ u16 Ws0[256*32], Ws1[256*32];
    int t = threadIdx.x;
    int lane = t & 63, w = t >> 6;
    int fr = lane & 15, quad = lane >> 4;
    size_t mb = (size_t)blockIdx.x * 64;
    int srow = lane >> 2, sslot = lane & 3;

    f32x4 acc[16] = {};
    for (int k0 = 0; k0 < K; k0 += 64){
        __syncthreads();
        {
            int r = w*16 + srow;
            int cw = sslot ^ ((r>>1)&3);
            gload_lds16(&A[(mb + r)*(size_t)lda + k0      + cw*8], &As0[(w*16)*32]);
            gload_lds16(&A[(mb + r)*(size_t)lda + k0 + 32 + cw*8], &As1[(w*16)*32]);
        }
        #pragma unroll
        for (int i=0;i<4;i++){
            int r = w*64 + i*16 + srow;
            int cw = sslot ^ ((r>>1)&3);
            gload_lds16(&W[(size_t)r*K + k0      + cw*8], &Ws0[(w*64 + i*16)*32]);
            gload_lds16(&W[(size_t)r*K + k0 + 32 + cw*8], &Ws1[(w*64 + i*16)*32]);
        }
        __syncthreads();
        int ra = w*16 + fr;
        int swa = (quad ^ ((ra>>1)&3)) << 3;
        short8 a0 = *(const short8*)&As0[ra*32 + swa];
        short8 a1 = *(const short8*)&As1[ra*32 + swa];
        #pragma unroll
        for (int nt=0; nt<16; nt++){
            int rb = nt*16 + fr;
            int swb = (quad ^ ((rb>>1)&3)) << 3;
            short8 b0 = *(const short8*)&Ws0[rb*32 + swb];
            short8 b1 = *(const short8*)&Ws1[rb*32 + swb];
            acc[nt] = __builtin_amdgcn_mfma_f32_16x16x32_bf16(a0, b0, acc[nt], 0,0,0);
            acc[nt] = __builtin_amdgcn_mfma_f32_16x16x32_bf16(a1, b1, acc[nt], 0,0,0);
        }
    }
    float bb[16], gg[16], be[16];
    #pragma unroll
    for (int nt=0; nt<16; nt++){
        int col = nt*16 + fr;
        bb[nt] = bias[col]; gg[nt] = gam[col]; be[nt] = bet[col];
    }
    #pragma unroll
    for (int r=0; r<4; r++){
        size_t row = row0 + mb + w*16 + quad*4 + r;
        float v[16];
        float s = 0.f;
        #pragma unroll
        for (int nt=0; nt<16; nt++){
            v[nt] = acc[nt][r] + bb[nt] + bf2f(h[row*HD + nt*16 + fr]);
            s += v[nt];
        }
        s += __shfl_xor(s, 1, 64); s += __shfl_xor(s, 2, 64);
        s += __shfl_xor(s, 4, 64); s += __shfl_xor(s, 8, 64);
        float mean = s * (1.f/256.f);
        float vv = 0.f;
        #pragma unroll
        for (int nt=0; nt<16; nt++){ float d = v[nt]-mean; vv += d*d; }
        vv += __shfl_xor(vv, 1, 64); vv += __shfl_xor(vv, 2, 64);
        vv += __shfl_xor(vv, 4, 64); vv += __shfl_xor(vv, 8, 64);
        float inv = rsqrtf(vv*(1.f/256.f) + EPSV);
        #pragma unroll
        for (int nt=0; nt<16; nt++)
            h[row*HD + nt*16 + fr] = f2bf((v[nt]-mean)*inv*gg[nt] + be[nt]);
    }
}

// ---------------- MFMA attention with causal tile-skipping ----------------
// Wave strips rebalanced: wave0 {0,1,3,6} (14 S-units), wave1 {2,4,5} (14 S-units).
#define KS_STR 40
#define VT_STR 136
#define PL_STR 136
__global__ __launch_bounds__(256)
void k_attn(u16* __restrict__ qkv)
{
    __shared__ u16 smem[26368];          // Ks 2x4480 | Vt 2x4352 | Pl 4x2176 (u16 counts)
    int t = threadIdx.x;
    int w = t >> 6, lane = t & 63;
    int fr = lane & 15, quad = lane >> 4;
    int p = t >> 7, t2 = t & 127;
    u16* Ks = smem + p*4480;
    u16* Vt = smem + 8960 + p*4352;
    u16* Pl = smem + 17664 + w*2176;

    {
        int gp = blockIdx.x*2 + p;
        size_t base = (size_t)(gp >> 3)*LSEQ*768 + (gp & 7)*32;
        for (int idx = t2; idx < 1792; idx += 128){
            int key = idx >> 4, d2 = (idx & 15) << 1;
            u32 kv = (key < LSEQ) ? *(const u32*)&qkv[base + (size_t)key*768 + 256 + d2] : 0u;
            *(u32*)&Ks[key*KS_STR + d2] = kv;
        }
        for (int idx = t2; idx < 2048; idx += 128){
            int key = idx >> 4, d2 = (idx & 15) << 1;
            u32 vv = (key < LSEQ) ? *(const u32*)&qkv[base + (size_t)key*768 + 512 + d2] : 0u;
            Vt[ d2   *VT_STR + key] = (u16)(vv & 0xffffu);
            Vt[(d2+1)*VT_STR + key] = (u16)(vv >> 16);
        }
    }
    __syncthreads();

    int wp = w >> 1;
    int gp = blockIdx.x*2 + wp;
    size_t base = (size_t)(gp >> 3)*LSEQ*768 + (gp & 7)*32;
    u16* Ksw = smem + wp*4480;
    u16* Vtw = smem + 8960 + wp*4352;

    short8 kf[7];
    #pragma unroll
    for (int nt=0; nt<7; nt++)
        kf[nt] = *(const short8*)&Ksw[(nt*16 + fr)*KS_STR + quad*8];
    short8 vfr[4][2];
    #pragma unroll
    for (int ks=0; ks<4; ks++)
        #pragma unroll
        for (int nt=0; nt<2; nt++)
            vfr[ks][nt] = *(const short8*)&Vtw[(nt*16 + fr)*VT_STR + ks*32 + quad*8];

    const float scale = 0.17677669529663687f;  // 1/sqrt(32)
    int smask = (w & 1) ? 0x34 : 0x4B;        // strips {2,4,5} / {0,1,3,6}
    #pragma unroll
    for (int st = 0; st < 7; ++st){
        if (!((smask >> st) & 1)) continue;
        const int ntile = (st == 6) ? 7 : (st + 1);
        const int nks   = (st == 6) ? 4 : (st/2 + 1);
        int q = st*16 + fr;
        short8 qf = {};
        if (q < LSEQ) qf = *(const short8*)&qkv[base + (size_t)q*768 + quad*8];
        f32x4 S[7];
        #pragma unroll
        for (int nt=0; nt<7; nt++){
            if (nt >= ntile) continue;
            f32x4 z = {};
            S[nt] = __builtin_amdgcn_mfma_f32_16x16x32_bf16(qf, kf[nt], z, 0,0,0);
        }
        float mx[4] = {-1e30f,-1e30f,-1e30f,-1e30f};
        #pragma unroll
        for (int r=0;r<4;r++){
            int qr = st*16 + quad*4 + r;
            int jmax = (qr < TT) ? qr : (LSEQ-1);
            #pragma unroll
            for (int nt=0;nt<7;nt++){
                if (nt >= ntile) continue;
                int j = nt*16 + fr;
                float s = (j <= jmax) ? S[nt][r]*scale : -1e30f;
                S[nt][r] = s;
                mx[r] = fmaxf(mx[r], s);
            }
        }
        #pragma unroll
        for (int r=0;r<4;r++){
            #pragma unroll
            for (int m=1;m<16;m<<=1) mx[r] = fmaxf(mx[r], __shfl_xor(mx[r], m, 64));
        }
        float l4[4] = {0.f,0.f,0.f,0.f};
        #pragma unroll
        for (int r=0;r<4;r++){
            #pragma unroll
            for (int nt=0;nt<7;nt++){
                if (nt >= ntile) continue;
                float pv = __expf(S[nt][r] - mx[r]);
                S[nt][r] = pv;
                l4[r] += pv;
            }
        }
        #pragma unroll
        for (int r=0;r<4;r++){
            #pragma unroll
            for (int m=1;m<16;m<<=1) l4[r] += __shfl_xor(l4[r], m, 64);
        }
        // pass 1: P_hi; zero-pad the straddling tile if PV covers past ntile*16
        #pragma unroll
        for (int nt=0;nt<7;nt++){
            if (nt >= ntile) continue;
            #pragma unroll
            for (int r=0;r<4;r++){
                u16 hb = f2bf(S[nt][r]);
                Pl[(quad*4+r)*PL_STR + nt*16 + fr] = hb;
                S[nt][r] -= bf2f(hb);
            }
        }
        if (ntile*16 < nks*32){
            #pragma unroll
            for (int r=0;r<4;r++)
                Pl[(quad*4+r)*PL_STR + ntile*16 + fr] = 0;
        }
        __builtin_amdgcn_s_waitcnt(0);
        f32x4 D[2] = {};
        #pragma unroll
        for (int ks=0; ks<4; ks++){
            if (ks >= nks) continue;
            short8 pf = *(const short8*)&Pl[fr*PL_STR + ks*32 + quad*8];
            #pragma unroll
            for (int nt=0; nt<2; nt++)
                D[nt] = __builtin_amdgcn_mfma_f32_16x16x32_bf16(pf, vfr[ks][nt], D[nt], 0,0,0);
        }
        __builtin_amdgcn_s_waitcnt(0);
        // pass 2: P_lo
        #pragma unroll
        for (int nt=0;nt<7;nt++){
            if (nt >= ntile) continue;
            #pragma unroll
            for (int r=0;r<4;r++)
                Pl[(quad*4+r)*PL_STR + nt*16 + fr] = f2bf(S[nt][r]);
        }
        __builtin_amdgcn_s_waitcnt(0);
        #pragma unroll
        for (int ks=0; ks<4; ks++){
            if (ks >= nks) continue;
            short8 pf = *(const short8*)&Pl[fr*PL_STR + ks*32 + quad*8];
            #pragma unroll
            for (int nt=0; nt<2; nt++)
                D[nt] = __builtin_amdgcn_mfma_f32_16x16x32_bf16(pf, vfr[ks][nt], D[nt], 0,0,0);
        }
        #pragma unroll
        for (int r=0;r<4;r++){
            int qr = st*16 + quad*4 + r;
            if (qr < LSEQ){
                float inv = 1.f / l4[r];
                #pragma unroll
                for (int nt=0; nt<2; nt++)
                    qkv[base + (size_t)qr*768 + nt*16 + fr] = f2bf(D[nt][r]*inv);
            }
        }
        __builtin_amdgcn_s_waitcnt(0);
    }
}

// ---------------- mixprop prep: graph propagation -> amid rows (bf16) ----------------
__global__ __launch_bounds__(256)
void k_mixprep(const u16* __restrict__ h, const float* __restrict__ a,
               u16* __restrict__ amid)
{
    int n = blockIdx.x >> 2, tt = blockIdx.x & 3;
    __shared__ float xs[256][17], h1s[256][17], h2s[256][17];
    __shared__ float as[16][17];
    int t = threadIdx.x;
    as[t>>4][t&15] = a[t];
    for (int idx=t; idx<4096; idx+=256){
        int w = idx >> 8, hc = idx & 255;
        xs[hc][w] = bf2f(h[((size_t)(n*16 + w)*LSEQ + TT + tt)*HD + hc]);
    }
    __syncthreads();
    for (int idx=t; idx<4096; idx+=256){
        int v = idx & 15, hc = idx >> 4;
        float acc = 0.f;
        #pragma unroll
        for (int w=0;w<16;w++) acc += as[v][w]*xs[hc][w];
        h1s[hc][v] = acc;
    }
    __syncthreads();
    for (int idx=t; idx<4096; idx+=256){
        int v = idx & 15, hc = idx >> 4;
        float acc = 0.f;
        #pragma unroll
        for (int w=0;w<16;w++) acc += as[v][w]*h1s[hc][w];
        h2s[hc][v] = acc;
    }
    __syncthreads();
    int hc = t;
    #pragma unroll
    for (int w=0;w<16;w++){
        size_t row = (size_t)((n*16 + w)*4 + tt);
        amid[row*768 +       hc] = f2bf(xs[hc][w]);
        amid[row*768 + 256 + hc] = f2bf(h1s[hc][w]);
        amid[row*768 + 512 + hc] = f2bf(h2s[hc][w]);
    }
}

// ---------------- head ----------------
__global__ __launch_bounds__(256)
void k_z(const u16* __restrict__ h, u16* __restrict__ z)
{
    int bid = blockIdx.x, t = threadIdx.x;     // bid = n*16+c
    #pragma unroll
    for (int tc=0;tc<4;tc++)
        z[((size_t)bid*4 + tc)*HD + t] = f2bf(tanhf(bf2f(h[((size_t)bid*LSEQ + TT + tc)*HD + t])));
}

// head1 partial: grid (nb 0..15, kb 0..15); partial over K-chunk of 1024; Wd1 read fp32
__global__ __launch_bounds__(256)
void k_head1p(const u16* __restrict__ z, const float* __restrict__ Wd1,
              float* __restrict__ d1p)
{
    __shared__ float zch[64][137];
    __shared__ float wt[16][137];
    int t = threadIdx.x;
    int col = t & 15, rgrp = t >> 4;
    int ob = blockIdx.x * 16;
    int kb = blockIdx.y;
    float acc[4] = {0.f,0.f,0.f,0.f};
    for (int kc=0; kc<1024; kc+=128){
        int base_k = kb*1024 + kc;
        #pragma unroll
        for (int jj=0; jj<16; jj++){
            int idx = t + jj*256;
            int n = idx >> 6, k2 = (idx & 63) << 1;
            u32 r = *(const u32*)&z[(size_t)n*16384 + base_k + k2];
            zch[n][k2] = lo16(r); zch[n][k2+1] = hi16(r);
        }
        #pragma unroll
        for (int jj=0; jj<2; jj++){
            int idx = t + jj*256;
            int r = idx >> 5, k4 = (idx & 31) << 2;
            float4 w4 = *(const float4*)&Wd1[(size_t)(ob + r)*16384 + base_k + k4];
            wt[r][k4] = w4.x; wt[r][k4+1] = w4.y; wt[r][k4+2] = w4.z; wt[r][k4+3] = w4.w;
        }
        __syncthreads();
        for (int k=0;k<128;k++){
            float wv = wt[col][k];
            #pragma unroll
            for (int u=0;u<4;u++) acc[u] += zch[rgrp + 16*u][k]*wv;
        }
        __syncthreads();
    }
    #pragma unroll
    for (int u=0;u<4;u++)
        d1p[(size_t)(kb*64 + rgrp + 16*u)*HD + ob + col] = acc[u];
}

// fused: reduce d1p partials -> GELU -> dot with Wd2 -> out
__global__ __launch_bounds__(256)
void k_headf(const float* __restrict__ d1p, const float* __restrict__ bd1,
             const float* __restrict__ Wd2, const float* __restrict__ bd2,
             float* __restrict__ out)
{
    __shared__ float red[4];
    int n = blockIdx.x, c = threadIdx.x;
    float s = 0.f;
    #pragma unroll
    for (int kb=0; kb<16; kb++) s += d1p[(size_t)(kb*64 + n)*HD + c];
    float xx = s + bd1[c];
    float ge = 0.5f*xx*(1.f + erff(xx*0.70710678118654752f));
    float p = ge * Wd2[c];
    #pragma unroll
    for (int m=1;m<64;m<<=1) p += __shfl_xor(p, m, 64);
    if ((c & 63) == 0) red[c >> 6] = p;
    __syncthreads();
    if (c == 0) out[n] = red[0]+red[1]+red[2]+red[3] + bd2[0];
}

// ---------------- launch ----------------
extern "C" void kernel_launch(void* const* d_in, const int* in_sizes, int n_in,
                              void* d_out, int out_size, void* d_ws, size_t ws_size,
                              hipStream_t stream)
{
    const float* x    = (const float*)d_in[0];
    const float* Wfc  = (const float*)d_in[3];
    const float* bfc  = (const float*)d_in[4];
    const float* cls  = (const float*)d_in[5];
    const float* pos  = (const float*)d_in[6];
    const float* emb1 = (const float*)d_in[7];
    const float* emb2 = (const float*)d_in[8];
    const float* Wl1  = (const float*)d_in[9];
    const float* bl1  = (const float*)d_in[10];
    const float* Wl2  = (const float*)d_in[11];
    const float* bl2  = (const float*)d_in[12];
    const float* Wqkv = (const float*)d_in[13];
    const float* bqkv = (const float*)d_in[14];
    const float* Wo   = (const float*)d_in[15];
    const float* bo   = (const float*)d_in[16];
    const float* W1   = (const float*)d_in[17];
    const float* b1   = (const float*)d_in[18];
    const float* W2   = (const float*)d_in[19];
    const float* b2   = (const float*)d_in[20];
    const float* ln1g = (const float*)d_in[21];
    const float* ln1b = (const float*)d_in[22];
    const float* ln2g = (const float*)d_in[23];
    const float* ln2b = (const float*)d_in[24];
    const float* Wmlp = (const float*)d_in[25];
    const float* bmlp = (const float*)d_in[26];
    const float* Wd1  = (const float*)d_in[27];
    const float* bd1  = (const float*)d_in[28];
    const float* Wd2  = (const float*)d_in[29];
    const float* bd2  = (const float*)d_in[30];

    // dynamic chunk selection
    int NCH = 8;
    {
        const size_t fixed = 63145088 + (1<<20);
        if      (fixed + (size_t)MTOK    *2560 <= ws_size) NCH = 1;
        else if (fixed + (size_t)(MTOK/2)*2560 <= ws_size) NCH = 2;
        else if (fixed + (size_t)(MTOK/4)*2560 <= ws_size) NCH = 4;
    }
    const int RCH = MTOK / NCH;
    const int SCH = BSEQ / NCH;

    // workspace layout (buf2 slot retained but unused by the fused path)
    u16* h    = (u16*)d_ws;                    // 26,214,400 u16
    u16* buf  = h    + (size_t)MTOK*HD;        // RCH*1024  (qkv / ff1 / mixprop amid)
    u16* buf2 = buf  + (size_t)RCH*1024;       // RCH*256
    u16* wq   = buf2 + (size_t)RCH*256;        //    786,432
    u16* wo   = wq   + (size_t)4*768*256;      //    262,144
    u16* w1   = wo   + (size_t)4*256*256;      //  1,048,576
    u16* w2   = w1   + (size_t)4*1024*256;     //  1,048,576
    u16* wmb  = w2   + (size_t)4*256*1024;     //    589,824
    u16* zb   = wmb  + (size_t)3*256*768;      //  1,048,576
    float* fp = (float*)(zb + (size_t)BSZ*16384);
    float* m1  = fp;
    float* m2  = m1 + CCH*HD;
    float* an  = m2 + CCH*HD;
    float* d1p = an + CCH*CCH;                 // 16*64*256

    // one-time weight prep
    k_cvt<<<512, 256, 0, stream>>>(Wqkv, wq, 4*768*256);
    k_cvt<<<256, 256, 0, stream>>>(Wo,   wo, 4*256*256);
    k_cvt<<<512, 256, 0, stream>>>(W1,   w1, 4*1024*256);
    k_cvt<<<512, 256, 0, stream>>>(W2,   w2, 4*256*1024);
    k_cvt<<<256, 256, 0, stream>>>(Wmlp, wmb, 3*256*768);

    k_embed<<<BSEQ, 256, 0, stream>>>(x, Wfc, bfc, cls, pos, h);
    k_graph_m<<<16, 256, 0, stream>>>(emb1, Wl1, bl1, m1);
    k_graph_m<<<16, 256, 0, stream>>>(emb2, Wl2, bl2, m2);
    k_graph_a<<<1, 256, 0, stream>>>(m1, m2, an);

    for (int l=0; l<NLAY; l++){
        if (l > 0){
            k_mixprep<<<BSZ*NCLS, 256, 0, stream>>>(h, an, buf);
            k_gemmA<<<dim3(4096/128, 256/128), 256, 0, stream>>>(
                buf, 768, wmb + (size_t)(l-1)*256*768, bmlp + (size_t)(l-1)*HD,
                h, HD, 768, 0, 1);
        }

        for (int c=0; c<NCH; c++){
            size_t row0 = (size_t)c * RCH;
            k_gemmA<<<dim3(RCH/128, 768/128), 256, 0, stream>>>(
                h + row0*HD, HD, wq + (size_t)l*768*256, bqkv + (size_t)l*768,
                buf, 768, HD, 0, 0);
            k_attn<<<SCH*NHEAD/2, 256, 0, stream>>>(buf);
            // out-proj + residual + LN1 fused (reads q-slot of buf, lda=768)
            k_gemmC<<<RCH/64, 256, 0, stream>>>(
                buf, 768, HD, wo + (size_t)l*256*256, bo + (size_t)l*HD,
                h, ln1g + (size_t)l*HD, ln1b + (size_t)l*HD, row0);
            k_gemmA<<<dim3(RCH/128, 1024/128), 256, 0, stream>>>(
                h + row0*HD, HD, w1 + (size_t)l*1024*256, b1 + (size_t)l*1024,
                buf, 1024, HD, 1, 0);
            // FF2 + residual + LN2 fused
            k_gemmC<<<RCH/64, 256, 0, stream>>>(
                buf, 1024, 1024, w2 + (size_t)l*256*1024, b2 + (size_t)l*HD,
                h, ln2g + (size_t)l*HD, ln2b + (size_t)l*HD, row0);
        }
    }

    k_z<<<BSZ*CCH, 256, 0, stream>>>(h, zb);
    k_head1p<<<dim3(16, 16), 256, 0, stream>>>(zb, Wd1, d1p);
    k_headf<<<BSZ, 256, 0, stream>>>(d1p, bd1, Wd2, bd2, (float*)d_out);
}